// Round 4
// baseline (723.171 us; speedup 1.0000x reference)
//
#include <hip/hip_runtime.h>
#include <stdint.h>

typedef uint32_t u32;
typedef uint64_t u64;

#define NLVL 4
#define NPRE 2000
#define NPOST 1000
#define KPAD 8192
#define TIE_CAP 4096
#define NCHUNK 128          // row stride in u64 words (125 used, padded to 128)

// ws layout (bytes)
#define OFF_SBITS 0u                       // 1 MB  (250K u32)
#define OFF_HIST  (1u<<20)                 // 1 MB  (4*64K u32)
#define OFF_CTRL  (2u<<20)                 // 64 KB
#define OFF_TIE   ((2u<<20) + (64u<<10))   // 64 KB
#define OFF_CAND  ((2u<<20) + (128u<<10))  // 64 KB
#define OFF_SHIFT ((2u<<20) + (192u<<10))  // 128 KB
#define OFF_KEPT  ((2u<<20) + (320u<<10))  // 64 KB
#define OFF_MASK  (3u<<20)                 // 8 MB  (8192 rows * 128 u64); first 1MB doubles as hist2
#define WS_NEED   ((size_t)(3u<<20) + (size_t)KPAD * NCHUNK * 8u)

// ctrl word indices
#define C_CANDCNT 0
#define C_KEPTCNT 1
#define C_SEPMAX  2
#define C_P       4   // +lvl  (0xFFFFFFFF = deficient level)
#define C_RANK    8   // +lvl
#define C_T       16  // +lvl
#define C_NEED    20  // +lvl
#define C_TIECNT  24  // +lvl

// ---- monotone float<->u32 map for atomic max over floats ----
__device__ __forceinline__ u32 fmap(float f) {
  u32 u = __float_as_uint(f);
  return (u & 0x80000000u) ? ~u : (u | 0x80000000u);
}
__device__ __forceinline__ float funmap(u32 u) {
  u = (u & 0x80000000u) ? (u & 0x7FFFFFFFu) : ~u;
  return __uint_as_float(u);
}

// ---- replicate XLA-CPU GenerateVF32Exp (Cephes/Eigen-3.3 style) ----
__device__ __forceinline__ float xla_expf(float x) {
  const float kLog2e = 1.44269504088896341f;
  const float kC1 = 0.693359375f;
  const float kC2 = -2.12194440e-4f;
  const float kP0 = 1.9875691500e-4f;
  const float kP1 = 1.3981999507e-3f;
  const float kP2 = 8.3334519073e-3f;
  const float kP3 = 4.1665795894e-2f;
  const float kP4 = 1.6666665459e-1f;
  const float kP5 = 5.0000001201e-1f;
  float xc = fminf(fmaxf(x, -88.3762626647949f), 88.3762626647950f);
  float fx = floorf(fmaf(xc, kLog2e, 0.5f));
  float tmp = __fmul_rn(kC1, fx);
  float z = __fmul_rn(kC2, fx);
  float r = __fsub_rn(xc, tmp);
  r = __fsub_rn(r, z);
  float r2 = __fmul_rn(r, r);
  float y = fmaf(r, kP0, kP1);
  y = fmaf(y, r, kP2);
  y = fmaf(y, r, kP3);
  y = fmaf(y, r, kP4);
  y = fmaf(y, r, kP5);
  y = fmaf(y, r2, r);
  y = __fadd_rn(y, 1.0f);
  int n = (int)fx;
  float two_n = __int_as_float((n + 127) << 23);
  return fmaxf(__fmul_rn(y, two_n), x);
}

// ---- IoU(a,b) > 0.7f with the reference's exact f32 op sequence (symmetric) ----
__device__ __forceinline__ bool suppress(float4 a, float4 b) {
  float aa = __fmul_rn(__fsub_rn(a.z, a.x), __fsub_rn(a.w, a.y));
  float ab = __fmul_rn(__fsub_rn(b.z, b.x), __fsub_rn(b.w, b.y));
  float lty = fmaxf(a.x, b.x);
  float ltx = fmaxf(a.y, b.y);
  float rby = fminf(a.z, b.z);
  float rbx = fminf(a.w, b.w);
  float why = fmaxf(__fsub_rn(rby, lty), 0.0f);
  float whx = fmaxf(__fsub_rn(rbx, ltx), 0.0f);
  float inter = __fmul_rn(why, whx);
  float uni = __fsub_rn(__fadd_rn(aa, ab), inter);
  float iou = inter / fmaxf(uni, 1e-9f);
  return iou > 0.7f;
}

__device__ __forceinline__ float4 shfl4(float4 v, int lane) {
  float4 r;
  r.x = __shfl(v.x, lane);
  r.y = __shfl(v.y, lane);
  r.z = __shfl(v.z, lane);
  r.w = __shfl(v.w, lane);
  return r;
}

__device__ __forceinline__ u64 makekey(u32 sbits, u32 lvl, u32 idx) {
  // ascending key == (score desc, level asc, index asc); total order (idx unique)
  return ((u64)(0x7FFFFFFFu - sbits) << 20) | ((u64)lvl << 18) | (u64)idx;
}

// 1) softmax score + hi16 histogram per level
__global__ void k_score_hist(const float2* __restrict__ logits, const int* __restrict__ levels,
                             u32* __restrict__ sbits, u32* __restrict__ hist, int n) {
  int i = blockIdx.x * blockDim.x + threadIdx.x;
  if (i >= n) return;
  float2 lg = logits[i];
  float m = fmaxf(lg.x, lg.y);
  float e0 = xla_expf(__fsub_rn(lg.x, m));
  float e1 = xla_expf(__fsub_rn(lg.y, m));
  float s = e1 / __fadd_rn(e0, e1);   // IEEE div
  u32 b = __float_as_uint(s);
  sbits[i] = b;
  int lv = levels[i];
  atomicAdd(&hist[lv * 65536 + (int)(b >> 16)], 1u);
}

// 2) per-level descending scan of hi16 histogram -> bin containing rank NPRE
__global__ void k_scan_hi(const u32* __restrict__ hist, u32* __restrict__ ctrl) {
  int lvl = blockIdx.x;
  int tid = threadIdx.x;
  const u32* h = hist + lvl * 65536;
  __shared__ u32 part[256];
  u32 s = 0;
  int base = tid * 256;
  for (int b = 0; b < 256; ++b) s += h[base + b];
  part[tid] = s;
  __syncthreads();
  if (tid == 0) {
    const u32 target = NPRE;
    u32 cum = 0, before = 0; int seg = -1;
    for (int t = 255; t >= 0; --t) {
      if (seg < 0 && cum + part[t] >= target) { seg = t; before = cum; }
      cum += part[t];
    }
    if (cum < target) {           // deficient level: select everything (score>0)
      ctrl[C_P + lvl] = 0xFFFFFFFFu;
      ctrl[C_T + lvl] = 0u;
      ctrl[C_NEED + lvl] = 0u;
    } else {
      u32 c = before; u32 bin = 0;
      for (int b = seg * 256 + 255; b >= seg * 256; --b) {
        u32 hb = h[b];
        if (c + hb >= target) { bin = (u32)b; break; }
        c += hb;
      }
      ctrl[C_P + lvl] = bin;
      ctrl[C_RANK + lvl] = target - c;   // >=1 elements needed inside bin
    }
  }
}

// 3) lo16 histogram restricted to hi16 == P
__global__ void k_hist_lo(const u32* __restrict__ sbits, const int* __restrict__ levels,
                          const u32* __restrict__ ctrl, u32* __restrict__ hist, int n) {
  int i = blockIdx.x * blockDim.x + threadIdx.x;
  if (i >= n) return;
  u32 b = sbits[i];
  int lv = levels[i];
  if ((b >> 16) == ctrl[C_P + lv])
    atomicAdd(&hist[lv * 65536 + (int)(b & 0xFFFFu)], 1u);
}

// 4) per-level descending scan of lo16 -> exact 32-bit threshold T and tie need
__global__ void k_scan_lo(const u32* __restrict__ hist, u32* __restrict__ ctrl) {
  int lvl = blockIdx.x;
  u32 P = ctrl[C_P + lvl];
  if (P == 0xFFFFFFFFu) return;   // uniform: deficient already handled
  int tid = threadIdx.x;
  const u32* h = hist + lvl * 65536;
  __shared__ u32 part[256];
  u32 s = 0;
  int base = tid * 256;
  for (int b = 0; b < 256; ++b) s += h[base + b];
  part[tid] = s;
  __syncthreads();
  if (tid == 0) {
    u32 target = ctrl[C_RANK + lvl];
    u32 cum = 0, before = 0; int seg = -1;
    for (int t = 255; t >= 0; --t) {
      if (seg < 0 && cum + part[t] >= target) { seg = t; before = cum; }
      cum += part[t];
    }
    u32 c = before; u32 bin = 0;
    for (int b = seg * 256 + 255; b >= seg * 256; --b) {
      u32 hb = h[b];
      if (c + hb >= target) { bin = (u32)b; break; }
      c += hb;
    }
    ctrl[C_T + lvl] = (P << 16) | bin;
    ctrl[C_NEED + lvl] = target - c;    // take this many smallest-index among ==T
  }
}

// 5) compact: strictly-above-threshold -> cand keys; ==T -> tie buffer; sep max
//    (no early return: all 64 lanes stay active for the wave-reduced sepmax)
__global__ void k_compact(const u32* __restrict__ sbits, const int* __restrict__ levels,
                          const float4* __restrict__ rois, u32* __restrict__ ctrl,
                          u64* __restrict__ cand, u32* __restrict__ tie, int n) {
  int i = blockIdx.x * blockDim.x + threadIdx.x;
  bool act = i < n;
  u32 b = 0; int lv = 0; u32 T = 0xFFFFFFFFu;
  if (act) {
    b = sbits[i];
    lv = levels[i];
    T = ctrl[C_T + lv];
  }
  u32 mx = 0;
  if (act && b > T) {
    u32 p = atomicAdd(&ctrl[C_CANDCNT], 1u);
    if (p < (u32)KPAD) cand[p] = makekey(b, (u32)lv, (u32)i);
    float4 r = rois[i];
    mx = max(max(fmap(r.x), fmap(r.y)), max(fmap(r.z), fmap(r.w)));
  } else if (act && b == T) {
    u32 t = atomicAdd(&ctrl[C_TIECNT + lv], 1u);
    if (t < TIE_CAP) tie[lv * TIE_CAP + t] = (u32)i;
  }
  // wave-reduce the sepmax candidate, one atomic per wave
  for (int o = 32; o; o >>= 1) {
    u32 v = (u32)__shfl_xor((int)mx, o);
    mx = max(mx, v);
  }
  if ((threadIdx.x & 63) == 0 && mx)
    atomicMax(&ctrl[C_SEPMAX], mx);
}

// 6) resolve threshold ties: smallest indices first (top_k is stable)
//    adaptive bitonic over next_pow2(n) instead of fixed 4096
__global__ void k_ties(const float4* __restrict__ rois, u32* __restrict__ ctrl,
                       u64* __restrict__ cand, const u32* __restrict__ tie) {
  int lvl = blockIdx.x;
  int tid = threadIdx.x;
  u32 need = ctrl[C_NEED + lvl];
  if (need == 0) return;            // uniform per block
  u32 n = min(ctrl[C_TIECNT + lvl], (u32)TIE_CAP);
  u32 m = 2; while (m < n) m <<= 1; // next pow2 >= n (>=2)
  __shared__ u32 buf[TIE_CAP];
  for (u32 t = tid; t < m; t += 256)
    buf[t] = (t < n) ? tie[lvl * TIE_CAP + t] : 0xFFFFFFFFu;
  __syncthreads();
  for (u32 k = 2; k <= m; k <<= 1) {
    for (u32 j = k >> 1; j > 0; j >>= 1) {
      for (u32 p = tid; p < m; p += 256) {
        u32 q = p ^ j;
        if (q > p) {
          u32 a = buf[p], b = buf[q];
          bool desc = (p & k) != 0;
          if (desc ? (a < b) : (a > b)) { buf[p] = b; buf[q] = a; }
        }
      }
      __syncthreads();
    }
  }
  __shared__ u32 basep;
  if (tid == 0) basep = atomicAdd(&ctrl[C_CANDCNT], need);
  __syncthreads();
  u32 T = ctrl[C_T + lvl];
  u32 mx = 0;
  for (u32 t = tid; t < need; t += 256) {
    u32 idx = buf[t];
    if (basep + t < (u32)KPAD) cand[basep + t] = makekey(T, (u32)lvl, idx);
    float4 r = rois[idx];
    mx = max(mx, max(max(fmap(r.x), fmap(r.y)), max(fmap(r.z), fmap(r.w))));
  }
  if (mx) atomicMax(&ctrl[C_SEPMAX], mx);
}

// 7) bitonic sort of 8192 u64 keys in LDS -> global NMS order (total order)
__global__ __launch_bounds__(1024) void k_sort(u64* __restrict__ cand, const u32* __restrict__ ctrl) {
  __shared__ u64 a[KPAD];
  int tid = threadIdx.x;
  u32 total = min(ctrl[C_CANDCNT], (u32)KPAD);
  for (int p = tid; p < KPAD; p += 1024) a[p] = (p < (int)total) ? cand[p] : ~0ull;
  __syncthreads();
  for (u32 k = 2; k <= KPAD; k <<= 1) {
    for (u32 j = k >> 1; j > 0; j >>= 1) {
      for (u32 p = tid; p < (u32)KPAD; p += 1024) {
        u32 q = p ^ j;
        if (q > p) {
          u64 x = a[p], y = a[q];
          bool desc = (p & k) != 0;
          if (desc ? (x < y) : (x > y)) { a[p] = y; a[q] = x; }
        }
      }
      __syncthreads();
    }
  }
  for (int p = tid; p < KPAD; p += 1024) cand[p] = a[p];
}

// 8) level-shifted boxes in sorted order (exact: sh = fl(lvl*sep); coord+sh)
__global__ void k_shift(const u64* __restrict__ cand, const float4* __restrict__ rois,
                        const u32* __restrict__ ctrl, float4* __restrict__ shifted) {
  int k = blockIdx.x * blockDim.x + threadIdx.x;
  if (k >= KPAD) return;
  u32 total = min(ctrl[C_CANDCNT], (u32)KPAD);
  float sep = __fadd_rn(funmap(ctrl[C_SEPMAX]), 1.0f);
  float4 o = make_float4(0.f, 0.f, 0.f, 0.f);
  if (k < (int)total) {
    u64 a = cand[k];
    u32 idx = (u32)(a & 0x3FFFFu);
    u32 lvl = (u32)((a >> 18) & 3u);
    float4 r = rois[idx];
    float sh = __fmul_rn((float)lvl, sep);
    o.x = __fadd_rn(r.x, sh);
    o.y = __fadd_rn(r.y, sh);
    o.z = __fadd_rn(r.z, sh);
    o.w = __fadd_rn(r.w, sh);
  }
  shifted[k] = o;
}

// 9a) build suppression bitmask: mask[i][cb] bit j = (iou(i, cb*64+j)>0.7 && cb*64+j > i)
__global__ __launch_bounds__(64) void k_build(const float4* __restrict__ shifted,
                                              u64* __restrict__ mask) {
  u32 cb = blockIdx.x, rb = blockIdx.y;
  if (cb < rb) return;                 // lower triangle never read meaningfully
  int t = threadIdx.x;
  __shared__ float4 cbox[64];
  cbox[t] = shifted[cb * 64 + t];
  u32 i = rb * 64 + t;
  float4 bi = shifted[i];
  __syncthreads();
  u64 bits = 0;
  for (int j = 0; j < 64; ++j) {
    u32 jg = cb * 64 + j;
    if (jg > i && suppress(bi, cbox[j])) bits |= (1ull << j);
  }
  mask[(u64)i * NCHUNK + cb] = bits;
}

// 9b) pipelined single-wave greedy scan.
//     Lane t owns removed words 2t,2t+1. Per chunk c:
//       - remc = shfl(removed word c) | urgent (recomputed word-c bits from chunk c-1's kept)
//       - resolve intra-chunk greedy via shfl of lane-resident diag words
//       - issue full-row loads for kept rows (consumed at END of NEXT chunk -> latency hidden)
//       - recompute urgent word c+1 bits from boxes (identical suppress() => bit-exact vs mask)
//       - consume previous chunk's deferred loads into removed regs
__global__ __launch_bounds__(64) void k_scan(const u64* __restrict__ mask,
                                             const float4* __restrict__ shifted,
                                             u32* __restrict__ ctrl,
                                             u32* __restrict__ keptpos) {
  int t = threadIdx.x;
  u32 total = min(ctrl[C_CANDCNT], (u32)KPAD);
  u32 chunks = (total + 63) >> 6;
  if (chunks == 0) { if (t == 0) ctrl[C_KEPTCNT] = 0; return; }
  u64 r0 = 0, r1 = 0;
  u32 kept = 0;
  u64 urgent = 0;
  u64 intra = mask[(u64)t * NCHUNK];        // diag word, chunk 0
  float4 bc = shifted[t];                   // this-chunk boxes, chunk 0
  ulonglong2 zz; zz.x = 0; zz.y = 0;
  ulonglong2 gA = zz, gB = zz, gC = zz, gD = zz, gE = zz, gF = zz, gG = zz, gH = zz;
  for (u32 c = 0; c < chunks; ++c) {
    u64 myintra = intra;
    float4 mybc = bc;
    u64 rr = (c & 1) ? r1 : r0;
    u64 remc = (u64)__shfl((long long)rr, (int)(c >> 1)) | urgent;
    u64 w = ~remc;
    u32 rem2 = total - c * 64;
    if (rem2 < 64) w &= ((1ull << rem2) - 1ull);
    u32 cn = c + 1;
    if (cn < chunks) intra = mask[((u64)cn * 64 + t) * NCHUNK + cn];
    float4 bn = shifted[min(cn * 64 + (u32)t, (u32)(KPAD - 1))];  // next-chunk boxes (zero-padded)
    // ---- intra-chunk greedy resolution (uniform across lanes) ----
    u64 keptbits = 0;
    while (w && kept < NPOST) {
      u32 s = (u32)__builtin_ctzll(w);
      keptbits |= (1ull << s);
      if (t == 0) keptpos[kept] = c * 64 + s;
      ++kept;
      u64 row = (u64)__shfl((long long)myintra, (int)s);
      w &= ~row;
      w &= ~(1ull << s);
    }
    // ---- issue deferred full-row loads for first <=8 kept rows (dup-filled) ----
    const u64* bp = mask + (u64)c * 64 * NCHUNK + (u64)(2 * t);
    ulonglong2 nA = zz, nB = zz, nC = zz, nD = zz, nE = zz, nF = zz, nG = zz, nH = zz;
    u64 kb = keptbits;
    if (kb) {
      u32 sA = (u32)__builtin_ctzll(kb); kb &= kb - 1;
      u32 sB = sA, sC = sA, sD = sA, sE = sA, sF = sA, sG = sA, sH = sA;
      if (kb) { sB = (u32)__builtin_ctzll(kb); kb &= kb - 1;
      if (kb) { sC = (u32)__builtin_ctzll(kb); kb &= kb - 1;
      if (kb) { sD = (u32)__builtin_ctzll(kb); kb &= kb - 1;
      if (kb) { sE = (u32)__builtin_ctzll(kb); kb &= kb - 1;
      if (kb) { sF = (u32)__builtin_ctzll(kb); kb &= kb - 1;
      if (kb) { sG = (u32)__builtin_ctzll(kb); kb &= kb - 1;
      if (kb) { sH = (u32)__builtin_ctzll(kb); kb &= kb - 1; }}}}}}}
      nA = *(const ulonglong2*)(bp + (u64)sA * NCHUNK);
      nB = *(const ulonglong2*)(bp + (u64)sB * NCHUNK);
      nC = *(const ulonglong2*)(bp + (u64)sC * NCHUNK);
      nD = *(const ulonglong2*)(bp + (u64)sD * NCHUNK);
      nE = *(const ulonglong2*)(bp + (u64)sE * NCHUNK);
      nF = *(const ulonglong2*)(bp + (u64)sF * NCHUNK);
      nG = *(const ulonglong2*)(bp + (u64)sG * NCHUNK);
      nH = *(const ulonglong2*)(bp + (u64)sH * NCHUNK);
      // rows beyond 8: blocking batches (rare)
      while (kb) {
        u32 tA = (u32)__builtin_ctzll(kb); kb &= kb - 1;
        u32 tB = tA, tC = tA, tD = tA, tE = tA, tF = tA, tG = tA, tH = tA;
        if (kb) { tB = (u32)__builtin_ctzll(kb); kb &= kb - 1;
        if (kb) { tC = (u32)__builtin_ctzll(kb); kb &= kb - 1;
        if (kb) { tD = (u32)__builtin_ctzll(kb); kb &= kb - 1;
        if (kb) { tE = (u32)__builtin_ctzll(kb); kb &= kb - 1;
        if (kb) { tF = (u32)__builtin_ctzll(kb); kb &= kb - 1;
        if (kb) { tG = (u32)__builtin_ctzll(kb); kb &= kb - 1;
        if (kb) { tH = (u32)__builtin_ctzll(kb); kb &= kb - 1; }}}}}}}
        ulonglong2 hA = *(const ulonglong2*)(bp + (u64)tA * NCHUNK);
        ulonglong2 hB = *(const ulonglong2*)(bp + (u64)tB * NCHUNK);
        ulonglong2 hC = *(const ulonglong2*)(bp + (u64)tC * NCHUNK);
        ulonglong2 hD = *(const ulonglong2*)(bp + (u64)tD * NCHUNK);
        ulonglong2 hE = *(const ulonglong2*)(bp + (u64)tE * NCHUNK);
        ulonglong2 hF = *(const ulonglong2*)(bp + (u64)tF * NCHUNK);
        ulonglong2 hG = *(const ulonglong2*)(bp + (u64)tG * NCHUNK);
        ulonglong2 hH = *(const ulonglong2*)(bp + (u64)tH * NCHUNK);
        r0 |= hA.x | hB.x | hC.x | hD.x | hE.x | hF.x | hG.x | hH.x;
        r1 |= hA.y | hB.y | hC.y | hD.y | hE.y | hF.y | hG.y | hH.y;
      }
    }
    // ---- urgent word c+1: recompute kept-row bits from boxes (bit-exact) ----
    u64 nxu = 0;
    if (cn < chunks && keptbits) {
      bool any = false;
      u64 kb2 = keptbits;
      while (kb2) {
        u32 s = (u32)__builtin_ctzll(kb2); kb2 &= kb2 - 1;
        float4 bs = shfl4(mybc, (int)s);
        any = any || suppress(bs, bn);
      }
      nxu = __ballot(any);
    }
    // ---- consume previous chunk's deferred loads (latency already hidden) ----
    r0 |= gA.x | gB.x | gC.x | gD.x | gE.x | gF.x | gG.x | gH.x;
    r1 |= gA.y | gB.y | gC.y | gD.y | gE.y | gF.y | gG.y | gH.y;
    gA = nA; gB = nB; gC = nC; gD = nD; gE = nE; gF = nF; gG = nG; gH = nH;
    urgent = nxu;
    bc = bn;
    if (kept >= NPOST) break;
  }
  if (t == 0) ctrl[C_KEPTCNT] = kept;
}

// 9-fallback) sequential greedy NMS (used only if ws too small for the mask)
__global__ __launch_bounds__(1024) void k_nms(const float4* __restrict__ shifted,
                                              u32* __restrict__ ctrl, u32* __restrict__ keptpos) {
  __shared__ float4 kbox[NPOST];
  __shared__ u32 wflag[16];
  int tid = threadIdx.x;
  u32 total = min(ctrl[C_CANDCNT], (u32)KPAD);
  int n = 0;
  for (u32 i = 0; i < total; ++i) {
    float4 cur = shifted[i];
    bool sup = false;
    if (tid < n) sup = suppress(kbox[tid], cur);
    int any = __any(sup);
    if ((tid & 63) == 0) wflag[tid >> 6] = (u32)any;
    __syncthreads();
    u32 f = 0;
#pragma unroll
    for (int w = 0; w < 16; ++w) f |= wflag[w];
    if (!f) {
      if (tid == 0) { kbox[n] = cur; keptpos[n] = i; }
      ++n;
    }
    __syncthreads();
    if (n >= NPOST) break;
  }
  if (tid == 0) ctrl[C_KEPTCNT] = (u32)n;
}

// 10) gather outputs; small-box filter; write everything as f32
__global__ void k_out(const u64* __restrict__ cand, const u32* __restrict__ keptpos,
                      const u32* __restrict__ ctrl, const float2* __restrict__ logits,
                      const float4* __restrict__ rois, float* __restrict__ out) {
  int r = blockIdx.x * blockDim.x + threadIdx.x;
  if (r >= NPOST) return;
  u32 kn = ctrl[C_KEPTCNT];
  float l0 = 0.f, l1 = 0.f, r0 = 0.f, r1 = 0.f, r2 = 0.f, r3 = 0.f;
  float lvf = -1.0f, vf = 0.0f;
  if (r < (int)kn) {
    u32 pos = keptpos[r];
    u64 a = cand[pos];
    u32 idx = (u32)(a & 0x3FFFFu);
    u32 lvl = (u32)((a >> 18) & 3u);
    float4 rb = rois[idx];
    float hs = __fsub_rn(rb.z, rb.x);
    float wsz = __fsub_rn(rb.w, rb.y);
    if (hs >= 1.0f && wsz >= 1.0f) {
      float2 lg = logits[idx];
      l0 = lg.x; l1 = lg.y;
      r0 = rb.x; r1 = rb.y; r2 = rb.z; r3 = rb.w;
      lvf = (float)lvl; vf = 1.0f;
    }
  }
  out[2 * r] = l0;
  out[2 * r + 1] = l1;
  out[2 * NPOST + 4 * r + 0] = r0;
  out[2 * NPOST + 4 * r + 1] = r1;
  out[2 * NPOST + 4 * r + 2] = r2;
  out[2 * NPOST + 4 * r + 3] = r3;
  out[6 * NPOST + r] = lvf;
  out[7 * NPOST + r] = vf;
}

extern "C" void kernel_launch(void* const* d_in, const int* in_sizes, int n_in,
                              void* d_out, int out_size, void* d_ws, size_t ws_size,
                              hipStream_t stream) {
  const float* logits = (const float*)d_in[0];
  const float* rois = (const float*)d_in[1];
  const int* levels = (const int*)d_in[2];
  int N = in_sizes[2];

  char* ws = (char*)d_ws;
  u32* sbits = (u32*)(ws + OFF_SBITS);
  u32* hist = (u32*)(ws + OFF_HIST);
  u32* ctrl = (u32*)(ws + OFF_CTRL);
  u32* tie = (u32*)(ws + OFF_TIE);
  u64* cand = (u64*)(ws + OFF_CAND);
  float4* shifted = (float4*)(ws + OFF_SHIFT);
  u32* keptpos = (u32*)(ws + OFF_KEPT);
  u64* mask = (u64*)(ws + OFF_MASK);

  int use_mask = ws_size >= WS_NEED;
  // hist2 lives in the (not-yet-used) mask region when available; falls back to
  // reusing hist (with a mid-pipeline clear) otherwise.
  u32* hist2 = use_mask ? (u32*)(ws + OFF_MASK) : hist;

  hipMemsetAsync(ctrl, 0, 4096, stream);
  hipMemsetAsync(hist, 0, NLVL * 65536 * sizeof(u32), stream);
  if (use_mask)
    hipMemsetAsync(hist2, 0, NLVL * 65536 * sizeof(u32), stream);

  int nb = (N + 255) / 256;
  k_score_hist<<<nb, 256, 0, stream>>>((const float2*)logits, levels, sbits, hist, N);
  k_scan_hi<<<NLVL, 256, 0, stream>>>(hist, ctrl);
  if (!use_mask)
    hipMemsetAsync(hist, 0, NLVL * 65536 * sizeof(u32), stream);
  k_hist_lo<<<nb, 256, 0, stream>>>(sbits, levels, ctrl, hist2, N);
  k_scan_lo<<<NLVL, 256, 0, stream>>>(hist2, ctrl);
  k_compact<<<nb, 256, 0, stream>>>(sbits, levels, (const float4*)rois, ctrl, cand, tie, N);
  k_ties<<<NLVL, 256, 0, stream>>>((const float4*)rois, ctrl, cand, tie);
  k_sort<<<1, 1024, 0, stream>>>(cand, ctrl);
  k_shift<<<(KPAD + 255) / 256, 256, 0, stream>>>(cand, (const float4*)rois, ctrl, shifted);
  if (use_mask) {
    dim3 g(KPAD / 64, KPAD / 64);   // rows/cols >= total are zero boxes
    k_build<<<g, 64, 0, stream>>>((const float4*)shifted, mask);
    k_scan<<<1, 64, 0, stream>>>(mask, (const float4*)shifted, ctrl, keptpos);
  } else {
    k_nms<<<1, 1024, 0, stream>>>(shifted, ctrl, keptpos);
  }
  k_out<<<(NPOST + 255) / 256, 256, 0, stream>>>(cand, keptpos, ctrl, (const float2*)logits,
                                                 (const float4*)rois, (float*)d_out);
}

// Round 5
// 548.247 us; speedup vs baseline: 1.3191x; 1.3191x over previous
//
#include <hip/hip_runtime.h>
#include <stdint.h>

typedef uint32_t u32;
typedef uint64_t u64;

#define NLVL 4
#define NPRE 2000
#define NPOST 1000
#define KPAD 8192
#define TIE_CAP 4096
#define NCHUNK 128          // row stride in u64 words (125 used, padded to 128)

// ws layout (bytes)
#define OFF_SBITS 0u                        // 1 MB  (250K u32)
#define OFF_HIST  (1u<<20)                  // 1 MB  (4*64K u32)  [memset with ctrl]
#define OFF_CTRL  (2u<<20)                  // 4 KB  (contiguous after hist)
#define OFF_KEPT  ((2u<<20) + (8u<<10))     // 4 KB  (fallback path only)
#define OFF_TIE   ((2u<<20) + (64u<<10))    // 128 KB u64[4][4096]
#define OFF_CAND  ((2u<<20) + (192u<<10))   // 64 KB u64[8192]
#define OFF_SHIFT ((2u<<20) + (256u<<10))   // 128 KB float4[8192]
#define OFF_DIAGT ((2u<<20) + (384u<<10))   // 64 KB u64[8192]
#define OFF_SUPT  ((2u<<20) + (448u<<10))   // 64 KB u64[8192]
#define OFF_MASK  (3u<<20)                  // 8 MB (8192 rows * 128 u64)
#define WS_NEED   ((size_t)(3u<<20) + (size_t)KPAD * NCHUNK * 8u)

// ctrl word indices
#define C_CANDCNT 0
#define C_KEPTCNT 1
#define C_SEPMAX  2
#define C_P       4   // +lvl  (0xFFFFFFFF = deficient level -> take all)
#define C_RANK    8   // +lvl  (elements needed from bin P)
#define C_TIECNT  12  // +lvl

// ---- monotone float<->u32 map for atomic max over floats ----
__device__ __forceinline__ u32 fmap(float f) {
  u32 u = __float_as_uint(f);
  return (u & 0x80000000u) ? ~u : (u | 0x80000000u);
}
__device__ __forceinline__ float funmap(u32 u) {
  u = (u & 0x80000000u) ? (u & 0x7FFFFFFFu) : ~u;
  return __uint_as_float(u);
}

// ---- replicate XLA-CPU GenerateVF32Exp (Cephes/Eigen-3.3 style) ----
__device__ __forceinline__ float xla_expf(float x) {
  const float kLog2e = 1.44269504088896341f;
  const float kC1 = 0.693359375f;
  const float kC2 = -2.12194440e-4f;
  const float kP0 = 1.9875691500e-4f;
  const float kP1 = 1.3981999507e-3f;
  const float kP2 = 8.3334519073e-3f;
  const float kP3 = 4.1665795894e-2f;
  const float kP4 = 1.6666665459e-1f;
  const float kP5 = 5.0000001201e-1f;
  float xc = fminf(fmaxf(x, -88.3762626647949f), 88.3762626647950f);
  float fx = floorf(fmaf(xc, kLog2e, 0.5f));
  float tmp = __fmul_rn(kC1, fx);
  float z = __fmul_rn(kC2, fx);
  float r = __fsub_rn(xc, tmp);
  r = __fsub_rn(r, z);
  float r2 = __fmul_rn(r, r);
  float y = fmaf(r, kP0, kP1);
  y = fmaf(y, r, kP2);
  y = fmaf(y, r, kP3);
  y = fmaf(y, r, kP4);
  y = fmaf(y, r, kP5);
  y = fmaf(y, r2, r);
  y = __fadd_rn(y, 1.0f);
  int n = (int)fx;
  float two_n = __int_as_float((n + 127) << 23);
  return fmaxf(__fmul_rn(y, two_n), x);
}

// ---- IoU(a,b) > 0.7f, reference's exact f32 op sequence; exactly symmetric ----
__device__ __forceinline__ bool suppress(float4 a, float4 b) {
  float aa = __fmul_rn(__fsub_rn(a.z, a.x), __fsub_rn(a.w, a.y));
  float ab = __fmul_rn(__fsub_rn(b.z, b.x), __fsub_rn(b.w, b.y));
  float lty = fmaxf(a.x, b.x);
  float ltx = fmaxf(a.y, b.y);
  float rby = fminf(a.z, b.z);
  float rbx = fminf(a.w, b.w);
  float why = fmaxf(__fsub_rn(rby, lty), 0.0f);
  float whx = fmaxf(__fsub_rn(rbx, ltx), 0.0f);
  float inter = __fmul_rn(why, whx);
  float uni = __fsub_rn(__fadd_rn(aa, ab), inter);
  float iou = inter / fmaxf(uni, 1e-9f);
  return iou > 0.7f;
}

__device__ __forceinline__ u64 makekey(u32 sbits, u32 lvl, u32 idx) {
  // ascending key == (score desc, level asc, index asc); total order (idx unique)
  return ((u64)(0x7FFFFFFFu - sbits) << 20) | ((u64)lvl << 18) | (u64)idx;
}

// 1) softmax score + hi16 histogram per level
__global__ void k_score_hist(const float2* __restrict__ logits, const int* __restrict__ levels,
                             u32* __restrict__ sbits, u32* __restrict__ hist, int n) {
  int i = blockIdx.x * blockDim.x + threadIdx.x;
  if (i >= n) return;
  float2 lg = logits[i];
  float m = fmaxf(lg.x, lg.y);
  float e0 = xla_expf(__fsub_rn(lg.x, m));
  float e1 = xla_expf(__fsub_rn(lg.y, m));
  float s = e1 / __fadd_rn(e0, e1);   // IEEE div
  u32 b = __float_as_uint(s);
  sbits[i] = b;
  int lv = levels[i];
  atomicAdd(&hist[lv * 65536 + (int)(b >> 16)], 1u);
}

// 2) per-level descending scan of hi16 histogram -> bin P containing rank NPRE,
//    and RANK = #elements needed from inside bin P
__global__ void k_scan_hi(const u32* __restrict__ hist, u32* __restrict__ ctrl) {
  int lvl = blockIdx.x;
  int tid = threadIdx.x;
  const u32* h = hist + lvl * 65536;
  __shared__ u32 part[256];
  u32 s = 0;
  int base = tid * 256;
  for (int b = 0; b < 256; ++b) s += h[base + b];
  part[tid] = s;
  __syncthreads();
  if (tid == 0) {
    const u32 target = NPRE;
    u32 cum = 0, before = 0; int seg = -1;
    for (int t = 255; t >= 0; --t) {
      if (seg < 0 && cum + part[t] >= target) { seg = t; before = cum; }
      cum += part[t];
    }
    if (cum < target) {           // deficient level: take everything at the level
      ctrl[C_P + lvl] = 0xFFFFFFFFu;
      ctrl[C_RANK + lvl] = 0u;
    } else {
      u32 c = before; u32 bin = 0;
      for (int b = seg * 256 + 255; b >= seg * 256; --b) {
        u32 hb = h[b];
        if (c + hb >= target) { bin = (u32)b; break; }
        c += hb;
      }
      ctrl[C_P + lvl] = bin;
      ctrl[C_RANK + lvl] = target - c;   // >=1 needed inside bin P
    }
  }
}

// 3) compact: hi16 above bin P -> cand keys; hi16 == P -> tie keys; sep max
//    (no early return: all 64 lanes stay active for the wave-reduced sepmax)
__global__ void k_compact(const u32* __restrict__ sbits, const int* __restrict__ levels,
                          const float4* __restrict__ rois, u32* __restrict__ ctrl,
                          u64* __restrict__ cand, u64* __restrict__ tie, int n) {
  int i = blockIdx.x * blockDim.x + threadIdx.x;
  bool act = i < n;
  u32 b = 0; int lv = 0; u32 P = 0xFFFFFFFEu;
  if (act) {
    b = sbits[i];
    lv = levels[i];
    P = ctrl[C_P + lv];
  }
  u32 mx = 0;
  if (act && (P == 0xFFFFFFFFu || (b >> 16) > P)) {
    u32 p = atomicAdd(&ctrl[C_CANDCNT], 1u);
    if (p < (u32)KPAD) cand[p] = makekey(b, (u32)lv, (u32)i);
    float4 r = rois[i];
    mx = max(max(fmap(r.x), fmap(r.y)), max(fmap(r.z), fmap(r.w)));
  } else if (act && (b >> 16) == P) {
    u32 t = atomicAdd(&ctrl[C_TIECNT + lv], 1u);
    if (t < TIE_CAP) tie[lv * TIE_CAP + t] = makekey(b, (u32)lv, (u32)i);
  }
  for (int o = 32; o; o >>= 1) {
    u32 v = (u32)__shfl_xor((int)mx, o);
    mx = max(mx, v);
  }
  if ((threadIdx.x & 63) == 0 && mx)
    atomicMax(&ctrl[C_SEPMAX], mx);
}

// 4) bin-P resolution: sort bin members by total-order key, take first RANK
__global__ void k_ties(const float4* __restrict__ rois, u32* __restrict__ ctrl,
                       u64* __restrict__ cand, const u64* __restrict__ tie) {
  int lvl = blockIdx.x;
  int tid = threadIdx.x;
  if (ctrl[C_P + lvl] == 0xFFFFFFFFu) return;   // deficient (uniform per block)
  u32 need = ctrl[C_RANK + lvl];
  if (need == 0) return;
  u32 n = min(ctrl[C_TIECNT + lvl], (u32)TIE_CAP);
  u32 m = 2; while (m < n) m <<= 1;
  __shared__ u64 buf[TIE_CAP];
  for (u32 t = tid; t < m; t += 256)
    buf[t] = (t < n) ? tie[lvl * TIE_CAP + t] : ~0ull;
  __syncthreads();
  for (u32 k = 2; k <= m; k <<= 1) {
    for (u32 j = k >> 1; j > 0; j >>= 1) {
      for (u32 p = tid; p < m; p += 256) {
        u32 q = p ^ j;
        if (q > p) {
          u64 a = buf[p], b = buf[q];
          bool desc = (p & k) != 0;
          if (desc ? (a < b) : (a > b)) { buf[p] = b; buf[q] = a; }
        }
      }
      __syncthreads();
    }
  }
  u32 cnt = min(need, n);
  __shared__ u32 basep;
  if (tid == 0) basep = atomicAdd(&ctrl[C_CANDCNT], cnt);
  __syncthreads();
  u32 mx = 0;
  for (u32 t = tid; t < cnt; t += 256) {
    u64 key = buf[t];
    if (basep + t < (u32)KPAD) cand[basep + t] = key;
    u32 idx = (u32)(key & 0x3FFFFu);
    float4 r = rois[idx];
    mx = max(mx, max(max(fmap(r.x), fmap(r.y)), max(fmap(r.z), fmap(r.w))));
  }
  if (mx) atomicMax(&ctrl[C_SEPMAX], mx);
}

// 5) bitonic sort of 8192 u64 keys in LDS -> global NMS order; fused shift-write
__global__ __launch_bounds__(1024) void k_sort(u64* __restrict__ cand, const u32* __restrict__ ctrl,
                                               const float4* __restrict__ rois,
                                               float4* __restrict__ shifted) {
  __shared__ u64 a[KPAD];
  int tid = threadIdx.x;
  u32 total = min(ctrl[C_CANDCNT], (u32)KPAD);
  for (int p = tid; p < KPAD; p += 1024) a[p] = (p < (int)total) ? cand[p] : ~0ull;
  __syncthreads();
  for (u32 k = 2; k <= KPAD; k <<= 1) {
    for (u32 j = k >> 1; j > 0; j >>= 1) {
      for (u32 p = tid; p < (u32)KPAD; p += 1024) {
        u32 q = p ^ j;
        if (q > p) {
          u64 x = a[p], y = a[q];
          bool desc = (p & k) != 0;
          if (desc ? (x < y) : (x > y)) { a[p] = y; a[q] = x; }
        }
      }
      __syncthreads();
    }
  }
  float sep = __fadd_rn(funmap(ctrl[C_SEPMAX]), 1.0f);
  for (int p = tid; p < KPAD; p += 1024) {
    u64 key = a[p];
    cand[p] = key;
    float4 o = make_float4(0.f, 0.f, 0.f, 0.f);
    if (p < (int)total) {
      u32 idx = (u32)(key & 0x3FFFFu);
      u32 lvl = (u32)((key >> 18) & 3u);
      float4 r = rois[idx];
      float sh = __fmul_rn((float)lvl, sep);
      o.x = __fadd_rn(r.x, sh);
      o.y = __fadd_rn(r.y, sh);
      o.z = __fadd_rn(r.z, sh);
      o.w = __fadd_rn(r.w, sh);
    }
    shifted[p] = o;
  }
}

// 6) build suppression bitmask rows + transposed diag/super-diag tiles
//    mask[i][cb] bit j = iou(i, cb*64+j)>0.7 && cb*64+j>i
//    diagT[c*64+t] bit j = j<t && iou>0.7 (within chunk c)
//    superT[c*64+t] bit s = iou(box_{c,s}, box_{c+1,t})>0.7
__global__ __launch_bounds__(64) void k_build(const float4* __restrict__ shifted,
                                              u64* __restrict__ mask,
                                              u64* __restrict__ diagT,
                                              u64* __restrict__ superT) {
  u32 cb = blockIdx.x, rb = blockIdx.y;
  if (cb < rb) return;
  int t = threadIdx.x;
  __shared__ float4 cbox[64];
  __shared__ float4 rbox[64];
  cbox[t] = shifted[cb * 64 + t];
  u32 i = rb * 64 + t;
  float4 bi = shifted[i];
  rbox[t] = bi;
  __syncthreads();
  u64 rbits = 0, cbits = 0;
  for (int j = 0; j < 64; ++j) {
    bool sp = suppress(bi, cbox[j]);
    if ((cb * 64 + (u32)j) > i && sp) rbits |= (1ull << j);
    if (j < t && sp) cbits |= (1ull << j);
  }
  mask[(u64)i * NCHUNK + cb] = rbits;
  if (cb == rb) {
    diagT[(u64)rb * 64 + t] = cbits;
  } else if (cb == rb + 1) {
    float4 myc = cbox[t];
    u64 sb = 0;
    for (int s = 0; s < 64; ++s)
      if (suppress(rbox[s], myc)) sb |= (1ull << s);
    superT[(u64)rb * 64 + t] = sb;
  }
}

// 7) single-wave greedy scan, shfl-free inner loop + deferred row ORs; fused output.
//    Lane t owns removed words 2t,2t+1. Per chunk c:
//      w = ~(premc | urgent); greedy: s=ctz(w); w &= ~ballot((diagT_t>>s)&1)
//      urgent(c+1) = ballot(superT_t & keptbits)      [covers chunk-c kept]
//      full-row loads issued now, consumed END of c+1  [covers chunks <= c-1]
//      premc(c+1) = shfl(removed word) precomputed after consume
__global__ __launch_bounds__(64) void k_scan(const u64* __restrict__ mask,
                                             const u64* __restrict__ diagT,
                                             const u64* __restrict__ superT,
                                             const u64* __restrict__ cand,
                                             u32* __restrict__ ctrl,
                                             const float2* __restrict__ logits,
                                             const float4* __restrict__ rois,
                                             float* __restrict__ out) {
  __shared__ u32 lkept[NPOST];
  int t = threadIdx.x;
  u32 total = min(ctrl[C_CANDCNT], (u32)KPAD);
  u32 chunks = (total + 63) >> 6;
  u32 kept = 0;
  if (chunks) {
    u64 r0 = 0, r1 = 0;
    u64 urgent = 0, premc = 0;
    u64 dT = diagT[t];
    u64 sT = superT[t];
    ulonglong2 zz; zz.x = 0; zz.y = 0;
    ulonglong2 gA = zz, gB = zz, gC = zz, gD = zz, gE = zz, gF = zz, gG = zz, gH = zz;
    for (u32 c = 0; c < chunks; ++c) {
      u64 myd = dT, mys = sT;
      u32 cn = c + 1;
      if (cn < chunks) { dT = diagT[(u64)cn * 64 + t]; sT = superT[(u64)cn * 64 + t]; }
      u64 w = ~(premc | urgent);
      u32 rem2 = total - c * 64;
      if (rem2 < 64) w &= ((1ull << rem2) - 1ull);
      // ---- greedy resolution: ~25 cyc/step, no cross-lane latency ----
      u64 keptbits = 0;
      while (w && kept < NPOST) {
        u32 s = (u32)__builtin_ctzll(w);
        keptbits |= (1ull << s);
        if (t == 0) lkept[kept] = c * 64 + s;
        ++kept;
        bool sup = (myd >> s) & 1ull;
        u64 bal = __ballot(sup);
        w &= ~bal;
        w &= ~(1ull << s);
      }
      if (kept >= NPOST || cn >= chunks) break;
      // ---- urgent word c+1 from transposed super-diagonal: one ballot ----
      urgent = __ballot((mys & keptbits) != 0ull);
      // ---- issue deferred full-row loads for first <=8 kept rows ----
      const u64* bp = mask + (u64)c * 64 * NCHUNK + (u64)(2 * t);
      ulonglong2 nA = zz, nB = zz, nC = zz, nD = zz, nE = zz, nF = zz, nG = zz, nH = zz;
      u64 kb = keptbits;
      if (kb) {
        u32 sA = (u32)__builtin_ctzll(kb); kb &= kb - 1;
        u32 sB = sA, sC = sA, sD = sA, sE = sA, sF = sA, sG = sA, sH = sA;
        if (kb) { sB = (u32)__builtin_ctzll(kb); kb &= kb - 1;
        if (kb) { sC = (u32)__builtin_ctzll(kb); kb &= kb - 1;
        if (kb) { sD = (u32)__builtin_ctzll(kb); kb &= kb - 1;
        if (kb) { sE = (u32)__builtin_ctzll(kb); kb &= kb - 1;
        if (kb) { sF = (u32)__builtin_ctzll(kb); kb &= kb - 1;
        if (kb) { sG = (u32)__builtin_ctzll(kb); kb &= kb - 1;
        if (kb) { sH = (u32)__builtin_ctzll(kb); kb &= kb - 1; }}}}}}}
        nA = *(const ulonglong2*)(bp + (u64)sA * NCHUNK);
        nB = *(const ulonglong2*)(bp + (u64)sB * NCHUNK);
        nC = *(const ulonglong2*)(bp + (u64)sC * NCHUNK);
        nD = *(const ulonglong2*)(bp + (u64)sD * NCHUNK);
        nE = *(const ulonglong2*)(bp + (u64)sE * NCHUNK);
        nF = *(const ulonglong2*)(bp + (u64)sF * NCHUNK);
        nG = *(const ulonglong2*)(bp + (u64)sG * NCHUNK);
        nH = *(const ulonglong2*)(bp + (u64)sH * NCHUNK);
        while (kb) {   // >8 kept in one chunk: rare blocking batches
          u32 tA = (u32)__builtin_ctzll(kb); kb &= kb - 1;
          u32 tB = tA, tC = tA, tD = tA, tE = tA, tF = tA, tG = tA, tH = tA;
          if (kb) { tB = (u32)__builtin_ctzll(kb); kb &= kb - 1;
          if (kb) { tC = (u32)__builtin_ctzll(kb); kb &= kb - 1;
          if (kb) { tD = (u32)__builtin_ctzll(kb); kb &= kb - 1;
          if (kb) { tE = (u32)__builtin_ctzll(kb); kb &= kb - 1;
          if (kb) { tF = (u32)__builtin_ctzll(kb); kb &= kb - 1;
          if (kb) { tG = (u32)__builtin_ctzll(kb); kb &= kb - 1;
          if (kb) { tH = (u32)__builtin_ctzll(kb); kb &= kb - 1; }}}}}}}
          ulonglong2 hA = *(const ulonglong2*)(bp + (u64)tA * NCHUNK);
          ulonglong2 hB = *(const ulonglong2*)(bp + (u64)tB * NCHUNK);
          ulonglong2 hC = *(const ulonglong2*)(bp + (u64)tC * NCHUNK);
          ulonglong2 hD = *(const ulonglong2*)(bp + (u64)tD * NCHUNK);
          ulonglong2 hE = *(const ulonglong2*)(bp + (u64)tE * NCHUNK);
          ulonglong2 hF = *(const ulonglong2*)(bp + (u64)tF * NCHUNK);
          ulonglong2 hG = *(const ulonglong2*)(bp + (u64)tG * NCHUNK);
          ulonglong2 hH = *(const ulonglong2*)(bp + (u64)tH * NCHUNK);
          r0 |= hA.x | hB.x | hC.x | hD.x | hE.x | hF.x | hG.x | hH.x;
          r1 |= hA.y | hB.y | hC.y | hD.y | hE.y | hF.y | hG.y | hH.y;
        }
      }
      // ---- consume previous chunk's deferred loads (latency hidden) ----
      r0 |= gA.x | gB.x | gC.x | gD.x | gE.x | gF.x | gG.x | gH.x;
      r1 |= gA.y | gB.y | gC.y | gD.y | gE.y | gF.y | gG.y | gH.y;
      gA = nA; gB = nB; gC = nC; gD = nD; gE = nE; gF = nF; gG = nG; gH = nH;
      // ---- precompute next chunk's broadcast (off critical path) ----
      u64 rr = (cn & 1) ? r1 : r0;
      premc = (u64)__shfl((long long)rr, (int)(cn >> 1));
    }
  }
  if (t == 0) ctrl[C_KEPTCNT] = kept;
  __syncthreads();
  // ---- fused output gather (small-box filter + padding) ----
#pragma unroll 4
  for (u32 r = (u32)t; r < NPOST; r += 64) {
    float l0 = 0.f, l1 = 0.f, b0 = 0.f, b1 = 0.f, b2 = 0.f, b3 = 0.f;
    float lvf = -1.0f, vf = 0.0f;
    if (r < kept) {
      u32 pos = lkept[r];
      u64 a = cand[pos];
      u32 idx = (u32)(a & 0x3FFFFu);
      u32 lvl = (u32)((a >> 18) & 3u);
      float4 rb = rois[idx];
      float hs = __fsub_rn(rb.z, rb.x);
      float wsz = __fsub_rn(rb.w, rb.y);
      if (hs >= 1.0f && wsz >= 1.0f) {
        float2 lg = logits[idx];
        l0 = lg.x; l1 = lg.y;
        b0 = rb.x; b1 = rb.y; b2 = rb.z; b3 = rb.w;
        lvf = (float)lvl; vf = 1.0f;
      }
    }
    out[2 * r] = l0;
    out[2 * r + 1] = l1;
    out[2 * NPOST + 4 * r + 0] = b0;
    out[2 * NPOST + 4 * r + 1] = b1;
    out[2 * NPOST + 4 * r + 2] = b2;
    out[2 * NPOST + 4 * r + 3] = b3;
    out[6 * NPOST + r] = lvf;
    out[7 * NPOST + r] = vf;
  }
}

// fallback) sequential greedy NMS (only if ws too small for the mask)
__global__ __launch_bounds__(1024) void k_nms(const float4* __restrict__ shifted,
                                              u32* __restrict__ ctrl, u32* __restrict__ keptpos) {
  __shared__ float4 kbox[NPOST];
  __shared__ u32 wflag[16];
  int tid = threadIdx.x;
  u32 total = min(ctrl[C_CANDCNT], (u32)KPAD);
  int n = 0;
  for (u32 i = 0; i < total; ++i) {
    float4 cur = shifted[i];
    bool sup = false;
    if (tid < n) sup = suppress(kbox[tid], cur);
    int any = __any(sup);
    if ((tid & 63) == 0) wflag[tid >> 6] = (u32)any;
    __syncthreads();
    u32 f = 0;
#pragma unroll
    for (int w = 0; w < 16; ++w) f |= wflag[w];
    if (!f) {
      if (tid == 0) { kbox[n] = cur; keptpos[n] = i; }
      ++n;
    }
    __syncthreads();
    if (n >= NPOST) break;
  }
  if (tid == 0) ctrl[C_KEPTCNT] = (u32)n;
}

// fallback output gather
__global__ void k_out(const u64* __restrict__ cand, const u32* __restrict__ keptpos,
                      const u32* __restrict__ ctrl, const float2* __restrict__ logits,
                      const float4* __restrict__ rois, float* __restrict__ out) {
  int r = blockIdx.x * blockDim.x + threadIdx.x;
  if (r >= NPOST) return;
  u32 kn = ctrl[C_KEPTCNT];
  float l0 = 0.f, l1 = 0.f, r0 = 0.f, r1 = 0.f, r2 = 0.f, r3 = 0.f;
  float lvf = -1.0f, vf = 0.0f;
  if (r < (int)kn) {
    u32 pos = keptpos[r];
    u64 a = cand[pos];
    u32 idx = (u32)(a & 0x3FFFFu);
    u32 lvl = (u32)((a >> 18) & 3u);
    float4 rb = rois[idx];
    float hs = __fsub_rn(rb.z, rb.x);
    float wsz = __fsub_rn(rb.w, rb.y);
    if (hs >= 1.0f && wsz >= 1.0f) {
      float2 lg = logits[idx];
      l0 = lg.x; l1 = lg.y;
      r0 = rb.x; r1 = rb.y; r2 = rb.z; r3 = rb.w;
      lvf = (float)lvl; vf = 1.0f;
    }
  }
  out[2 * r] = l0;
  out[2 * r + 1] = l1;
  out[2 * NPOST + 4 * r + 0] = r0;
  out[2 * NPOST + 4 * r + 1] = r1;
  out[2 * NPOST + 4 * r + 2] = r2;
  out[2 * NPOST + 4 * r + 3] = r3;
  out[6 * NPOST + r] = lvf;
  out[7 * NPOST + r] = vf;
}

extern "C" void kernel_launch(void* const* d_in, const int* in_sizes, int n_in,
                              void* d_out, int out_size, void* d_ws, size_t ws_size,
                              hipStream_t stream) {
  const float* logits = (const float*)d_in[0];
  const float* rois = (const float*)d_in[1];
  const int* levels = (const int*)d_in[2];
  int N = in_sizes[2];

  char* ws = (char*)d_ws;
  u32* sbits = (u32*)(ws + OFF_SBITS);
  u32* hist = (u32*)(ws + OFF_HIST);
  u32* ctrl = (u32*)(ws + OFF_CTRL);
  u32* keptpos = (u32*)(ws + OFF_KEPT);
  u64* tie = (u64*)(ws + OFF_TIE);
  u64* cand = (u64*)(ws + OFF_CAND);
  float4* shifted = (float4*)(ws + OFF_SHIFT);
  u64* diagT = (u64*)(ws + OFF_DIAGT);
  u64* superT = (u64*)(ws + OFF_SUPT);
  u64* mask = (u64*)(ws + OFF_MASK);

  // hist [1MB,2MB) and ctrl [2MB,2MB+4KB) are contiguous: one memset
  hipMemsetAsync(hist, 0, (1u << 20) + 4096, stream);

  int nb = (N + 255) / 256;
  k_score_hist<<<nb, 256, 0, stream>>>((const float2*)logits, levels, sbits, hist, N);
  k_scan_hi<<<NLVL, 256, 0, stream>>>(hist, ctrl);
  k_compact<<<nb, 256, 0, stream>>>(sbits, levels, (const float4*)rois, ctrl, cand, tie, N);
  k_ties<<<NLVL, 256, 0, stream>>>((const float4*)rois, ctrl, cand, tie);
  k_sort<<<1, 1024, 0, stream>>>(cand, ctrl, (const float4*)rois, shifted);
  if (ws_size >= WS_NEED) {
    dim3 g(KPAD / 64, KPAD / 64);
    k_build<<<g, 64, 0, stream>>>((const float4*)shifted, mask, diagT, superT);
    k_scan<<<1, 64, 0, stream>>>(mask, diagT, superT, cand, ctrl,
                                 (const float2*)logits, (const float4*)rois, (float*)d_out);
  } else {
    k_nms<<<1, 1024, 0, stream>>>(shifted, ctrl, keptpos);
    k_out<<<(NPOST + 255) / 256, 256, 0, stream>>>(cand, keptpos, ctrl, (const float2*)logits,
                                                   (const float4*)rois, (float*)d_out);
  }
}

// Round 6
// 396.959 us; speedup vs baseline: 1.8218x; 1.3811x over previous
//
#include <hip/hip_runtime.h>
#include <stdint.h>

typedef uint32_t u32;
typedef uint64_t u64;

#define NLVL 4
#define NPRE 2000
#define NPOST 1000
#define KPAD 8192
#define TIE_CAP 4096
#define NCHUNK 128          // chunk count (125 used, padded to 128)

// ws layout (bytes)
#define OFF_SBITS 0u                        // 1 MB  (250K u32)
#define OFF_HIST  (1u<<20)                  // 1 MB  (4*64K u32)  [memset with ctrl]
#define OFF_CTRL  (2u<<20)                  // 4 KB  (contiguous after hist)
#define OFF_KEPT  ((2u<<20) + (8u<<10))     // 4 KB  (fallback path only)
#define OFF_TIE   ((2u<<20) + (64u<<10))    // 128 KB u64[4][4096]
#define OFF_CAND  ((2u<<20) + (192u<<10))   // 64 KB u64[8192]
#define OFF_SHIFT ((2u<<20) + (256u<<10))   // 128 KB float4[8192]
#define OFF_MASK  (3u<<20)                  // 8 MB: maskT2[128 row-chunks][8192 cols] u64
#define WS_NEED   ((size_t)(3u<<20) + (size_t)NCHUNK * KPAD * 8u)

// ctrl word indices
#define C_CANDCNT 0
#define C_KEPTCNT 1
#define C_SEPMAX  2
#define C_P       4   // +lvl  (0xFFFFFFFF = deficient level -> take all)
#define C_RANK    8   // +lvl  (elements needed from bin P)
#define C_TIECNT  12  // +lvl

// ---- monotone float<->u32 map for atomic max over floats ----
__device__ __forceinline__ u32 fmap(float f) {
  u32 u = __float_as_uint(f);
  return (u & 0x80000000u) ? ~u : (u | 0x80000000u);
}
__device__ __forceinline__ float funmap(u32 u) {
  u = (u & 0x80000000u) ? (u & 0x7FFFFFFFu) : ~u;
  return __uint_as_float(u);
}

// ---- replicate XLA-CPU GenerateVF32Exp (Cephes/Eigen-3.3 style) ----
__device__ __forceinline__ float xla_expf(float x) {
  const float kLog2e = 1.44269504088896341f;
  const float kC1 = 0.693359375f;
  const float kC2 = -2.12194440e-4f;
  const float kP0 = 1.9875691500e-4f;
  const float kP1 = 1.3981999507e-3f;
  const float kP2 = 8.3334519073e-3f;
  const float kP3 = 4.1665795894e-2f;
  const float kP4 = 1.6666665459e-1f;
  const float kP5 = 5.0000001201e-1f;
  float xc = fminf(fmaxf(x, -88.3762626647949f), 88.3762626647950f);
  float fx = floorf(fmaf(xc, kLog2e, 0.5f));
  float tmp = __fmul_rn(kC1, fx);
  float z = __fmul_rn(kC2, fx);
  float r = __fsub_rn(xc, tmp);
  r = __fsub_rn(r, z);
  float r2 = __fmul_rn(r, r);
  float y = fmaf(r, kP0, kP1);
  y = fmaf(y, r, kP2);
  y = fmaf(y, r, kP3);
  y = fmaf(y, r, kP4);
  y = fmaf(y, r, kP5);
  y = fmaf(y, r2, r);
  y = __fadd_rn(y, 1.0f);
  int n = (int)fx;
  float two_n = __int_as_float((n + 127) << 23);
  return fmaxf(__fmul_rn(y, two_n), x);
}

// ---- IoU(a,b) > 0.7f, reference's exact f32 op sequence; exactly symmetric ----
__device__ __forceinline__ bool suppress(float4 a, float4 b) {
  float aa = __fmul_rn(__fsub_rn(a.z, a.x), __fsub_rn(a.w, a.y));
  float ab = __fmul_rn(__fsub_rn(b.z, b.x), __fsub_rn(b.w, b.y));
  float lty = fmaxf(a.x, b.x);
  float ltx = fmaxf(a.y, b.y);
  float rby = fminf(a.z, b.z);
  float rbx = fminf(a.w, b.w);
  float why = fmaxf(__fsub_rn(rby, lty), 0.0f);
  float whx = fmaxf(__fsub_rn(rbx, ltx), 0.0f);
  float inter = __fmul_rn(why, whx);
  float uni = __fsub_rn(__fadd_rn(aa, ab), inter);
  float iou = inter / fmaxf(uni, 1e-9f);
  return iou > 0.7f;
}

__device__ __forceinline__ u64 makekey(u32 sbits, u32 lvl, u32 idx) {
  // ascending key == (score desc, level asc, index asc); total order (idx unique)
  return ((u64)(0x7FFFFFFFu - sbits) << 20) | ((u64)lvl << 18) | (u64)idx;
}

// 1) softmax score + hi16 histogram per level
__global__ void k_score_hist(const float2* __restrict__ logits, const int* __restrict__ levels,
                             u32* __restrict__ sbits, u32* __restrict__ hist, int n) {
  int i = blockIdx.x * blockDim.x + threadIdx.x;
  if (i >= n) return;
  float2 lg = logits[i];
  float m = fmaxf(lg.x, lg.y);
  float e0 = xla_expf(__fsub_rn(lg.x, m));
  float e1 = xla_expf(__fsub_rn(lg.y, m));
  float s = e1 / __fadd_rn(e0, e1);   // IEEE div
  u32 b = __float_as_uint(s);
  sbits[i] = b;
  int lv = levels[i];
  atomicAdd(&hist[lv * 65536 + (int)(b >> 16)], 1u);
}

// 2) per-level descending scan of hi16 histogram -> bin P containing rank NPRE,
//    and RANK = #elements needed from inside bin P
__global__ void k_scan_hi(const u32* __restrict__ hist, u32* __restrict__ ctrl) {
  int lvl = blockIdx.x;
  int tid = threadIdx.x;
  const u32* h = hist + lvl * 65536;
  __shared__ u32 part[256];
  u32 s = 0;
  int base = tid * 256;
  for (int b = 0; b < 256; ++b) s += h[base + b];
  part[tid] = s;
  __syncthreads();
  if (tid == 0) {
    const u32 target = NPRE;
    u32 cum = 0, before = 0; int seg = -1;
    for (int t = 255; t >= 0; --t) {
      if (seg < 0 && cum + part[t] >= target) { seg = t; before = cum; }
      cum += part[t];
    }
    if (cum < target) {           // deficient level: take everything at the level
      ctrl[C_P + lvl] = 0xFFFFFFFFu;
      ctrl[C_RANK + lvl] = 0u;
    } else {
      u32 c = before; u32 bin = 0;
      for (int b = seg * 256 + 255; b >= seg * 256; --b) {
        u32 hb = h[b];
        if (c + hb >= target) { bin = (u32)b; break; }
        c += hb;
      }
      ctrl[C_P + lvl] = bin;
      ctrl[C_RANK + lvl] = target - c;   // >=1 needed inside bin P
    }
  }
}

// 3) compact: hi16 above bin P -> cand keys; hi16 == P -> tie keys; sep max
__global__ void k_compact(const u32* __restrict__ sbits, const int* __restrict__ levels,
                          const float4* __restrict__ rois, u32* __restrict__ ctrl,
                          u64* __restrict__ cand, u64* __restrict__ tie, int n) {
  int i = blockIdx.x * blockDim.x + threadIdx.x;
  bool act = i < n;
  u32 b = 0; int lv = 0; u32 P = 0xFFFFFFFEu;
  if (act) {
    b = sbits[i];
    lv = levels[i];
    P = ctrl[C_P + lv];
  }
  u32 mx = 0;
  if (act && (P == 0xFFFFFFFFu || (b >> 16) > P)) {
    u32 p = atomicAdd(&ctrl[C_CANDCNT], 1u);
    if (p < (u32)KPAD) cand[p] = makekey(b, (u32)lv, (u32)i);
    float4 r = rois[i];
    mx = max(max(fmap(r.x), fmap(r.y)), max(fmap(r.z), fmap(r.w)));
  } else if (act && (b >> 16) == P) {
    u32 t = atomicAdd(&ctrl[C_TIECNT + lv], 1u);
    if (t < TIE_CAP) tie[lv * TIE_CAP + t] = makekey(b, (u32)lv, (u32)i);
  }
  for (int o = 32; o; o >>= 1) {
    u32 v = (u32)__shfl_xor((int)mx, o);
    mx = max(mx, v);
  }
  if ((threadIdx.x & 63) == 0 && mx)
    atomicMax(&ctrl[C_SEPMAX], mx);
}

// 4) bin-P resolution: sort bin members by total-order key, take first RANK
__global__ void k_ties(const float4* __restrict__ rois, u32* __restrict__ ctrl,
                       u64* __restrict__ cand, const u64* __restrict__ tie) {
  int lvl = blockIdx.x;
  int tid = threadIdx.x;
  if (ctrl[C_P + lvl] == 0xFFFFFFFFu) return;   // deficient (uniform per block)
  u32 need = ctrl[C_RANK + lvl];
  if (need == 0) return;
  u32 n = min(ctrl[C_TIECNT + lvl], (u32)TIE_CAP);
  u32 m = 2; while (m < n) m <<= 1;
  __shared__ u64 buf[TIE_CAP];
  for (u32 t = tid; t < m; t += 256)
    buf[t] = (t < n) ? tie[lvl * TIE_CAP + t] : ~0ull;
  __syncthreads();
  for (u32 k = 2; k <= m; k <<= 1) {
    for (u32 j = k >> 1; j > 0; j >>= 1) {
      for (u32 p = tid; p < m; p += 256) {
        u32 q = p ^ j;
        if (q > p) {
          u64 a = buf[p], b = buf[q];
          bool desc = (p & k) != 0;
          if (desc ? (a < b) : (a > b)) { buf[p] = b; buf[q] = a; }
        }
      }
      __syncthreads();
    }
  }
  u32 cnt = min(need, n);
  __shared__ u32 basep;
  if (tid == 0) basep = atomicAdd(&ctrl[C_CANDCNT], cnt);
  __syncthreads();
  u32 mx = 0;
  for (u32 t = tid; t < cnt; t += 256) {
    u64 key = buf[t];
    if (basep + t < (u32)KPAD) cand[basep + t] = key;
    u32 idx = (u32)(key & 0x3FFFFu);
    float4 r = rois[idx];
    mx = max(mx, max(max(fmap(r.x), fmap(r.y)), max(fmap(r.z), fmap(r.w))));
  }
  if (mx) atomicMax(&ctrl[C_SEPMAX], mx);
}

// 5) bitonic sort of 8192 u64 keys in LDS -> global NMS order; fused shift-write
__global__ __launch_bounds__(1024) void k_sort(u64* __restrict__ cand, const u32* __restrict__ ctrl,
                                               const float4* __restrict__ rois,
                                               float4* __restrict__ shifted) {
  __shared__ u64 a[KPAD];
  int tid = threadIdx.x;
  u32 total = min(ctrl[C_CANDCNT], (u32)KPAD);
  for (int p = tid; p < KPAD; p += 1024) a[p] = (p < (int)total) ? cand[p] : ~0ull;
  __syncthreads();
  for (u32 k = 2; k <= KPAD; k <<= 1) {
    for (u32 j = k >> 1; j > 0; j >>= 1) {
      for (u32 p = tid; p < (u32)KPAD; p += 1024) {
        u32 q = p ^ j;
        if (q > p) {
          u64 x = a[p], y = a[q];
          bool desc = (p & k) != 0;
          if (desc ? (x < y) : (x > y)) { a[p] = y; a[q] = x; }
        }
      }
      __syncthreads();
    }
  }
  float sep = __fadd_rn(funmap(ctrl[C_SEPMAX]), 1.0f);
  for (int p = tid; p < KPAD; p += 1024) {
    u64 key = a[p];
    cand[p] = key;
    float4 o = make_float4(0.f, 0.f, 0.f, 0.f);
    if (p < (int)total) {
      u32 idx = (u32)(key & 0x3FFFFu);
      u32 lvl = (u32)((key >> 18) & 3u);
      float4 r = rois[idx];
      float sh = __fmul_rn((float)lvl, sep);
      o.x = __fadd_rn(r.x, sh);
      o.y = __fadd_rn(r.y, sh);
      o.z = __fadd_rn(r.z, sh);
      o.w = __fadd_rn(r.w, sh);
    }
    shifted[p] = o;
  }
}

// 6) build column-major suppression mask:
//    maskT2[rb*KPAD + j] bit s = suppress(box[rb*64+s], box[j]) && (rb*64+s < j)
//    Writes are coalesced (lane t -> consecutive j). Upper triangle only.
__global__ __launch_bounds__(64) void k_build(const float4* __restrict__ shifted,
                                              u64* __restrict__ maskT2) {
  u32 cb = blockIdx.x, rb = blockIdx.y;
  if (rb > cb) return;
  int t = threadIdx.x;
  __shared__ float4 rbox[64];
  rbox[t] = shifted[rb * 64 + t];
  u32 jg = cb * 64 + (u32)t;
  float4 myc = shifted[jg];
  __syncthreads();
  u64 bits = 0;
  for (int s = 0; s < 64; ++s) {
    if ((rb * 64 + (u32)s) < jg && suppress(rbox[s], myc)) bits |= (1ull << s);
  }
  maskT2[(u64)rb * KPAD + jg] = bits;
}

// 7) single-wave greedy scan: ballot-fixpoint intra-chunk resolution (exact greedy
//    on the s<t DAG), cross-chunk suppression via coalesced column loads ANDed
//    with LDS kept-masks. No per-kept serial chain, no per-kept row loads.
__global__ __launch_bounds__(64) void k_scan(const u64* __restrict__ maskT2,
                                             const u64* __restrict__ cand,
                                             u32* __restrict__ ctrl,
                                             const float2* __restrict__ logits,
                                             const float4* __restrict__ rois,
                                             float* __restrict__ out) {
  __shared__ u64 keptm[NCHUNK];
  __shared__ u32 lkept[NPOST];
  int t = threadIdx.x;
  u32 total = min(ctrl[C_CANDCNT], (u32)KPAD);
  u32 chunks = (total + 63) >> 6;
  u32 kept = 0;
  keptm[t] = 0;
  keptm[64 + t] = 0;
  __syncthreads();
  for (u32 c = 0; c < chunks && kept < NPOST; ++c) {
    const u64* colbase = maskT2 + (u64)c * 64 + (u64)t;  // + ci*KPAD per row-chunk
    u64 diagw = colbase[(u64)c * KPAD];   // bits s<t suppressing t within chunk
    // ---- cross-chunk removed bit: OR over resolved chunks (coalesced loads) ----
    u64 a0 = 0, a1 = 0;
    u32 ci = 0;
    for (; ci + 8 <= c; ci += 8) {
      u64 w0 = colbase[(u64)(ci + 0) * KPAD];
      u64 w1 = colbase[(u64)(ci + 1) * KPAD];
      u64 w2 = colbase[(u64)(ci + 2) * KPAD];
      u64 w3 = colbase[(u64)(ci + 3) * KPAD];
      u64 w4 = colbase[(u64)(ci + 4) * KPAD];
      u64 w5 = colbase[(u64)(ci + 5) * KPAD];
      u64 w6 = colbase[(u64)(ci + 6) * KPAD];
      u64 w7 = colbase[(u64)(ci + 7) * KPAD];
      a0 |= (w0 & keptm[ci + 0]) | (w1 & keptm[ci + 1]) |
            (w2 & keptm[ci + 2]) | (w3 & keptm[ci + 3]);
      a1 |= (w4 & keptm[ci + 4]) | (w5 & keptm[ci + 5]) |
            (w6 & keptm[ci + 6]) | (w7 & keptm[ci + 7]);
    }
    for (; ci < c; ++ci) a0 |= colbase[(u64)ci * KPAD] & keptm[ci];
    bool removed = (a0 | a1) != 0ull;
    u64 w = ~__ballot(removed);
    u32 rem2 = total - c * 64;
    if (rem2 < 64) w &= ((1ull << rem2) - 1ull);
    // ---- intra-chunk greedy via ballot fixpoint (converges in <= depth iters) ----
    u64 keep = w;
    for (int it = 0; it < 64; ++it) {
      bool sup = (diagw & keep) != 0ull;
      u64 nk = w & ~__ballot(sup);
      if (nk == keep) break;     // uniform condition
      keep = nk;
    }
    // ---- parallel record via popcount prefix ----
    u32 pos = kept + (u32)__popcll(keep & ((1ull << t) - 1ull));
    if (((keep >> t) & 1ull) && pos < NPOST) lkept[pos] = c * 64 + (u32)t;
    if (t == 0) keptm[c] = keep;
    kept += (u32)__popcll(keep);
  }
  if (t == 0) ctrl[C_KEPTCNT] = min(kept, (u32)NPOST);
  __syncthreads();
  u32 kn = min(kept, (u32)NPOST);
  // ---- fused output gather (small-box filter + padding) ----
#pragma unroll 4
  for (u32 r = (u32)t; r < NPOST; r += 64) {
    float l0 = 0.f, l1 = 0.f, b0 = 0.f, b1 = 0.f, b2 = 0.f, b3 = 0.f;
    float lvf = -1.0f, vf = 0.0f;
    if (r < kn) {
      u32 pos = lkept[r];
      u64 a = cand[pos];
      u32 idx = (u32)(a & 0x3FFFFu);
      u32 lvl = (u32)((a >> 18) & 3u);
      float4 rb = rois[idx];
      float hs = __fsub_rn(rb.z, rb.x);
      float wsz = __fsub_rn(rb.w, rb.y);
      if (hs >= 1.0f && wsz >= 1.0f) {
        float2 lg = logits[idx];
        l0 = lg.x; l1 = lg.y;
        b0 = rb.x; b1 = rb.y; b2 = rb.z; b3 = rb.w;
        lvf = (float)lvl; vf = 1.0f;
      }
    }
    out[2 * r] = l0;
    out[2 * r + 1] = l1;
    out[2 * NPOST + 4 * r + 0] = b0;
    out[2 * NPOST + 4 * r + 1] = b1;
    out[2 * NPOST + 4 * r + 2] = b2;
    out[2 * NPOST + 4 * r + 3] = b3;
    out[6 * NPOST + r] = lvf;
    out[7 * NPOST + r] = vf;
  }
}

// fallback) sequential greedy NMS (only if ws too small for the mask)
__global__ __launch_bounds__(1024) void k_nms(const float4* __restrict__ shifted,
                                              u32* __restrict__ ctrl, u32* __restrict__ keptpos) {
  __shared__ float4 kbox[NPOST];
  __shared__ u32 wflag[16];
  int tid = threadIdx.x;
  u32 total = min(ctrl[C_CANDCNT], (u32)KPAD);
  int n = 0;
  for (u32 i = 0; i < total; ++i) {
    float4 cur = shifted[i];
    bool sup = false;
    if (tid < n) sup = suppress(kbox[tid], cur);
    int any = __any(sup);
    if ((tid & 63) == 0) wflag[tid >> 6] = (u32)any;
    __syncthreads();
    u32 f = 0;
#pragma unroll
    for (int w = 0; w < 16; ++w) f |= wflag[w];
    if (!f) {
      if (tid == 0) { kbox[n] = cur; keptpos[n] = i; }
      ++n;
    }
    __syncthreads();
    if (n >= NPOST) break;
  }
  if (tid == 0) ctrl[C_KEPTCNT] = (u32)n;
}

// fallback output gather
__global__ void k_out(const u64* __restrict__ cand, const u32* __restrict__ keptpos,
                      const u32* __restrict__ ctrl, const float2* __restrict__ logits,
                      const float4* __restrict__ rois, float* __restrict__ out) {
  int r = blockIdx.x * blockDim.x + threadIdx.x;
  if (r >= NPOST) return;
  u32 kn = ctrl[C_KEPTCNT];
  float l0 = 0.f, l1 = 0.f, r0 = 0.f, r1 = 0.f, r2 = 0.f, r3 = 0.f;
  float lvf = -1.0f, vf = 0.0f;
  if (r < (int)kn) {
    u32 pos = keptpos[r];
    u64 a = cand[pos];
    u32 idx = (u32)(a & 0x3FFFFu);
    u32 lvl = (u32)((a >> 18) & 3u);
    float4 rb = rois[idx];
    float hs = __fsub_rn(rb.z, rb.x);
    float wsz = __fsub_rn(rb.w, rb.y);
    if (hs >= 1.0f && wsz >= 1.0f) {
      float2 lg = logits[idx];
      l0 = lg.x; l1 = lg.y;
      r0 = rb.x; r1 = rb.y; r2 = rb.z; r3 = rb.w;
      lvf = (float)lvl; vf = 1.0f;
    }
  }
  out[2 * r] = l0;
  out[2 * r + 1] = l1;
  out[2 * NPOST + 4 * r + 0] = r0;
  out[2 * NPOST + 4 * r + 1] = r1;
  out[2 * NPOST + 4 * r + 2] = r2;
  out[2 * NPOST + 4 * r + 3] = r3;
  out[6 * NPOST + r] = lvf;
  out[7 * NPOST + r] = vf;
}

extern "C" void kernel_launch(void* const* d_in, const int* in_sizes, int n_in,
                              void* d_out, int out_size, void* d_ws, size_t ws_size,
                              hipStream_t stream) {
  const float* logits = (const float*)d_in[0];
  const float* rois = (const float*)d_in[1];
  const int* levels = (const int*)d_in[2];
  int N = in_sizes[2];

  char* ws = (char*)d_ws;
  u32* sbits = (u32*)(ws + OFF_SBITS);
  u32* hist = (u32*)(ws + OFF_HIST);
  u32* ctrl = (u32*)(ws + OFF_CTRL);
  u32* keptpos = (u32*)(ws + OFF_KEPT);
  u64* tie = (u64*)(ws + OFF_TIE);
  u64* cand = (u64*)(ws + OFF_CAND);
  float4* shifted = (float4*)(ws + OFF_SHIFT);
  u64* maskT2 = (u64*)(ws + OFF_MASK);

  // hist [1MB,2MB) and ctrl [2MB,2MB+4KB) are contiguous: one memset
  hipMemsetAsync(hist, 0, (1u << 20) + 4096, stream);

  int nb = (N + 255) / 256;
  k_score_hist<<<nb, 256, 0, stream>>>((const float2*)logits, levels, sbits, hist, N);
  k_scan_hi<<<NLVL, 256, 0, stream>>>(hist, ctrl);
  k_compact<<<nb, 256, 0, stream>>>(sbits, levels, (const float4*)rois, ctrl, cand, tie, N);
  k_ties<<<NLVL, 256, 0, stream>>>((const float4*)rois, ctrl, cand, tie);
  k_sort<<<1, 1024, 0, stream>>>(cand, ctrl, (const float4*)rois, shifted);
  if (ws_size >= WS_NEED) {
    dim3 g(KPAD / 64, KPAD / 64);
    k_build<<<g, 64, 0, stream>>>((const float4*)shifted, maskT2);
    k_scan<<<1, 64, 0, stream>>>(maskT2, cand, ctrl,
                                 (const float2*)logits, (const float4*)rois, (float*)d_out);
  } else {
    k_nms<<<1, 1024, 0, stream>>>(shifted, ctrl, keptpos);
    k_out<<<(NPOST + 255) / 256, 256, 0, stream>>>(cand, keptpos, ctrl, (const float2*)logits,
                                                   (const float4*)rois, (float*)d_out);
  }
}

// Round 7
// 378.803 us; speedup vs baseline: 1.9091x; 1.0479x over previous
//
#include <hip/hip_runtime.h>
#include <stdint.h>

typedef uint32_t u32;
typedef uint64_t u64;

#define NLVL 4
#define NPRE 2000
#define NPOST 1000
#define KPAD 8192
#define TIE_CAP 4096
#define NCHUNK 128          // chunk count (125 used, padded to 128)

// ws layout (bytes)
#define OFF_SBITS 0u                        // 1 MB  (250K u32)
#define OFF_HIST  (1u<<20)                  // 1 MB  (4*64K u32)  [memset with ctrl]
#define OFF_CTRL  (2u<<20)                  // 4 KB  (contiguous after hist)
#define OFF_KEPT  ((2u<<20) + (8u<<10))     // 4 KB  (fallback path only)
#define OFF_TIE   ((2u<<20) + (64u<<10))    // 128 KB u64[4][4096]
#define OFF_CAND  ((2u<<20) + (192u<<10))   // 64 KB u64[8192]  (unsorted)
#define OFF_SHIFT ((2u<<20) + (256u<<10))   // 128 KB float4[8192] (sorted order)
#define OFF_CAND2 ((2u<<20) + (384u<<10))   // 64 KB u64[8192]  (sorted)
#define OFF_MASK  (3u<<20)                  // 8 MB: maskT2[128 row-chunks][8192 cols] u64
#define WS_NEED   ((size_t)(3u<<20) + (size_t)NCHUNK * KPAD * 8u)

// ctrl word indices
#define C_CANDCNT 0
#define C_KEPTCNT 1
#define C_SEPMAX  2
#define C_P       4   // +lvl  (0xFFFFFFFF = deficient level -> take all)
#define C_RANK    8   // +lvl  (elements needed from bin P)
#define C_TIECNT  12  // +lvl

// ---- monotone float<->u32 map for atomic max over floats ----
__device__ __forceinline__ u32 fmap(float f) {
  u32 u = __float_as_uint(f);
  return (u & 0x80000000u) ? ~u : (u | 0x80000000u);
}
__device__ __forceinline__ float funmap(u32 u) {
  u = (u & 0x80000000u) ? (u & 0x7FFFFFFFu) : ~u;
  return __uint_as_float(u);
}

// ---- replicate XLA-CPU GenerateVF32Exp (Cephes/Eigen-3.3 style) ----
__device__ __forceinline__ float xla_expf(float x) {
  const float kLog2e = 1.44269504088896341f;
  const float kC1 = 0.693359375f;
  const float kC2 = -2.12194440e-4f;
  const float kP0 = 1.9875691500e-4f;
  const float kP1 = 1.3981999507e-3f;
  const float kP2 = 8.3334519073e-3f;
  const float kP3 = 4.1665795894e-2f;
  const float kP4 = 1.6666665459e-1f;
  const float kP5 = 5.0000001201e-1f;
  float xc = fminf(fmaxf(x, -88.3762626647949f), 88.3762626647950f);
  float fx = floorf(fmaf(xc, kLog2e, 0.5f));
  float tmp = __fmul_rn(kC1, fx);
  float z = __fmul_rn(kC2, fx);
  float r = __fsub_rn(xc, tmp);
  r = __fsub_rn(r, z);
  float r2 = __fmul_rn(r, r);
  float y = fmaf(r, kP0, kP1);
  y = fmaf(y, r, kP2);
  y = fmaf(y, r, kP3);
  y = fmaf(y, r, kP4);
  y = fmaf(y, r, kP5);
  y = fmaf(y, r2, r);
  y = __fadd_rn(y, 1.0f);
  int n = (int)fx;
  float two_n = __int_as_float((n + 127) << 23);
  return fmaxf(__fmul_rn(y, two_n), x);
}

// ---- IoU(a,b) > 0.7f, reference's exact f32 op sequence; exactly symmetric ----
__device__ __forceinline__ bool suppress(float4 a, float4 b) {
  float aa = __fmul_rn(__fsub_rn(a.z, a.x), __fsub_rn(a.w, a.y));
  float ab = __fmul_rn(__fsub_rn(b.z, b.x), __fsub_rn(b.w, b.y));
  float lty = fmaxf(a.x, b.x);
  float ltx = fmaxf(a.y, b.y);
  float rby = fminf(a.z, b.z);
  float rbx = fminf(a.w, b.w);
  float why = fmaxf(__fsub_rn(rby, lty), 0.0f);
  float whx = fmaxf(__fsub_rn(rbx, ltx), 0.0f);
  float inter = __fmul_rn(why, whx);
  float uni = __fsub_rn(__fadd_rn(aa, ab), inter);
  float iou = inter / fmaxf(uni, 1e-9f);
  return iou > 0.7f;
}

__device__ __forceinline__ u64 makekey(u32 sbits, u32 lvl, u32 idx) {
  // ascending key == (score desc, level asc, index asc); total order (idx unique)
  return ((u64)(0x7FFFFFFFu - sbits) << 20) | ((u64)lvl << 18) | (u64)idx;
}

// 1) softmax score + hi16 histogram per level
__global__ void k_score_hist(const float2* __restrict__ logits, const int* __restrict__ levels,
                             u32* __restrict__ sbits, u32* __restrict__ hist, int n) {
  int i = blockIdx.x * blockDim.x + threadIdx.x;
  if (i >= n) return;
  float2 lg = logits[i];
  float m = fmaxf(lg.x, lg.y);
  float e0 = xla_expf(__fsub_rn(lg.x, m));
  float e1 = xla_expf(__fsub_rn(lg.y, m));
  float s = e1 / __fadd_rn(e0, e1);   // IEEE div
  u32 b = __float_as_uint(s);
  sbits[i] = b;
  int lv = levels[i];
  atomicAdd(&hist[lv * 65536 + (int)(b >> 16)], 1u);
}

// 2) per-level descending scan of hi16 histogram -> bin P containing rank NPRE,
//    and RANK = #elements needed from inside bin P
__global__ void k_scan_hi(const u32* __restrict__ hist, u32* __restrict__ ctrl) {
  int lvl = blockIdx.x;
  int tid = threadIdx.x;
  const u32* h = hist + lvl * 65536;
  __shared__ u32 part[256];
  u32 s = 0;
  int base = tid * 256;
  for (int b = 0; b < 256; ++b) s += h[base + b];
  part[tid] = s;
  __syncthreads();
  if (tid == 0) {
    const u32 target = NPRE;
    u32 cum = 0, before = 0; int seg = -1;
    for (int t = 255; t >= 0; --t) {
      if (seg < 0 && cum + part[t] >= target) { seg = t; before = cum; }
      cum += part[t];
    }
    if (cum < target) {           // deficient level: take everything at the level
      ctrl[C_P + lvl] = 0xFFFFFFFFu;
      ctrl[C_RANK + lvl] = 0u;
    } else {
      u32 c = before; u32 bin = 0;
      for (int b = seg * 256 + 255; b >= seg * 256; --b) {
        u32 hb = h[b];
        if (c + hb >= target) { bin = (u32)b; break; }
        c += hb;
      }
      ctrl[C_P + lvl] = bin;
      ctrl[C_RANK + lvl] = target - c;   // >=1 needed inside bin P
    }
  }
}

// 3) compact: hi16 above bin P -> cand keys; hi16 == P -> tie keys; sep max
__global__ void k_compact(const u32* __restrict__ sbits, const int* __restrict__ levels,
                          const float4* __restrict__ rois, u32* __restrict__ ctrl,
                          u64* __restrict__ cand, u64* __restrict__ tie, int n) {
  int i = blockIdx.x * blockDim.x + threadIdx.x;
  bool act = i < n;
  u32 b = 0; int lv = 0; u32 P = 0xFFFFFFFEu;
  if (act) {
    b = sbits[i];
    lv = levels[i];
    P = ctrl[C_P + lv];
  }
  u32 mx = 0;
  if (act && (P == 0xFFFFFFFFu || (b >> 16) > P)) {
    u32 p = atomicAdd(&ctrl[C_CANDCNT], 1u);
    if (p < (u32)KPAD) cand[p] = makekey(b, (u32)lv, (u32)i);
    float4 r = rois[i];
    mx = max(max(fmap(r.x), fmap(r.y)), max(fmap(r.z), fmap(r.w)));
  } else if (act && (b >> 16) == P) {
    u32 t = atomicAdd(&ctrl[C_TIECNT + lv], 1u);
    if (t < TIE_CAP) tie[lv * TIE_CAP + t] = makekey(b, (u32)lv, (u32)i);
  }
  for (int o = 32; o; o >>= 1) {
    u32 v = (u32)__shfl_xor((int)mx, o);
    mx = max(mx, v);
  }
  if ((threadIdx.x & 63) == 0 && mx)
    atomicMax(&ctrl[C_SEPMAX], mx);
}

// 4) bin-P resolution: sort bin members by total-order key, take first RANK
__global__ void k_ties(const float4* __restrict__ rois, u32* __restrict__ ctrl,
                       u64* __restrict__ cand, const u64* __restrict__ tie) {
  int lvl = blockIdx.x;
  int tid = threadIdx.x;
  if (ctrl[C_P + lvl] == 0xFFFFFFFFu) return;   // deficient (uniform per block)
  u32 need = ctrl[C_RANK + lvl];
  if (need == 0) return;
  u32 n = min(ctrl[C_TIECNT + lvl], (u32)TIE_CAP);
  u32 m = 2; while (m < n) m <<= 1;
  __shared__ u64 buf[TIE_CAP];
  for (u32 t = tid; t < m; t += 256)
    buf[t] = (t < n) ? tie[lvl * TIE_CAP + t] : ~0ull;
  __syncthreads();
  for (u32 k = 2; k <= m; k <<= 1) {
    for (u32 j = k >> 1; j > 0; j >>= 1) {
      for (u32 p = tid; p < m; p += 256) {
        u32 q = p ^ j;
        if (q > p) {
          u64 a = buf[p], b = buf[q];
          bool desc = (p & k) != 0;
          if (desc ? (a < b) : (a > b)) { buf[p] = b; buf[q] = a; }
        }
      }
      __syncthreads();
    }
  }
  u32 cnt = min(need, n);
  __shared__ u32 basep;
  if (tid == 0) basep = atomicAdd(&ctrl[C_CANDCNT], cnt);
  __syncthreads();
  u32 mx = 0;
  for (u32 t = tid; t < cnt; t += 256) {
    u64 key = buf[t];
    if (basep + t < (u32)KPAD) cand[basep + t] = key;
    u32 idx = (u32)(key & 0x3FFFFu);
    float4 r = rois[idx];
    mx = max(mx, max(max(fmap(r.x), fmap(r.y)), max(fmap(r.z), fmap(r.w))));
  }
  if (mx) atomicMax(&ctrl[C_SEPMAX], mx);
}

// 5) enumeration (rank) sort: keys are unique -> rank = exact position.
//    32 blocks x 256 threads; each thread ranks one key vs all keys staged
//    through LDS tiles (broadcast reads). Fused shift-write scatter.
__global__ __launch_bounds__(256) void k_rank(const u64* __restrict__ cand,
                                              const u32* __restrict__ ctrl,
                                              const float4* __restrict__ rois,
                                              u64* __restrict__ cand2,
                                              float4* __restrict__ shifted) {
  __shared__ u64 tilek[256];
  int tid = threadIdx.x;
  u32 gid = blockIdx.x * 256 + (u32)tid;
  u32 total = min(ctrl[C_CANDCNT], (u32)KPAD);
  u64 mykey = (gid < total) ? cand[gid] : ~0ull;
  u32 rank = 0;
  for (u32 base = 0; base < total; base += 256) {
    u32 n = min(256u, total - base);
    __syncthreads();
    if ((u32)tid < n) tilek[tid] = cand[base + (u32)tid];
    __syncthreads();
    if (n == 256u) {
#pragma unroll 8
      for (u32 j = 0; j < 256u; ++j) rank += (tilek[j] < mykey) ? 1u : 0u;
    } else {
      for (u32 j = 0; j < n; ++j) rank += (tilek[j] < mykey) ? 1u : 0u;
    }
  }
  if (gid < total) {
    cand2[rank] = mykey;
    float sep = __fadd_rn(funmap(ctrl[C_SEPMAX]), 1.0f);
    u32 idx = (u32)(mykey & 0x3FFFFu);
    u32 lvl = (u32)((mykey >> 18) & 3u);
    float4 r = rois[idx];
    float sh = __fmul_rn((float)lvl, sep);
    float4 o;
    o.x = __fadd_rn(r.x, sh);
    o.y = __fadd_rn(r.y, sh);
    o.z = __fadd_rn(r.z, sh);
    o.w = __fadd_rn(r.w, sh);
    shifted[rank] = o;
  }
}

// 6) build column-major suppression mask:
//    maskT2[rb*KPAD + j] bit s = suppress(box[rb*64+s], box[j]) && (rb*64+s < j)
//    Writes are coalesced (lane t -> consecutive j). Upper triangle only.
__global__ __launch_bounds__(64) void k_build(const float4* __restrict__ shifted,
                                              u64* __restrict__ maskT2) {
  u32 cb = blockIdx.x, rb = blockIdx.y;
  if (rb > cb) return;
  int t = threadIdx.x;
  __shared__ float4 rbox[64];
  rbox[t] = shifted[rb * 64 + t];
  u32 jg = cb * 64 + (u32)t;
  float4 myc = shifted[jg];
  __syncthreads();
  u64 bits = 0;
  for (int s = 0; s < 64; ++s) {
    if ((rb * 64 + (u32)s) < jg && suppress(rbox[s], myc)) bits |= (1ull << s);
  }
  maskT2[(u64)rb * KPAD + jg] = bits;
}

// 7) single-wave greedy scan: ballot-fixpoint intra-chunk resolution (exact greedy
//    on the s<t DAG), cross-chunk suppression via coalesced column loads ANDed
//    with LDS kept-masks. No per-kept serial chain, no per-kept row loads.
__global__ __launch_bounds__(64) void k_scan(const u64* __restrict__ maskT2,
                                             const u64* __restrict__ cand,
                                             u32* __restrict__ ctrl,
                                             const float2* __restrict__ logits,
                                             const float4* __restrict__ rois,
                                             float* __restrict__ out) {
  __shared__ u64 keptm[NCHUNK];
  __shared__ u32 lkept[NPOST];
  int t = threadIdx.x;
  u32 total = min(ctrl[C_CANDCNT], (u32)KPAD);
  u32 chunks = (total + 63) >> 6;
  u32 kept = 0;
  keptm[t] = 0;
  keptm[64 + t] = 0;
  __syncthreads();
  for (u32 c = 0; c < chunks && kept < NPOST; ++c) {
    const u64* colbase = maskT2 + (u64)c * 64 + (u64)t;  // + ci*KPAD per row-chunk
    u64 diagw = colbase[(u64)c * KPAD];   // bits s<t suppressing t within chunk
    // ---- cross-chunk removed bit: OR over resolved chunks (coalesced loads) ----
    u64 a0 = 0, a1 = 0;
    u32 ci = 0;
    for (; ci + 8 <= c; ci += 8) {
      u64 w0 = colbase[(u64)(ci + 0) * KPAD];
      u64 w1 = colbase[(u64)(ci + 1) * KPAD];
      u64 w2 = colbase[(u64)(ci + 2) * KPAD];
      u64 w3 = colbase[(u64)(ci + 3) * KPAD];
      u64 w4 = colbase[(u64)(ci + 4) * KPAD];
      u64 w5 = colbase[(u64)(ci + 5) * KPAD];
      u64 w6 = colbase[(u64)(ci + 6) * KPAD];
      u64 w7 = colbase[(u64)(ci + 7) * KPAD];
      a0 |= (w0 & keptm[ci + 0]) | (w1 & keptm[ci + 1]) |
            (w2 & keptm[ci + 2]) | (w3 & keptm[ci + 3]);
      a1 |= (w4 & keptm[ci + 4]) | (w5 & keptm[ci + 5]) |
            (w6 & keptm[ci + 6]) | (w7 & keptm[ci + 7]);
    }
    for (; ci < c; ++ci) a0 |= colbase[(u64)ci * KPAD] & keptm[ci];
    bool removed = (a0 | a1) != 0ull;
    u64 w = ~__ballot(removed);
    u32 rem2 = total - c * 64;
    if (rem2 < 64) w &= ((1ull << rem2) - 1ull);
    // ---- intra-chunk greedy via ballot fixpoint (converges in <= depth iters) ----
    u64 keep = w;
    for (int it = 0; it < 64; ++it) {
      bool sup = (diagw & keep) != 0ull;
      u64 nk = w & ~__ballot(sup);
      if (nk == keep) break;     // uniform condition
      keep = nk;
    }
    // ---- parallel record via popcount prefix ----
    u32 pos = kept + (u32)__popcll(keep & ((1ull << t) - 1ull));
    if (((keep >> t) & 1ull) && pos < NPOST) lkept[pos] = c * 64 + (u32)t;
    if (t == 0) keptm[c] = keep;
    kept += (u32)__popcll(keep);
  }
  if (t == 0) ctrl[C_KEPTCNT] = min(kept, (u32)NPOST);
  __syncthreads();
  u32 kn = min(kept, (u32)NPOST);
  // ---- fused output gather (small-box filter + padding) ----
#pragma unroll 4
  for (u32 r = (u32)t; r < NPOST; r += 64) {
    float l0 = 0.f, l1 = 0.f, b0 = 0.f, b1 = 0.f, b2 = 0.f, b3 = 0.f;
    float lvf = -1.0f, vf = 0.0f;
    if (r < kn) {
      u32 pos = lkept[r];
      u64 a = cand[pos];
      u32 idx = (u32)(a & 0x3FFFFu);
      u32 lvl = (u32)((a >> 18) & 3u);
      float4 rb = rois[idx];
      float hs = __fsub_rn(rb.z, rb.x);
      float wsz = __fsub_rn(rb.w, rb.y);
      if (hs >= 1.0f && wsz >= 1.0f) {
        float2 lg = logits[idx];
        l0 = lg.x; l1 = lg.y;
        b0 = rb.x; b1 = rb.y; b2 = rb.z; b3 = rb.w;
        lvf = (float)lvl; vf = 1.0f;
      }
    }
    out[2 * r] = l0;
    out[2 * r + 1] = l1;
    out[2 * NPOST + 4 * r + 0] = b0;
    out[2 * NPOST + 4 * r + 1] = b1;
    out[2 * NPOST + 4 * r + 2] = b2;
    out[2 * NPOST + 4 * r + 3] = b3;
    out[6 * NPOST + r] = lvf;
    out[7 * NPOST + r] = vf;
  }
}

// fallback) sequential greedy NMS (only if ws too small for the mask)
__global__ __launch_bounds__(1024) void k_nms(const float4* __restrict__ shifted,
                                              u32* __restrict__ ctrl, u32* __restrict__ keptpos) {
  __shared__ float4 kbox[NPOST];
  __shared__ u32 wflag[16];
  int tid = threadIdx.x;
  u32 total = min(ctrl[C_CANDCNT], (u32)KPAD);
  int n = 0;
  for (u32 i = 0; i < total; ++i) {
    float4 cur = shifted[i];
    bool sup = false;
    if (tid < n) sup = suppress(kbox[tid], cur);
    int any = __any(sup);
    if ((tid & 63) == 0) wflag[tid >> 6] = (u32)any;
    __syncthreads();
    u32 f = 0;
#pragma unroll
    for (int w = 0; w < 16; ++w) f |= wflag[w];
    if (!f) {
      if (tid == 0) { kbox[n] = cur; keptpos[n] = i; }
      ++n;
    }
    __syncthreads();
    if (n >= NPOST) break;
  }
  if (tid == 0) ctrl[C_KEPTCNT] = (u32)n;
}

// fallback output gather
__global__ void k_out(const u64* __restrict__ cand, const u32* __restrict__ keptpos,
                      const u32* __restrict__ ctrl, const float2* __restrict__ logits,
                      const float4* __restrict__ rois, float* __restrict__ out) {
  int r = blockIdx.x * blockDim.x + threadIdx.x;
  if (r >= NPOST) return;
  u32 kn = ctrl[C_KEPTCNT];
  float l0 = 0.f, l1 = 0.f, r0 = 0.f, r1 = 0.f, r2 = 0.f, r3 = 0.f;
  float lvf = -1.0f, vf = 0.0f;
  if (r < (int)kn) {
    u32 pos = keptpos[r];
    u64 a = cand[pos];
    u32 idx = (u32)(a & 0x3FFFFu);
    u32 lvl = (u32)((a >> 18) & 3u);
    float4 rb = rois[idx];
    float hs = __fsub_rn(rb.z, rb.x);
    float wsz = __fsub_rn(rb.w, rb.y);
    if (hs >= 1.0f && wsz >= 1.0f) {
      float2 lg = logits[idx];
      l0 = lg.x; l1 = lg.y;
      r0 = rb.x; r1 = rb.y; r2 = rb.z; r3 = rb.w;
      lvf = (float)lvl; vf = 1.0f;
    }
  }
  out[2 * r] = l0;
  out[2 * r + 1] = l1;
  out[2 * NPOST + 4 * r + 0] = r0;
  out[2 * NPOST + 4 * r + 1] = r1;
  out[2 * NPOST + 4 * r + 2] = r2;
  out[2 * NPOST + 4 * r + 3] = r3;
  out[6 * NPOST + r] = lvf;
  out[7 * NPOST + r] = vf;
}

extern "C" void kernel_launch(void* const* d_in, const int* in_sizes, int n_in,
                              void* d_out, int out_size, void* d_ws, size_t ws_size,
                              hipStream_t stream) {
  const float* logits = (const float*)d_in[0];
  const float* rois = (const float*)d_in[1];
  const int* levels = (const int*)d_in[2];
  int N = in_sizes[2];

  char* ws = (char*)d_ws;
  u32* sbits = (u32*)(ws + OFF_SBITS);
  u32* hist = (u32*)(ws + OFF_HIST);
  u32* ctrl = (u32*)(ws + OFF_CTRL);
  u32* keptpos = (u32*)(ws + OFF_KEPT);
  u64* tie = (u64*)(ws + OFF_TIE);
  u64* cand = (u64*)(ws + OFF_CAND);
  float4* shifted = (float4*)(ws + OFF_SHIFT);
  u64* cand2 = (u64*)(ws + OFF_CAND2);
  u64* maskT2 = (u64*)(ws + OFF_MASK);

  // hist [1MB,2MB) and ctrl [2MB,2MB+4KB) are contiguous: one memset
  hipMemsetAsync(hist, 0, (1u << 20) + 4096, stream);

  int nb = (N + 255) / 256;
  k_score_hist<<<nb, 256, 0, stream>>>((const float2*)logits, levels, sbits, hist, N);
  k_scan_hi<<<NLVL, 256, 0, stream>>>(hist, ctrl);
  k_compact<<<nb, 256, 0, stream>>>(sbits, levels, (const float4*)rois, ctrl, cand, tie, N);
  k_ties<<<NLVL, 256, 0, stream>>>((const float4*)rois, ctrl, cand, tie);
  k_rank<<<KPAD / 256, 256, 0, stream>>>(cand, ctrl, (const float4*)rois, cand2, shifted);
  if (ws_size >= WS_NEED) {
    dim3 g(KPAD / 64, KPAD / 64);
    k_build<<<g, 64, 0, stream>>>((const float4*)shifted, maskT2);
    k_scan<<<1, 64, 0, stream>>>(maskT2, cand2, ctrl,
                                 (const float2*)logits, (const float4*)rois, (float*)d_out);
  } else {
    k_nms<<<1, 1024, 0, stream>>>(shifted, ctrl, keptpos);
    k_out<<<(NPOST + 255) / 256, 256, 0, stream>>>(cand2, keptpos, ctrl, (const float2*)logits,
                                                   (const float4*)rois, (float*)d_out);
  }
}

// Round 8
// 280.174 us; speedup vs baseline: 2.5811x; 1.3520x over previous
//
#include <hip/hip_runtime.h>
#include <stdint.h>

typedef uint32_t u32;
typedef uint64_t u64;

#define NLVL 4
#define NPRE 2000
#define NPOST 1000
#define KPAD 8192
#define TIE_CAP 4096
#define NCHUNK 128          // chunk count (125 used, padded to 128)

// ws layout (bytes)
#define OFF_SBITS 0u                        // 1 MB  (250K u32)
#define OFF_HIST  (1u<<20)                  // 1 MB  (4*64K u32)  [memset]
#define OFF_CTRL  (2u<<20)                  // 4 KB  [memset, contiguous]
#define OFF_RANK  ((2u<<20) + (4u<<10))     // 32 KB u32[8192] [memset, contiguous]
#define OFF_KEPT  ((2u<<20) + (40u<<10))    // 4 KB  (fallback path only)
#define OFF_TIE   ((2u<<20) + (64u<<10))    // 128 KB u64[4][4096]
#define OFF_CAND  ((2u<<20) + (192u<<10))   // 64 KB u64[8192]  (unsorted)
#define OFF_SHIFT ((2u<<20) + (256u<<10))   // 128 KB float4[8192] (sorted order)
#define OFF_CAND2 ((2u<<20) + (384u<<10))   // 64 KB u64[8192]  (sorted)
#define OFF_MASK  (3u<<20)                  // 8 MB: maskT2[128 row-chunks][8192 cols] u64
#define WS_NEED   ((size_t)(3u<<20) + (size_t)NCHUNK * KPAD * 8u)
#define MEMSET_BYTES ((1u<<20) + (4u<<10) + (32u<<10))   // hist + ctrl + rankbuf

// ctrl word indices
#define C_CANDCNT 0
#define C_KEPTCNT 1
#define C_SEPMAX  2
#define C_P       4   // +lvl  (0xFFFFFFFF = deficient level -> take all)
#define C_RANK    8   // +lvl  (elements needed from bin P)
#define C_TIECNT  12  // +lvl

// ---- monotone float<->u32 map for atomic max over floats ----
__device__ __forceinline__ u32 fmap(float f) {
  u32 u = __float_as_uint(f);
  return (u & 0x80000000u) ? ~u : (u | 0x80000000u);
}
__device__ __forceinline__ float funmap(u32 u) {
  u = (u & 0x80000000u) ? (u & 0x7FFFFFFFu) : ~u;
  return __uint_as_float(u);
}

// ---- replicate XLA-CPU GenerateVF32Exp (Cephes/Eigen-3.3 style) ----
__device__ __forceinline__ float xla_expf(float x) {
  const float kLog2e = 1.44269504088896341f;
  const float kC1 = 0.693359375f;
  const float kC2 = -2.12194440e-4f;
  const float kP0 = 1.9875691500e-4f;
  const float kP1 = 1.3981999507e-3f;
  const float kP2 = 8.3334519073e-3f;
  const float kP3 = 4.1665795894e-2f;
  const float kP4 = 1.6666665459e-1f;
  const float kP5 = 5.0000001201e-1f;
  float xc = fminf(fmaxf(x, -88.3762626647949f), 88.3762626647950f);
  float fx = floorf(fmaf(xc, kLog2e, 0.5f));
  float tmp = __fmul_rn(kC1, fx);
  float z = __fmul_rn(kC2, fx);
  float r = __fsub_rn(xc, tmp);
  r = __fsub_rn(r, z);
  float r2 = __fmul_rn(r, r);
  float y = fmaf(r, kP0, kP1);
  y = fmaf(y, r, kP2);
  y = fmaf(y, r, kP3);
  y = fmaf(y, r, kP4);
  y = fmaf(y, r, kP5);
  y = fmaf(y, r2, r);
  y = __fadd_rn(y, 1.0f);
  int n = (int)fx;
  float two_n = __int_as_float((n + 127) << 23);
  return fmaxf(__fmul_rn(y, two_n), x);
}

// ---- IoU(a,b) > 0.7f, reference's exact f32 op sequence; exactly symmetric ----
__device__ __forceinline__ bool suppress(float4 a, float4 b) {
  float aa = __fmul_rn(__fsub_rn(a.z, a.x), __fsub_rn(a.w, a.y));
  float ab = __fmul_rn(__fsub_rn(b.z, b.x), __fsub_rn(b.w, b.y));
  float lty = fmaxf(a.x, b.x);
  float ltx = fmaxf(a.y, b.y);
  float rby = fminf(a.z, b.z);
  float rbx = fminf(a.w, b.w);
  float why = fmaxf(__fsub_rn(rby, lty), 0.0f);
  float whx = fmaxf(__fsub_rn(rbx, ltx), 0.0f);
  float inter = __fmul_rn(why, whx);
  float uni = __fsub_rn(__fadd_rn(aa, ab), inter);
  float iou = inter / fmaxf(uni, 1e-9f);
  return iou > 0.7f;
}

__device__ __forceinline__ u64 makekey(u32 sbits, u32 lvl, u32 idx) {
  // ascending key == (score desc, level asc, index asc); total order (idx unique)
  return ((u64)(0x7FFFFFFFu - sbits) << 20) | ((u64)lvl << 18) | (u64)idx;
}

// 1) softmax score + hi16 histogram per level
__global__ void k_score_hist(const float2* __restrict__ logits, const int* __restrict__ levels,
                             u32* __restrict__ sbits, u32* __restrict__ hist, int n) {
  int i = blockIdx.x * blockDim.x + threadIdx.x;
  if (i >= n) return;
  float2 lg = logits[i];
  float m = fmaxf(lg.x, lg.y);
  float e0 = xla_expf(__fsub_rn(lg.x, m));
  float e1 = xla_expf(__fsub_rn(lg.y, m));
  float s = e1 / __fadd_rn(e0, e1);   // IEEE div
  u32 b = __float_as_uint(s);
  sbits[i] = b;
  int lv = levels[i];
  atomicAdd(&hist[lv * 65536 + (int)(b >> 16)], 1u);
}

// 2) per-level descending scan of hi16 histogram -> bin P containing rank NPRE,
//    and RANK = #elements needed from inside bin P
__global__ void k_scan_hi(const u32* __restrict__ hist, u32* __restrict__ ctrl) {
  int lvl = blockIdx.x;
  int tid = threadIdx.x;
  const u32* h = hist + lvl * 65536;
  __shared__ u32 part[256];
  u32 s = 0;
  int base = tid * 256;
  for (int b = 0; b < 256; ++b) s += h[base + b];
  part[tid] = s;
  __syncthreads();
  if (tid == 0) {
    const u32 target = NPRE;
    u32 cum = 0, before = 0; int seg = -1;
    for (int t = 255; t >= 0; --t) {
      if (seg < 0 && cum + part[t] >= target) { seg = t; before = cum; }
      cum += part[t];
    }
    if (cum < target) {           // deficient level: take everything at the level
      ctrl[C_P + lvl] = 0xFFFFFFFFu;
      ctrl[C_RANK + lvl] = 0u;
    } else {
      u32 c = before; u32 bin = 0;
      for (int b = seg * 256 + 255; b >= seg * 256; --b) {
        u32 hb = h[b];
        if (c + hb >= target) { bin = (u32)b; break; }
        c += hb;
      }
      ctrl[C_P + lvl] = bin;
      ctrl[C_RANK + lvl] = target - c;   // >=1 needed inside bin P
    }
  }
}

// 3) compact: hi16 above bin P -> cand keys; hi16 == P -> tie keys; sep max
__global__ void k_compact(const u32* __restrict__ sbits, const int* __restrict__ levels,
                          const float4* __restrict__ rois, u32* __restrict__ ctrl,
                          u64* __restrict__ cand, u64* __restrict__ tie, int n) {
  int i = blockIdx.x * blockDim.x + threadIdx.x;
  bool act = i < n;
  u32 b = 0; int lv = 0; u32 P = 0xFFFFFFFEu;
  if (act) {
    b = sbits[i];
    lv = levels[i];
    P = ctrl[C_P + lv];
  }
  u32 mx = 0;
  if (act && (P == 0xFFFFFFFFu || (b >> 16) > P)) {
    u32 p = atomicAdd(&ctrl[C_CANDCNT], 1u);
    if (p < (u32)KPAD) cand[p] = makekey(b, (u32)lv, (u32)i);
    float4 r = rois[i];
    mx = max(max(fmap(r.x), fmap(r.y)), max(fmap(r.z), fmap(r.w)));
  } else if (act && (b >> 16) == P) {
    u32 t = atomicAdd(&ctrl[C_TIECNT + lv], 1u);
    if (t < TIE_CAP) tie[lv * TIE_CAP + t] = makekey(b, (u32)lv, (u32)i);
  }
  for (int o = 32; o; o >>= 1) {
    u32 v = (u32)__shfl_xor((int)mx, o);
    mx = max(mx, v);
  }
  if ((threadIdx.x & 63) == 0 && mx)
    atomicMax(&ctrl[C_SEPMAX], mx);
}

// 4) bin-P resolution: sort bin members by total-order key, take first RANK
__global__ void k_ties(const float4* __restrict__ rois, u32* __restrict__ ctrl,
                       u64* __restrict__ cand, const u64* __restrict__ tie) {
  int lvl = blockIdx.x;
  int tid = threadIdx.x;
  if (ctrl[C_P + lvl] == 0xFFFFFFFFu) return;   // deficient (uniform per block)
  u32 need = ctrl[C_RANK + lvl];
  if (need == 0) return;
  u32 n = min(ctrl[C_TIECNT + lvl], (u32)TIE_CAP);
  u32 m = 2; while (m < n) m <<= 1;
  __shared__ u64 buf[TIE_CAP];
  for (u32 t = tid; t < m; t += 256)
    buf[t] = (t < n) ? tie[lvl * TIE_CAP + t] : ~0ull;
  __syncthreads();
  for (u32 k = 2; k <= m; k <<= 1) {
    for (u32 j = k >> 1; j > 0; j >>= 1) {
      for (u32 p = tid; p < m; p += 256) {
        u32 q = p ^ j;
        if (q > p) {
          u64 a = buf[p], b = buf[q];
          bool desc = (p & k) != 0;
          if (desc ? (a < b) : (a > b)) { buf[p] = b; buf[q] = a; }
        }
      }
      __syncthreads();
    }
  }
  u32 cnt = min(need, n);
  __shared__ u32 basep;
  if (tid == 0) basep = atomicAdd(&ctrl[C_CANDCNT], cnt);
  __syncthreads();
  u32 mx = 0;
  for (u32 t = tid; t < cnt; t += 256) {
    u64 key = buf[t];
    if (basep + t < (u32)KPAD) cand[basep + t] = key;
    u32 idx = (u32)(key & 0x3FFFFu);
    float4 r = rois[idx];
    mx = max(mx, max(max(fmap(r.x), fmap(r.y)), max(fmap(r.z), fmap(r.w))));
  }
  if (mx) atomicMax(&ctrl[C_SEPMAX], mx);
}

// 5a) partial enumeration rank: block (g,h) ranks key-group g (256 keys) against
//     tile super-group h (1024 keys via LDS); atomicAdd partial counts.
//     Grid (32,8) = 256 blocks -> all CUs busy.
__global__ __launch_bounds__(256) void k_rankp(const u64* __restrict__ cand,
                                               const u32* __restrict__ ctrl,
                                               u32* __restrict__ rankbuf) {
  __shared__ u64 tilek[256];
  int tid = threadIdx.x;
  u32 g = blockIdx.x, h = blockIdx.y;
  u32 total = min(ctrl[C_CANDCNT], (u32)KPAD);
  u32 gid = g * 256 + (u32)tid;
  u64 mykey = (gid < total) ? cand[gid] : ~0ull;
  u32 jbeg = h * 1024;
  if (jbeg >= total) return;                 // uniform per block
  u32 jend = min(jbeg + 1024, total);
  u32 cnt = 0;
  for (u32 base = jbeg; base < jend; base += 256) {
    u32 n = min(256u, jend - base);
    __syncthreads();
    if ((u32)tid < n) tilek[tid] = cand[base + (u32)tid];
    __syncthreads();
    if (n == 256u) {
#pragma unroll 8
      for (u32 j = 0; j < 256u; ++j) cnt += (tilek[j] < mykey) ? 1u : 0u;
    } else {
      for (u32 j = 0; j < n; ++j) cnt += (tilek[j] < mykey) ? 1u : 0u;
    }
  }
  if (gid < total && cnt) atomicAdd(&rankbuf[gid], cnt);
}

// 5b) scatter by rank (unique keys -> exact permutation); fused shift-write
__global__ __launch_bounds__(256) void k_scatter(const u64* __restrict__ cand,
                                                 const u32* __restrict__ rankbuf,
                                                 const u32* __restrict__ ctrl,
                                                 const float4* __restrict__ rois,
                                                 u64* __restrict__ cand2,
                                                 float4* __restrict__ shifted) {
  u32 gid = blockIdx.x * 256 + threadIdx.x;
  u32 total = min(ctrl[C_CANDCNT], (u32)KPAD);
  if (gid >= total) return;
  u64 mykey = cand[gid];
  u32 rank = rankbuf[gid];
  cand2[rank] = mykey;
  float sep = __fadd_rn(funmap(ctrl[C_SEPMAX]), 1.0f);
  u32 idx = (u32)(mykey & 0x3FFFFu);
  u32 lvl = (u32)((mykey >> 18) & 3u);
  float4 r = rois[idx];
  float sh = __fmul_rn((float)lvl, sep);
  float4 o;
  o.x = __fadd_rn(r.x, sh);
  o.y = __fadd_rn(r.y, sh);
  o.z = __fadd_rn(r.z, sh);
  o.w = __fadd_rn(r.w, sh);
  shifted[rank] = o;
}

// 6) build column-major suppression mask:
//    maskT2[rb*KPAD + j] bit s = suppress(box[rb*64+s], box[j]) && (rb*64+s < j)
__global__ __launch_bounds__(64) void k_build(const float4* __restrict__ shifted,
                                              u64* __restrict__ maskT2) {
  u32 cb = blockIdx.x, rb = blockIdx.y;
  if (rb > cb) return;
  int t = threadIdx.x;
  __shared__ float4 rbox[64];
  rbox[t] = shifted[rb * 64 + t];
  u32 jg = cb * 64 + (u32)t;
  float4 myc = shifted[jg];
  __syncthreads();
  u64 bits = 0;
  for (int s = 0; s < 64; ++s) {
    if ((rb * 64 + (u32)s) < jg && suppress(rbox[s], myc)) bits |= (1ull << s);
  }
  maskT2[(u64)rb * KPAD + jg] = bits;
}

// 7) single-wave greedy scan: ballot-fixpoint intra-chunk resolution (exact greedy
//    on the s<t DAG), cross-chunk suppression via coalesced column loads ANDed
//    with LDS kept-masks; early exit at NPOST. Fused output gather.
__global__ __launch_bounds__(64) void k_scan(const u64* __restrict__ maskT2,
                                             const u64* __restrict__ cand,
                                             u32* __restrict__ ctrl,
                                             const float2* __restrict__ logits,
                                             const float4* __restrict__ rois,
                                             float* __restrict__ out) {
  __shared__ u64 keptm[NCHUNK];
  __shared__ u32 lkept[NPOST];
  int t = threadIdx.x;
  u32 total = min(ctrl[C_CANDCNT], (u32)KPAD);
  u32 chunks = (total + 63) >> 6;
  u32 kept = 0;
  keptm[t] = 0;
  keptm[64 + t] = 0;
  __syncthreads();
  for (u32 c = 0; c < chunks && kept < NPOST; ++c) {
    const u64* colbase = maskT2 + (u64)c * 64 + (u64)t;  // + ci*KPAD per row-chunk
    u64 diagw = colbase[(u64)c * KPAD];   // bits s<t suppressing t within chunk
    // ---- cross-chunk removed bit: OR over resolved chunks (coalesced loads) ----
    u64 a0 = 0, a1 = 0;
    u32 ci = 0;
    for (; ci + 8 <= c; ci += 8) {
      u64 w0 = colbase[(u64)(ci + 0) * KPAD];
      u64 w1 = colbase[(u64)(ci + 1) * KPAD];
      u64 w2 = colbase[(u64)(ci + 2) * KPAD];
      u64 w3 = colbase[(u64)(ci + 3) * KPAD];
      u64 w4 = colbase[(u64)(ci + 4) * KPAD];
      u64 w5 = colbase[(u64)(ci + 5) * KPAD];
      u64 w6 = colbase[(u64)(ci + 6) * KPAD];
      u64 w7 = colbase[(u64)(ci + 7) * KPAD];
      a0 |= (w0 & keptm[ci + 0]) | (w1 & keptm[ci + 1]) |
            (w2 & keptm[ci + 2]) | (w3 & keptm[ci + 3]);
      a1 |= (w4 & keptm[ci + 4]) | (w5 & keptm[ci + 5]) |
            (w6 & keptm[ci + 6]) | (w7 & keptm[ci + 7]);
    }
    for (; ci < c; ++ci) a0 |= colbase[(u64)ci * KPAD] & keptm[ci];
    bool removed = (a0 | a1) != 0ull;
    u64 w = ~__ballot(removed);
    u32 rem2 = total - c * 64;
    if (rem2 < 64) w &= ((1ull << rem2) - 1ull);
    // ---- intra-chunk greedy via ballot fixpoint (converges in <= depth iters) ----
    u64 keep = w;
    for (int it = 0; it < 64; ++it) {
      bool sup = (diagw & keep) != 0ull;
      u64 nk = w & ~__ballot(sup);
      if (nk == keep) break;     // uniform condition
      keep = nk;
    }
    // ---- parallel record via popcount prefix ----
    u32 pos = kept + (u32)__popcll(keep & ((1ull << t) - 1ull));
    if (((keep >> t) & 1ull) && pos < NPOST) lkept[pos] = c * 64 + (u32)t;
    if (t == 0) keptm[c] = keep;
    kept += (u32)__popcll(keep);
  }
  if (t == 0) ctrl[C_KEPTCNT] = min(kept, (u32)NPOST);
  __syncthreads();
  u32 kn = min(kept, (u32)NPOST);
  // ---- fused output gather (small-box filter + padding) ----
#pragma unroll 4
  for (u32 r = (u32)t; r < NPOST; r += 64) {
    float l0 = 0.f, l1 = 0.f, b0 = 0.f, b1 = 0.f, b2 = 0.f, b3 = 0.f;
    float lvf = -1.0f, vf = 0.0f;
    if (r < kn) {
      u32 pos = lkept[r];
      u64 a = cand[pos];
      u32 idx = (u32)(a & 0x3FFFFu);
      u32 lvl = (u32)((a >> 18) & 3u);
      float4 rb = rois[idx];
      float hs = __fsub_rn(rb.z, rb.x);
      float wsz = __fsub_rn(rb.w, rb.y);
      if (hs >= 1.0f && wsz >= 1.0f) {
        float2 lg = logits[idx];
        l0 = lg.x; l1 = lg.y;
        b0 = rb.x; b1 = rb.y; b2 = rb.z; b3 = rb.w;
        lvf = (float)lvl; vf = 1.0f;
      }
    }
    out[2 * r] = l0;
    out[2 * r + 1] = l1;
    out[2 * NPOST + 4 * r + 0] = b0;
    out[2 * NPOST + 4 * r + 1] = b1;
    out[2 * NPOST + 4 * r + 2] = b2;
    out[2 * NPOST + 4 * r + 3] = b3;
    out[6 * NPOST + r] = lvf;
    out[7 * NPOST + r] = vf;
  }
}

// fallback) sequential greedy NMS (only if ws too small for the mask)
__global__ __launch_bounds__(1024) void k_nms(const float4* __restrict__ shifted,
                                              u32* __restrict__ ctrl, u32* __restrict__ keptpos) {
  __shared__ float4 kbox[NPOST];
  __shared__ u32 wflag[16];
  int tid = threadIdx.x;
  u32 total = min(ctrl[C_CANDCNT], (u32)KPAD);
  int n = 0;
  for (u32 i = 0; i < total; ++i) {
    float4 cur = shifted[i];
    bool sup = false;
    if (tid < n) sup = suppress(kbox[tid], cur);
    int any = __any(sup);
    if ((tid & 63) == 0) wflag[tid >> 6] = (u32)any;
    __syncthreads();
    u32 f = 0;
#pragma unroll
    for (int w = 0; w < 16; ++w) f |= wflag[w];
    if (!f) {
      if (tid == 0) { kbox[n] = cur; keptpos[n] = i; }
      ++n;
    }
    __syncthreads();
    if (n >= NPOST) break;
  }
  if (tid == 0) ctrl[C_KEPTCNT] = (u32)n;
}

// fallback output gather
__global__ void k_out(const u64* __restrict__ cand, const u32* __restrict__ keptpos,
                      const u32* __restrict__ ctrl, const float2* __restrict__ logits,
                      const float4* __restrict__ rois, float* __restrict__ out) {
  int r = blockIdx.x * blockDim.x + threadIdx.x;
  if (r >= NPOST) return;
  u32 kn = ctrl[C_KEPTCNT];
  float l0 = 0.f, l1 = 0.f, r0 = 0.f, r1 = 0.f, r2 = 0.f, r3 = 0.f;
  float lvf = -1.0f, vf = 0.0f;
  if (r < (int)kn) {
    u32 pos = keptpos[r];
    u64 a = cand[pos];
    u32 idx = (u32)(a & 0x3FFFFu);
    u32 lvl = (u32)((a >> 18) & 3u);
    float4 rb = rois[idx];
    float hs = __fsub_rn(rb.z, rb.x);
    float wsz = __fsub_rn(rb.w, rb.y);
    if (hs >= 1.0f && wsz >= 1.0f) {
      float2 lg = logits[idx];
      l0 = lg.x; l1 = lg.y;
      r0 = rb.x; r1 = rb.y; r2 = rb.z; r3 = rb.w;
      lvf = (float)lvl; vf = 1.0f;
    }
  }
  out[2 * r] = l0;
  out[2 * r + 1] = l1;
  out[2 * NPOST + 4 * r + 0] = r0;
  out[2 * NPOST + 4 * r + 1] = r1;
  out[2 * NPOST + 4 * r + 2] = r2;
  out[2 * NPOST + 4 * r + 3] = r3;
  out[6 * NPOST + r] = lvf;
  out[7 * NPOST + r] = vf;
}

extern "C" void kernel_launch(void* const* d_in, const int* in_sizes, int n_in,
                              void* d_out, int out_size, void* d_ws, size_t ws_size,
                              hipStream_t stream) {
  const float* logits = (const float*)d_in[0];
  const float* rois = (const float*)d_in[1];
  const int* levels = (const int*)d_in[2];
  int N = in_sizes[2];

  char* ws = (char*)d_ws;
  u32* sbits = (u32*)(ws + OFF_SBITS);
  u32* hist = (u32*)(ws + OFF_HIST);
  u32* ctrl = (u32*)(ws + OFF_CTRL);
  u32* rankbuf = (u32*)(ws + OFF_RANK);
  u32* keptpos = (u32*)(ws + OFF_KEPT);
  u64* tie = (u64*)(ws + OFF_TIE);
  u64* cand = (u64*)(ws + OFF_CAND);
  float4* shifted = (float4*)(ws + OFF_SHIFT);
  u64* cand2 = (u64*)(ws + OFF_CAND2);
  u64* maskT2 = (u64*)(ws + OFF_MASK);

  // hist [1MB,2MB), ctrl [2MB,2MB+4KB), rankbuf [2MB+4KB,2MB+36KB): one memset
  hipMemsetAsync(hist, 0, MEMSET_BYTES, stream);

  int nb = (N + 255) / 256;
  k_score_hist<<<nb, 256, 0, stream>>>((const float2*)logits, levels, sbits, hist, N);
  k_scan_hi<<<NLVL, 256, 0, stream>>>(hist, ctrl);
  k_compact<<<nb, 256, 0, stream>>>(sbits, levels, (const float4*)rois, ctrl, cand, tie, N);
  k_ties<<<NLVL, 256, 0, stream>>>((const float4*)rois, ctrl, cand, tie);
  {
    dim3 g(KPAD / 256, 8);
    k_rankp<<<g, 256, 0, stream>>>(cand, ctrl, rankbuf);
  }
  k_scatter<<<KPAD / 256, 256, 0, stream>>>(cand, rankbuf, ctrl, (const float4*)rois,
                                            cand2, shifted);
  if (ws_size >= WS_NEED) {
    dim3 g(KPAD / 64, KPAD / 64);
    k_build<<<g, 64, 0, stream>>>((const float4*)shifted, maskT2);
    k_scan<<<1, 64, 0, stream>>>(maskT2, cand2, ctrl,
                                 (const float2*)logits, (const float4*)rois, (float*)d_out);
  } else {
    k_nms<<<1, 1024, 0, stream>>>(shifted, ctrl, keptpos);
    k_out<<<(NPOST + 255) / 256, 256, 0, stream>>>(cand2, keptpos, ctrl, (const float2*)logits,
                                                   (const float4*)rois, (float*)d_out);
  }
}

// Round 9
// 193.703 us; speedup vs baseline: 3.7334x; 1.4464x over previous
//
#include <hip/hip_runtime.h>
#include <stdint.h>

typedef uint32_t u32;
typedef uint64_t u64;

#define NLVL 4
#define NPRE 2000
#define NPOST 1000
#define KPAD 8192
#define TIE_CAP 4096
#define NCHUNK 128          // chunk count (125 used, padded to 128)

// ws layout (bytes)
#define OFF_SBITS 0u                        // 1 MB  (250K u32)
#define OFF_HIST  (1u<<20)                  // 1 MB  (4*64K u32)  [memset]
#define OFF_CTRL  (2u<<20)                  // 4 KB  [memset, contiguous]
#define OFF_RANK  ((2u<<20) + (4u<<10))     // 32 KB u32[8192] [memset, contiguous]
#define OFF_KEPT  ((2u<<20) + (40u<<10))    // 4 KB  (fallback path only)
#define OFF_TIE   ((2u<<20) + (64u<<10))    // 128 KB u64[4][4096]
#define OFF_CAND  ((2u<<20) + (192u<<10))   // 64 KB u64[8192]  (unsorted)
#define OFF_SHIFT ((2u<<20) + (256u<<10))   // 128 KB float4[8192] (sorted order)
#define OFF_CAND2 ((2u<<20) + (384u<<10))   // 64 KB u64[8192]  (sorted)
#define OFF_MASK  (3u<<20)                  // 8 MB: maskT2[128 row-chunks][8192 cols] u64
#define WS_NEED   ((size_t)(3u<<20) + (size_t)NCHUNK * KPAD * 8u)
#define MEMSET_BYTES ((1u<<20) + (4u<<10) + (32u<<10))   // hist + ctrl + rankbuf

// ctrl word indices -- each hot group on its OWN 64B cacheline
#define C_CANDCNT 0    // line 0: block-aggregated adds
#define C_KEPTCNT 1
#define C_SEPMAX  16   // line 1: wave-reduced atomicMax (k_rankp h==0 only)
#define C_P       32   // line 2: read-only broadcast (P[4], RANK[4])
#define C_RANK    36
#define C_TIECNT  48   // line 3: block-aggregated tie adds

// ---- monotone float<->u32 map for atomic max over floats ----
__device__ __forceinline__ u32 fmap(float f) {
  u32 u = __float_as_uint(f);
  return (u & 0x80000000u) ? ~u : (u | 0x80000000u);
}
__device__ __forceinline__ float funmap(u32 u) {
  u = (u & 0x80000000u) ? (u & 0x7FFFFFFFu) : ~u;
  return __uint_as_float(u);
}

// ---- replicate XLA-CPU GenerateVF32Exp (Cephes/Eigen-3.3 style) ----
__device__ __forceinline__ float xla_expf(float x) {
  const float kLog2e = 1.44269504088896341f;
  const float kC1 = 0.693359375f;
  const float kC2 = -2.12194440e-4f;
  const float kP0 = 1.9875691500e-4f;
  const float kP1 = 1.3981999507e-3f;
  const float kP2 = 8.3334519073e-3f;
  const float kP3 = 4.1665795894e-2f;
  const float kP4 = 1.6666665459e-1f;
  const float kP5 = 5.0000001201e-1f;
  float xc = fminf(fmaxf(x, -88.3762626647949f), 88.3762626647950f);
  float fx = floorf(fmaf(xc, kLog2e, 0.5f));
  float tmp = __fmul_rn(kC1, fx);
  float z = __fmul_rn(kC2, fx);
  float r = __fsub_rn(xc, tmp);
  r = __fsub_rn(r, z);
  float r2 = __fmul_rn(r, r);
  float y = fmaf(r, kP0, kP1);
  y = fmaf(y, r, kP2);
  y = fmaf(y, r, kP3);
  y = fmaf(y, r, kP4);
  y = fmaf(y, r, kP5);
  y = fmaf(y, r2, r);
  y = __fadd_rn(y, 1.0f);
  int n = (int)fx;
  float two_n = __int_as_float((n + 127) << 23);
  return fmaxf(__fmul_rn(y, two_n), x);
}

// ---- IoU(a,b) > 0.7f, reference's exact f32 op sequence; exactly symmetric ----
__device__ __forceinline__ bool suppress(float4 a, float4 b) {
  float aa = __fmul_rn(__fsub_rn(a.z, a.x), __fsub_rn(a.w, a.y));
  float ab = __fmul_rn(__fsub_rn(b.z, b.x), __fsub_rn(b.w, b.y));
  float lty = fmaxf(a.x, b.x);
  float ltx = fmaxf(a.y, b.y);
  float rby = fminf(a.z, b.z);
  float rbx = fminf(a.w, b.w);
  float why = fmaxf(__fsub_rn(rby, lty), 0.0f);
  float whx = fmaxf(__fsub_rn(rbx, ltx), 0.0f);
  float inter = __fmul_rn(why, whx);
  float uni = __fsub_rn(__fadd_rn(aa, ab), inter);
  float iou = inter / fmaxf(uni, 1e-9f);
  return iou > 0.7f;
}

__device__ __forceinline__ u64 makekey(u32 sbits, u32 lvl, u32 idx) {
  // ascending key == (score desc, level asc, index asc); total order (idx unique)
  return ((u64)(0x7FFFFFFFu - sbits) << 20) | ((u64)lvl << 18) | (u64)idx;
}

// 1) softmax score + hi16 histogram per level
__global__ void k_score_hist(const float2* __restrict__ logits, const int* __restrict__ levels,
                             u32* __restrict__ sbits, u32* __restrict__ hist, int n) {
  int i = blockIdx.x * blockDim.x + threadIdx.x;
  if (i >= n) return;
  float2 lg = logits[i];
  float m = fmaxf(lg.x, lg.y);
  float e0 = xla_expf(__fsub_rn(lg.x, m));
  float e1 = xla_expf(__fsub_rn(lg.y, m));
  float s = e1 / __fadd_rn(e0, e1);   // IEEE div
  u32 b = __float_as_uint(s);
  sbits[i] = b;
  int lv = levels[i];
  atomicAdd(&hist[lv * 65536 + (int)(b >> 16)], 1u);
}

// 2) per-level descending scan of hi16 histogram -> bin P containing rank NPRE,
//    and RANK = #elements needed from inside bin P
__global__ void k_scan_hi(const u32* __restrict__ hist, u32* __restrict__ ctrl) {
  int lvl = blockIdx.x;
  int tid = threadIdx.x;
  const u32* h = hist + lvl * 65536;
  __shared__ u32 part[256];
  u32 s = 0;
  int base = tid * 256;
  for (int b = 0; b < 256; ++b) s += h[base + b];
  part[tid] = s;
  __syncthreads();
  if (tid == 0) {
    const u32 target = NPRE;
    u32 cum = 0, before = 0; int seg = -1;
    for (int t = 255; t >= 0; --t) {
      if (seg < 0 && cum + part[t] >= target) { seg = t; before = cum; }
      cum += part[t];
    }
    if (cum < target) {           // deficient level: take everything at the level
      ctrl[C_P + lvl] = 0xFFFFFFFFu;
      ctrl[C_RANK + lvl] = 0u;
    } else {
      u32 c = before; u32 bin = 0;
      for (int b = seg * 256 + 255; b >= seg * 256; --b) {
        u32 hb = h[b];
        if (c + hb >= target) { bin = (u32)b; break; }
        c += hb;
      }
      ctrl[C_P + lvl] = bin;
      ctrl[C_RANK + lvl] = target - c;   // >=1 needed inside bin P
    }
  }
}

// 3) compact with BLOCK-AGGREGATED atomics: ballots + popcount prefixes give
//    in-block positions; one atomicAdd(CANDCNT) + <=4 atomicAdd(TIECNT) per block.
//    Set of emitted keys identical to per-thread version (order canonicalized later).
__global__ __launch_bounds__(512) void k_compact(const u32* __restrict__ sbits,
                                                 const int* __restrict__ levels,
                                                 u32* __restrict__ ctrl,
                                                 u64* __restrict__ cand,
                                                 u64* __restrict__ tie, int n) {
  __shared__ u32 wcnt[8], wtieS[8][4];
  __shared__ u32 wbase, tiebase[4];
  int tid = threadIdx.x;
  int wid = tid >> 6, lane = tid & 63;
  int i = blockIdx.x * 512 + tid;
  bool act = i < n;
  u32 b = 0; int lv = 0; u32 P = 0xFFFFFFFEu;
  if (act) {
    b = sbits[i];
    lv = levels[i];
    P = ctrl[C_P + lv];
  }
  bool iscand = act && (P == 0xFFFFFFFFu || (b >> 16) > P);
  bool istie  = act && !iscand && ((b >> 16) == P);
  u64 cb = __ballot(iscand);
  u64 t0 = __ballot(istie && lv == 0);
  u64 t1 = __ballot(istie && lv == 1);
  u64 t2 = __ballot(istie && lv == 2);
  u64 t3 = __ballot(istie && lv == 3);
  if (lane == 0) {
    wcnt[wid] = (u32)__popcll(cb);
    wtieS[wid][0] = (u32)__popcll(t0);
    wtieS[wid][1] = (u32)__popcll(t1);
    wtieS[wid][2] = (u32)__popcll(t2);
    wtieS[wid][3] = (u32)__popcll(t3);
  }
  __syncthreads();
  if (tid == 0) {
    u32 tot = 0;
#pragma unroll
    for (int w = 0; w < 8; ++w) tot += wcnt[w];
    wbase = tot ? atomicAdd(&ctrl[C_CANDCNT], tot) : 0u;
  }
  if (tid < 4) {
    u32 tt = 0;
#pragma unroll
    for (int w = 0; w < 8; ++w) tt += wtieS[w][tid];
    tiebase[tid] = tt ? atomicAdd(&ctrl[C_TIECNT + tid], tt) : 0u;
  }
  __syncthreads();
  u64 lm = (1ull << lane) - 1ull;
  if (iscand) {
    u32 pre = 0;
    for (int w = 0; w < wid; ++w) pre += wcnt[w];
    u32 pos = wbase + pre + (u32)__popcll(cb & lm);
    if (pos < (u32)KPAD) cand[pos] = makekey(b, (u32)lv, (u32)i);
  }
  if (istie) {
    u64 tb = (lv == 0) ? t0 : (lv == 1) ? t1 : (lv == 2) ? t2 : t3;
    u32 pre = 0;
    for (int w = 0; w < wid; ++w) pre += wtieS[w][lv];
    u32 pos = tiebase[lv] + pre + (u32)__popcll(tb & lm);
    if (pos < (u32)TIE_CAP) tie[lv * TIE_CAP + pos] = makekey(b, (u32)lv, (u32)i);
  }
}

// 4) bin-P resolution: sort bin members by total-order key, take first RANK
__global__ void k_ties(u32* __restrict__ ctrl, u64* __restrict__ cand,
                       const u64* __restrict__ tie) {
  int lvl = blockIdx.x;
  int tid = threadIdx.x;
  if (ctrl[C_P + lvl] == 0xFFFFFFFFu) return;   // deficient (uniform per block)
  u32 need = ctrl[C_RANK + lvl];
  if (need == 0) return;
  u32 n = min(ctrl[C_TIECNT + lvl], (u32)TIE_CAP);
  u32 m = 2; while (m < n) m <<= 1;
  __shared__ u64 buf[TIE_CAP];
  for (u32 t = tid; t < m; t += 256)
    buf[t] = (t < n) ? tie[lvl * TIE_CAP + t] : ~0ull;
  __syncthreads();
  for (u32 k = 2; k <= m; k <<= 1) {
    for (u32 j = k >> 1; j > 0; j >>= 1) {
      for (u32 p = tid; p < m; p += 256) {
        u32 q = p ^ j;
        if (q > p) {
          u64 a = buf[p], b = buf[q];
          bool desc = (p & k) != 0;
          if (desc ? (a < b) : (a > b)) { buf[p] = b; buf[q] = a; }
        }
      }
      __syncthreads();
    }
  }
  u32 cnt = min(need, n);
  __shared__ u32 basep;
  if (tid == 0) basep = atomicAdd(&ctrl[C_CANDCNT], cnt);
  __syncthreads();
  for (u32 t = tid; t < cnt; t += 256) {
    if (basep + t < (u32)KPAD) cand[basep + t] = buf[t];
  }
}

// 5a) partial enumeration rank (grid 32x8 = all CUs busy) + sepmax fold-in:
//     h==0 blocks wave-reduce the selected-roi max -> <=128 atomicMax on line 1.
__global__ __launch_bounds__(256) void k_rankp(const u64* __restrict__ cand,
                                               const u32* __restrict__ ctrl,
                                               const float4* __restrict__ rois,
                                               u32* __restrict__ rankbuf,
                                               u32* __restrict__ ctrlw) {
  __shared__ u64 tilek[256];
  int tid = threadIdx.x;
  u32 g = blockIdx.x, h = blockIdx.y;
  u32 total = min(ctrl[C_CANDCNT], (u32)KPAD);
  u32 gid = g * 256 + (u32)tid;
  u64 mykey = (gid < total) ? cand[gid] : ~0ull;
  if (h == 0) {   // sepmax over selected candidates (exact set)
    u32 mx = 0;
    if (gid < total) {
      u32 idx = (u32)(mykey & 0x3FFFFu);
      float4 r = rois[idx];
      mx = max(max(fmap(r.x), fmap(r.y)), max(fmap(r.z), fmap(r.w)));
    }
    for (int o = 32; o; o >>= 1) {
      u32 v = (u32)__shfl_xor((int)mx, o);
      mx = max(mx, v);
    }
    if ((tid & 63) == 0 && mx) atomicMax(&ctrlw[C_SEPMAX], mx);
  }
  u32 jbeg = h * 1024;
  if (jbeg >= total) return;                 // uniform per block
  u32 jend = min(jbeg + 1024, total);
  u32 cnt = 0;
  for (u32 base = jbeg; base < jend; base += 256) {
    u32 n = min(256u, jend - base);
    __syncthreads();
    if ((u32)tid < n) tilek[tid] = cand[base + (u32)tid];
    __syncthreads();
    if (n == 256u) {
#pragma unroll 8
      for (u32 j = 0; j < 256u; ++j) cnt += (tilek[j] < mykey) ? 1u : 0u;
    } else {
      for (u32 j = 0; j < n; ++j) cnt += (tilek[j] < mykey) ? 1u : 0u;
    }
  }
  if (gid < total && cnt) atomicAdd(&rankbuf[gid], cnt);
}

// 5b) scatter by rank (unique keys -> exact permutation); fused shift-write
__global__ __launch_bounds__(256) void k_scatter(const u64* __restrict__ cand,
                                                 const u32* __restrict__ rankbuf,
                                                 const u32* __restrict__ ctrl,
                                                 const float4* __restrict__ rois,
                                                 u64* __restrict__ cand2,
                                                 float4* __restrict__ shifted) {
  u32 gid = blockIdx.x * 256 + threadIdx.x;
  u32 total = min(ctrl[C_CANDCNT], (u32)KPAD);
  if (gid >= total) return;
  u64 mykey = cand[gid];
  u32 rank = rankbuf[gid];
  cand2[rank] = mykey;
  float sep = __fadd_rn(funmap(ctrl[C_SEPMAX]), 1.0f);
  u32 idx = (u32)(mykey & 0x3FFFFu);
  u32 lvl = (u32)((mykey >> 18) & 3u);
  float4 r = rois[idx];
  float sh = __fmul_rn((float)lvl, sep);
  float4 o;
  o.x = __fadd_rn(r.x, sh);
  o.y = __fadd_rn(r.y, sh);
  o.z = __fadd_rn(r.z, sh);
  o.w = __fadd_rn(r.w, sh);
  shifted[rank] = o;
}

// 6) build column-major suppression mask:
//    maskT2[rb*KPAD + j] bit s = suppress(box[rb*64+s], box[j]) && (rb*64+s < j)
__global__ __launch_bounds__(64) void k_build(const float4* __restrict__ shifted,
                                              u64* __restrict__ maskT2) {
  u32 cb = blockIdx.x, rb = blockIdx.y;
  if (rb > cb) return;
  int t = threadIdx.x;
  __shared__ float4 rbox[64];
  rbox[t] = shifted[rb * 64 + t];
  u32 jg = cb * 64 + (u32)t;
  float4 myc = shifted[jg];
  __syncthreads();
  u64 bits = 0;
  for (int s = 0; s < 64; ++s) {
    if ((rb * 64 + (u32)s) < jg && suppress(rbox[s], myc)) bits |= (1ull << s);
  }
  maskT2[(u64)rb * KPAD + jg] = bits;
}

// 7) single-wave greedy scan: ballot-fixpoint intra-chunk resolution (exact greedy
//    on the s<t DAG), cross-chunk suppression via coalesced column loads ANDed
//    with LDS kept-masks; early exit at NPOST. Fused output gather.
__global__ __launch_bounds__(64) void k_scan(const u64* __restrict__ maskT2,
                                             const u64* __restrict__ cand,
                                             u32* __restrict__ ctrl,
                                             const float2* __restrict__ logits,
                                             const float4* __restrict__ rois,
                                             float* __restrict__ out) {
  __shared__ u64 keptm[NCHUNK];
  __shared__ u32 lkept[NPOST];
  int t = threadIdx.x;
  u32 total = min(ctrl[C_CANDCNT], (u32)KPAD);
  u32 chunks = (total + 63) >> 6;
  u32 kept = 0;
  keptm[t] = 0;
  keptm[64 + t] = 0;
  __syncthreads();
  for (u32 c = 0; c < chunks && kept < NPOST; ++c) {
    const u64* colbase = maskT2 + (u64)c * 64 + (u64)t;  // + ci*KPAD per row-chunk
    u64 diagw = colbase[(u64)c * KPAD];   // bits s<t suppressing t within chunk
    // ---- cross-chunk removed bit: OR over resolved chunks (coalesced loads) ----
    u64 a0 = 0, a1 = 0;
    u32 ci = 0;
    for (; ci + 8 <= c; ci += 8) {
      u64 w0 = colbase[(u64)(ci + 0) * KPAD];
      u64 w1 = colbase[(u64)(ci + 1) * KPAD];
      u64 w2 = colbase[(u64)(ci + 2) * KPAD];
      u64 w3 = colbase[(u64)(ci + 3) * KPAD];
      u64 w4 = colbase[(u64)(ci + 4) * KPAD];
      u64 w5 = colbase[(u64)(ci + 5) * KPAD];
      u64 w6 = colbase[(u64)(ci + 6) * KPAD];
      u64 w7 = colbase[(u64)(ci + 7) * KPAD];
      a0 |= (w0 & keptm[ci + 0]) | (w1 & keptm[ci + 1]) |
            (w2 & keptm[ci + 2]) | (w3 & keptm[ci + 3]);
      a1 |= (w4 & keptm[ci + 4]) | (w5 & keptm[ci + 5]) |
            (w6 & keptm[ci + 6]) | (w7 & keptm[ci + 7]);
    }
    for (; ci < c; ++ci) a0 |= colbase[(u64)ci * KPAD] & keptm[ci];
    bool removed = (a0 | a1) != 0ull;
    u64 w = ~__ballot(removed);
    u32 rem2 = total - c * 64;
    if (rem2 < 64) w &= ((1ull << rem2) - 1ull);
    // ---- intra-chunk greedy via ballot fixpoint (converges in <= depth iters) ----
    u64 keep = w;
    for (int it = 0; it < 64; ++it) {
      bool sup = (diagw & keep) != 0ull;
      u64 nk = w & ~__ballot(sup);
      if (nk == keep) break;     // uniform condition
      keep = nk;
    }
    // ---- parallel record via popcount prefix ----
    u32 pos = kept + (u32)__popcll(keep & ((1ull << t) - 1ull));
    if (((keep >> t) & 1ull) && pos < NPOST) lkept[pos] = c * 64 + (u32)t;
    if (t == 0) keptm[c] = keep;
    kept += (u32)__popcll(keep);
  }
  if (t == 0) ctrl[C_KEPTCNT] = min(kept, (u32)NPOST);
  __syncthreads();
  u32 kn = min(kept, (u32)NPOST);
  // ---- fused output gather (small-box filter + padding) ----
#pragma unroll 4
  for (u32 r = (u32)t; r < NPOST; r += 64) {
    float l0 = 0.f, l1 = 0.f, b0 = 0.f, b1 = 0.f, b2 = 0.f, b3 = 0.f;
    float lvf = -1.0f, vf = 0.0f;
    if (r < kn) {
      u32 pos = lkept[r];
      u64 a = cand[pos];
      u32 idx = (u32)(a & 0x3FFFFu);
      u32 lvl = (u32)((a >> 18) & 3u);
      float4 rb = rois[idx];
      float hs = __fsub_rn(rb.z, rb.x);
      float wsz = __fsub_rn(rb.w, rb.y);
      if (hs >= 1.0f && wsz >= 1.0f) {
        float2 lg = logits[idx];
        l0 = lg.x; l1 = lg.y;
        b0 = rb.x; b1 = rb.y; b2 = rb.z; b3 = rb.w;
        lvf = (float)lvl; vf = 1.0f;
      }
    }
    out[2 * r] = l0;
    out[2 * r + 1] = l1;
    out[2 * NPOST + 4 * r + 0] = b0;
    out[2 * NPOST + 4 * r + 1] = b1;
    out[2 * NPOST + 4 * r + 2] = b2;
    out[2 * NPOST + 4 * r + 3] = b3;
    out[6 * NPOST + r] = lvf;
    out[7 * NPOST + r] = vf;
  }
}

// fallback) sequential greedy NMS (only if ws too small for the mask)
__global__ __launch_bounds__(1024) void k_nms(const float4* __restrict__ shifted,
                                              u32* __restrict__ ctrl, u32* __restrict__ keptpos) {
  __shared__ float4 kbox[NPOST];
  __shared__ u32 wflag[16];
  int tid = threadIdx.x;
  u32 total = min(ctrl[C_CANDCNT], (u32)KPAD);
  int n = 0;
  for (u32 i = 0; i < total; ++i) {
    float4 cur = shifted[i];
    bool sup = false;
    if (tid < n) sup = suppress(kbox[tid], cur);
    int any = __any(sup);
    if ((tid & 63) == 0) wflag[tid >> 6] = (u32)any;
    __syncthreads();
    u32 f = 0;
#pragma unroll
    for (int w = 0; w < 16; ++w) f |= wflag[w];
    if (!f) {
      if (tid == 0) { kbox[n] = cur; keptpos[n] = i; }
      ++n;
    }
    __syncthreads();
    if (n >= NPOST) break;
  }
  if (tid == 0) ctrl[C_KEPTCNT] = (u32)n;
}

// fallback output gather
__global__ void k_out(const u64* __restrict__ cand, const u32* __restrict__ keptpos,
                      const u32* __restrict__ ctrl, const float2* __restrict__ logits,
                      const float4* __restrict__ rois, float* __restrict__ out) {
  int r = blockIdx.x * blockDim.x + threadIdx.x;
  if (r >= NPOST) return;
  u32 kn = ctrl[C_KEPTCNT];
  float l0 = 0.f, l1 = 0.f, r0 = 0.f, r1 = 0.f, r2 = 0.f, r3 = 0.f;
  float lvf = -1.0f, vf = 0.0f;
  if (r < (int)kn) {
    u32 pos = keptpos[r];
    u64 a = cand[pos];
    u32 idx = (u32)(a & 0x3FFFFu);
    u32 lvl = (u32)((a >> 18) & 3u);
    float4 rb = rois[idx];
    float hs = __fsub_rn(rb.z, rb.x);
    float wsz = __fsub_rn(rb.w, rb.y);
    if (hs >= 1.0f && wsz >= 1.0f) {
      float2 lg = logits[idx];
      l0 = lg.x; l1 = lg.y;
      r0 = rb.x; r1 = rb.y; r2 = rb.z; r3 = rb.w;
      lvf = (float)lvl; vf = 1.0f;
    }
  }
  out[2 * r] = l0;
  out[2 * r + 1] = l1;
  out[2 * NPOST + 4 * r + 0] = r0;
  out[2 * NPOST + 4 * r + 1] = r1;
  out[2 * NPOST + 4 * r + 2] = r2;
  out[2 * NPOST + 4 * r + 3] = r3;
  out[6 * NPOST + r] = lvf;
  out[7 * NPOST + r] = vf;
}

extern "C" void kernel_launch(void* const* d_in, const int* in_sizes, int n_in,
                              void* d_out, int out_size, void* d_ws, size_t ws_size,
                              hipStream_t stream) {
  const float* logits = (const float*)d_in[0];
  const float* rois = (const float*)d_in[1];
  const int* levels = (const int*)d_in[2];
  int N = in_sizes[2];

  char* ws = (char*)d_ws;
  u32* sbits = (u32*)(ws + OFF_SBITS);
  u32* hist = (u32*)(ws + OFF_HIST);
  u32* ctrl = (u32*)(ws + OFF_CTRL);
  u32* rankbuf = (u32*)(ws + OFF_RANK);
  u32* keptpos = (u32*)(ws + OFF_KEPT);
  u64* tie = (u64*)(ws + OFF_TIE);
  u64* cand = (u64*)(ws + OFF_CAND);
  float4* shifted = (float4*)(ws + OFF_SHIFT);
  u64* cand2 = (u64*)(ws + OFF_CAND2);
  u64* maskT2 = (u64*)(ws + OFF_MASK);

  // hist [1MB,2MB), ctrl [2MB,2MB+4KB), rankbuf [2MB+4KB,2MB+36KB): one memset
  hipMemsetAsync(hist, 0, MEMSET_BYTES, stream);

  int nb = (N + 255) / 256;
  int nb2 = (N + 511) / 512;
  k_score_hist<<<nb, 256, 0, stream>>>((const float2*)logits, levels, sbits, hist, N);
  k_scan_hi<<<NLVL, 256, 0, stream>>>(hist, ctrl);
  k_compact<<<nb2, 512, 0, stream>>>(sbits, levels, ctrl, cand, tie, N);
  k_ties<<<NLVL, 256, 0, stream>>>(ctrl, cand, tie);
  {
    dim3 g(KPAD / 256, 8);
    k_rankp<<<g, 256, 0, stream>>>(cand, ctrl, (const float4*)rois, rankbuf, ctrl);
  }
  k_scatter<<<KPAD / 256, 256, 0, stream>>>(cand, rankbuf, ctrl, (const float4*)rois,
                                            cand2, shifted);
  if (ws_size >= WS_NEED) {
    dim3 g(KPAD / 64, KPAD / 64);
    k_build<<<g, 64, 0, stream>>>((const float4*)shifted, maskT2);
    k_scan<<<1, 64, 0, stream>>>(maskT2, cand2, ctrl,
                                 (const float2*)logits, (const float4*)rois, (float*)d_out);
  } else {
    k_nms<<<1, 1024, 0, stream>>>(shifted, ctrl, keptpos);
    k_out<<<(NPOST + 255) / 256, 256, 0, stream>>>(cand2, keptpos, ctrl, (const float2*)logits,
                                                   (const float4*)rois, (float*)d_out);
  }
}

// Round 10
// 152.291 us; speedup vs baseline: 4.7486x; 1.2719x over previous
//
#include <hip/hip_runtime.h>
#include <stdint.h>

typedef uint32_t u32;
typedef uint64_t u64;

#define NLVL 4
#define NPRE 2000
#define NPOST 1000
#define KPAD 8192
#define TIE_CAP 4096
#define NCHUNK 128          // chunk count (125 used, padded to 128)

// ws layout (bytes)
#define OFF_SBITS 0u                        // 1 MB  (250K u32)
#define OFF_CTRL  (2u<<20)                  // 4 KB  [memset]
#define OFF_RANK  ((2u<<20) + (4u<<10))     // 32 KB u32[8192] [memset, contiguous]
#define OFF_H1    ((2u<<20) + (36u<<10))    // 4 KB  u32[4][256] exponent hist [memset]
#define OFF_HM    ((2u<<20) + (40u<<10))    // 4 KB  u32[4][256] mantissa hist [memset]
#define OFF_KEPT  ((2u<<20) + (48u<<10))    // 4 KB  (fallback path only)
#define OFF_TIE   ((2u<<20) + (64u<<10))    // 128 KB u64[4][4096]
#define OFF_CAND  ((2u<<20) + (192u<<10))   // 64 KB u64[8192]  (unsorted)
#define OFF_SHIFT ((2u<<20) + (256u<<10))   // 128 KB float4[8192] (sorted order)
#define OFF_CAND2 ((2u<<20) + (384u<<10))   // 64 KB u64[8192]  (sorted)
#define OFF_MASK  (3u<<20)                  // 8 MB: maskT2[128 row-chunks][8192 cols] u64
#define WS_NEED   ((size_t)(3u<<20) + (size_t)NCHUNK * KPAD * 8u)
#define MEMSET_BYTES ((44u<<10))            // ctrl + rankbuf + h1 + hm (from OFF_CTRL)

// ctrl word indices -- each hot group on its OWN 64B cacheline
#define C_CANDCNT 0    // line 0: block-aggregated adds
#define C_KEPTCNT 1
#define C_SEPMAX  16   // line 1: wave-reduced atomicMax (k_rankp h==0 only)
#define C_P       32   // line 2: read-only threshold (b>>15 value) + RANK
#define C_RANK    36
#define C_TIECNT  48   // line 3: block-aggregated tie adds
#define C_E       64   // line 4: exponent bin + residual rank
#define C_RANK1   68

// ---- monotone float<->u32 map for atomic max over floats ----
__device__ __forceinline__ u32 fmap(float f) {
  u32 u = __float_as_uint(f);
  return (u & 0x80000000u) ? ~u : (u | 0x80000000u);
}
__device__ __forceinline__ float funmap(u32 u) {
  u = (u & 0x80000000u) ? (u & 0x7FFFFFFFu) : ~u;
  return __uint_as_float(u);
}

// ---- replicate XLA-CPU GenerateVF32Exp (Cephes/Eigen-3.3 style) ----
__device__ __forceinline__ float xla_expf(float x) {
  const float kLog2e = 1.44269504088896341f;
  const float kC1 = 0.693359375f;
  const float kC2 = -2.12194440e-4f;
  const float kP0 = 1.9875691500e-4f;
  const float kP1 = 1.3981999507e-3f;
  const float kP2 = 8.3334519073e-3f;
  const float kP3 = 4.1665795894e-2f;
  const float kP4 = 1.6666665459e-1f;
  const float kP5 = 5.0000001201e-1f;
  float xc = fminf(fmaxf(x, -88.3762626647949f), 88.3762626647950f);
  float fx = floorf(fmaf(xc, kLog2e, 0.5f));
  float tmp = __fmul_rn(kC1, fx);
  float z = __fmul_rn(kC2, fx);
  float r = __fsub_rn(xc, tmp);
  r = __fsub_rn(r, z);
  float r2 = __fmul_rn(r, r);
  float y = fmaf(r, kP0, kP1);
  y = fmaf(y, r, kP2);
  y = fmaf(y, r, kP3);
  y = fmaf(y, r, kP4);
  y = fmaf(y, r, kP5);
  y = fmaf(y, r2, r);
  y = __fadd_rn(y, 1.0f);
  int n = (int)fx;
  float two_n = __int_as_float((n + 127) << 23);
  return fmaxf(__fmul_rn(y, two_n), x);
}

// ---- IoU(a,b) > 0.7f, reference's exact f32 op sequence; exactly symmetric ----
__device__ __forceinline__ bool suppress(float4 a, float4 b) {
  float aa = __fmul_rn(__fsub_rn(a.z, a.x), __fsub_rn(a.w, a.y));
  float ab = __fmul_rn(__fsub_rn(b.z, b.x), __fsub_rn(b.w, b.y));
  float lty = fmaxf(a.x, b.x);
  float ltx = fmaxf(a.y, b.y);
  float rby = fminf(a.z, b.z);
  float rbx = fminf(a.w, b.w);
  float why = fmaxf(__fsub_rn(rby, lty), 0.0f);
  float whx = fmaxf(__fsub_rn(rbx, ltx), 0.0f);
  float inter = __fmul_rn(why, whx);
  float uni = __fsub_rn(__fadd_rn(aa, ab), inter);
  float iou = inter / fmaxf(uni, 1e-9f);
  return iou > 0.7f;
}

__device__ __forceinline__ u64 makekey(u32 sbits, u32 lvl, u32 idx) {
  // ascending key == (score desc, level asc, index asc); total order (idx unique)
  return ((u64)(0x7FFFFFFFu - sbits) << 20) | ((u64)lvl << 18) | (u64)idx;
}

// 1) softmax score + LDS-aggregated exponent histogram (4KB global footprint)
__global__ __launch_bounds__(512) void k_score_hist(const float2* __restrict__ logits,
                                                    const int* __restrict__ levels,
                                                    u32* __restrict__ sbits,
                                                    u32* __restrict__ hist1, int n) {
  __shared__ u32 lh[NLVL * 256];
  int tid = threadIdx.x;
  for (int p = tid; p < NLVL * 256; p += 512) lh[p] = 0;
  __syncthreads();
  int i = blockIdx.x * 512 + tid;
  if (i < n) {
    float2 lg = logits[i];
    float m = fmaxf(lg.x, lg.y);
    float e0 = xla_expf(__fsub_rn(lg.x, m));
    float e1 = xla_expf(__fsub_rn(lg.y, m));
    float s = e1 / __fadd_rn(e0, e1);   // IEEE div
    u32 b = __float_as_uint(s);
    sbits[i] = b;
    int lv = levels[i];
    atomicAdd(&lh[lv * 256 + (int)((b >> 23) & 0xFFu)], 1u);
  }
  __syncthreads();
  for (int p = tid; p < NLVL * 256; p += 512) {
    u32 v = lh[p];
    if (v) atomicAdd(&hist1[p], v);
  }
}

// 2) exponent-level descending scan -> bin E containing rank NPRE, residual RANK1
__global__ void k_scan_e(const u32* __restrict__ hist1, u32* __restrict__ ctrl) {
  int lvl = blockIdx.x;
  if (threadIdx.x != 0) return;
  const u32* h = hist1 + lvl * 256;
  const u32 target = NPRE;
  u32 cum = 0, before = 0; int E = -1;
  for (int b2 = 255; b2 >= 0; --b2) {
    u32 hb = h[b2];
    if (E < 0 && cum + hb >= target) { E = b2; before = cum; }
    cum += hb;
  }
  if (cum < target) {            // deficient level: take everything at the level
    ctrl[C_E + lvl] = 0xFFFFFFFFu;
    ctrl[C_P + lvl] = 0xFFFFFFFFu;
    ctrl[C_RANK + lvl] = 0u;
  } else {
    ctrl[C_E + lvl] = (u32)E;
    ctrl[C_RANK1 + lvl] = target - before;   // >=1 needed inside exponent bin E
  }
}

// 3) mantissa histogram (bits 22:15) restricted to exp==E; LDS-aggregated
__global__ __launch_bounds__(512) void k_hist_m(const u32* __restrict__ sbits,
                                                const int* __restrict__ levels,
                                                const u32* __restrict__ ctrl,
                                                u32* __restrict__ histm, int n) {
  __shared__ u32 lh[NLVL * 256];
  int tid = threadIdx.x;
  for (int p = tid; p < NLVL * 256; p += 512) lh[p] = 0;
  __syncthreads();
  int i = blockIdx.x * 512 + tid;
  if (i < n) {
    u32 b = sbits[i];
    int lv = levels[i];
    if (((b >> 23) & 0xFFu) == ctrl[C_E + lv])
      atomicAdd(&lh[lv * 256 + (int)((b >> 15) & 0xFFu)], 1u);
  }
  __syncthreads();
  for (int p = tid; p < NLVL * 256; p += 512) {
    u32 v = lh[p];
    if (v) atomicAdd(&histm[p], v);
  }
}

// 4) mantissa-level descending scan -> final threshold P=(E<<8)|M at b>>15, RANK
__global__ void k_scan_m(const u32* __restrict__ histm, u32* __restrict__ ctrl) {
  int lvl = blockIdx.x;
  if (threadIdx.x != 0) return;
  u32 E = ctrl[C_E + lvl];
  if (E == 0xFFFFFFFFu) return;   // deficient handled
  const u32* h = histm + lvl * 256;
  u32 target = ctrl[C_RANK1 + lvl];
  u32 cum = 0, before = 0; int M = 0;
  for (int b2 = 255; b2 >= 0; --b2) {
    u32 hb = h[b2];
    if (cum + hb >= target) { M = b2; before = cum; break; }
    cum += hb;
  }
  ctrl[C_P + lvl] = (E << 8) | (u32)M;
  ctrl[C_RANK + lvl] = target - before;    // >=1 needed inside threshold bin
}

// 5) compact with BLOCK-AGGREGATED atomics (K = b>>15 vs threshold P)
__global__ __launch_bounds__(512) void k_compact(const u32* __restrict__ sbits,
                                                 const int* __restrict__ levels,
                                                 u32* __restrict__ ctrl,
                                                 u64* __restrict__ cand,
                                                 u64* __restrict__ tie, int n) {
  __shared__ u32 wcnt[8], wtieS[8][4];
  __shared__ u32 wbase, tiebase[4];
  int tid = threadIdx.x;
  int wid = tid >> 6, lane = tid & 63;
  int i = blockIdx.x * 512 + tid;
  bool act = i < n;
  u32 b = 0; int lv = 0; u32 P = 0xFFFFFFFEu;
  if (act) {
    b = sbits[i];
    lv = levels[i];
    P = ctrl[C_P + lv];
  }
  u32 K = b >> 15;
  bool iscand = act && (P == 0xFFFFFFFFu || K > P);
  bool istie  = act && !iscand && (K == P);
  u64 cb = __ballot(iscand);
  u64 t0 = __ballot(istie && lv == 0);
  u64 t1 = __ballot(istie && lv == 1);
  u64 t2 = __ballot(istie && lv == 2);
  u64 t3 = __ballot(istie && lv == 3);
  if (lane == 0) {
    wcnt[wid] = (u32)__popcll(cb);
    wtieS[wid][0] = (u32)__popcll(t0);
    wtieS[wid][1] = (u32)__popcll(t1);
    wtieS[wid][2] = (u32)__popcll(t2);
    wtieS[wid][3] = (u32)__popcll(t3);
  }
  __syncthreads();
  if (tid == 0) {
    u32 tot = 0;
#pragma unroll
    for (int w = 0; w < 8; ++w) tot += wcnt[w];
    wbase = tot ? atomicAdd(&ctrl[C_CANDCNT], tot) : 0u;
  }
  if (tid < 4) {
    u32 tt = 0;
#pragma unroll
    for (int w = 0; w < 8; ++w) tt += wtieS[w][tid];
    tiebase[tid] = tt ? atomicAdd(&ctrl[C_TIECNT + tid], tt) : 0u;
  }
  __syncthreads();
  u64 lm = (1ull << lane) - 1ull;
  if (iscand) {
    u32 pre = 0;
    for (int w = 0; w < wid; ++w) pre += wcnt[w];
    u32 pos = wbase + pre + (u32)__popcll(cb & lm);
    if (pos < (u32)KPAD) cand[pos] = makekey(b, (u32)lv, (u32)i);
  }
  if (istie) {
    u64 tb = (lv == 0) ? t0 : (lv == 1) ? t1 : (lv == 2) ? t2 : t3;
    u32 pre = 0;
    for (int w = 0; w < wid; ++w) pre += wtieS[w][lv];
    u32 pos = tiebase[lv] + pre + (u32)__popcll(tb & lm);
    if (pos < (u32)TIE_CAP) tie[lv * TIE_CAP + pos] = makekey(b, (u32)lv, (u32)i);
  }
}

// 6) bin-P resolution: sort bin members by total-order key, take first RANK
__global__ void k_ties(u32* __restrict__ ctrl, u64* __restrict__ cand,
                       const u64* __restrict__ tie) {
  int lvl = blockIdx.x;
  int tid = threadIdx.x;
  if (ctrl[C_P + lvl] == 0xFFFFFFFFu) return;   // deficient (uniform per block)
  u32 need = ctrl[C_RANK + lvl];
  if (need == 0) return;
  u32 n = min(ctrl[C_TIECNT + lvl], (u32)TIE_CAP);
  u32 m = 2; while (m < n) m <<= 1;
  __shared__ u64 buf[TIE_CAP];
  for (u32 t = tid; t < m; t += 256)
    buf[t] = (t < n) ? tie[lvl * TIE_CAP + t] : ~0ull;
  __syncthreads();
  for (u32 k = 2; k <= m; k <<= 1) {
    for (u32 j = k >> 1; j > 0; j >>= 1) {
      for (u32 p = tid; p < m; p += 256) {
        u32 q = p ^ j;
        if (q > p) {
          u64 a = buf[p], b = buf[q];
          bool desc = (p & k) != 0;
          if (desc ? (a < b) : (a > b)) { buf[p] = b; buf[q] = a; }
        }
      }
      __syncthreads();
    }
  }
  u32 cnt = min(need, n);
  __shared__ u32 basep;
  if (tid == 0) basep = atomicAdd(&ctrl[C_CANDCNT], cnt);
  __syncthreads();
  for (u32 t = tid; t < cnt; t += 256) {
    if (basep + t < (u32)KPAD) cand[basep + t] = buf[t];
  }
}

// 7a) partial enumeration rank (grid 32x8 = all CUs busy) + sepmax fold-in
__global__ __launch_bounds__(256) void k_rankp(const u64* __restrict__ cand,
                                               const u32* __restrict__ ctrl,
                                               const float4* __restrict__ rois,
                                               u32* __restrict__ rankbuf,
                                               u32* __restrict__ ctrlw) {
  __shared__ u64 tilek[256];
  int tid = threadIdx.x;
  u32 g = blockIdx.x, h = blockIdx.y;
  u32 total = min(ctrl[C_CANDCNT], (u32)KPAD);
  u32 gid = g * 256 + (u32)tid;
  u64 mykey = (gid < total) ? cand[gid] : ~0ull;
  if (h == 0) {   // sepmax over selected candidates (exact set)
    u32 mx = 0;
    if (gid < total) {
      u32 idx = (u32)(mykey & 0x3FFFFu);
      float4 r = rois[idx];
      mx = max(max(fmap(r.x), fmap(r.y)), max(fmap(r.z), fmap(r.w)));
    }
    for (int o = 32; o; o >>= 1) {
      u32 v = (u32)__shfl_xor((int)mx, o);
      mx = max(mx, v);
    }
    if ((tid & 63) == 0 && mx) atomicMax(&ctrlw[C_SEPMAX], mx);
  }
  u32 jbeg = h * 1024;
  if (jbeg >= total) return;                 // uniform per block
  u32 jend = min(jbeg + 1024, total);
  u32 cnt = 0;
  for (u32 base = jbeg; base < jend; base += 256) {
    u32 n = min(256u, jend - base);
    __syncthreads();
    if ((u32)tid < n) tilek[tid] = cand[base + (u32)tid];
    __syncthreads();
    if (n == 256u) {
#pragma unroll 8
      for (u32 j = 0; j < 256u; ++j) cnt += (tilek[j] < mykey) ? 1u : 0u;
    } else {
      for (u32 j = 0; j < n; ++j) cnt += (tilek[j] < mykey) ? 1u : 0u;
    }
  }
  if (gid < total && cnt) atomicAdd(&rankbuf[gid], cnt);
}

// 7b) scatter by rank (unique keys -> exact permutation); fused shift-write
__global__ __launch_bounds__(256) void k_scatter(const u64* __restrict__ cand,
                                                 const u32* __restrict__ rankbuf,
                                                 const u32* __restrict__ ctrl,
                                                 const float4* __restrict__ rois,
                                                 u64* __restrict__ cand2,
                                                 float4* __restrict__ shifted) {
  u32 gid = blockIdx.x * 256 + threadIdx.x;
  u32 total = min(ctrl[C_CANDCNT], (u32)KPAD);
  if (gid >= total) return;
  u64 mykey = cand[gid];
  u32 rank = rankbuf[gid];
  cand2[rank] = mykey;
  float sep = __fadd_rn(funmap(ctrl[C_SEPMAX]), 1.0f);
  u32 idx = (u32)(mykey & 0x3FFFFu);
  u32 lvl = (u32)((mykey >> 18) & 3u);
  float4 r = rois[idx];
  float sh = __fmul_rn((float)lvl, sep);
  float4 o;
  o.x = __fadd_rn(r.x, sh);
  o.y = __fadd_rn(r.y, sh);
  o.z = __fadd_rn(r.z, sh);
  o.w = __fadd_rn(r.w, sh);
  shifted[rank] = o;
}

// 8) build column-major suppression mask:
//    maskT2[rb*KPAD + j] bit s = suppress(box[rb*64+s], box[j]) && (rb*64+s < j)
__global__ __launch_bounds__(64) void k_build(const float4* __restrict__ shifted,
                                              u64* __restrict__ maskT2) {
  u32 cb = blockIdx.x, rb = blockIdx.y;
  if (rb > cb) return;
  int t = threadIdx.x;
  __shared__ float4 rbox[64];
  rbox[t] = shifted[rb * 64 + t];
  u32 jg = cb * 64 + (u32)t;
  float4 myc = shifted[jg];
  __syncthreads();
  u64 bits = 0;
  for (int s = 0; s < 64; ++s) {
    if ((rb * 64 + (u32)s) < jg && suppress(rbox[s], myc)) bits |= (1ull << s);
  }
  maskT2[(u64)rb * KPAD + jg] = bits;
}

// 9) single-wave greedy scan: ballot-fixpoint intra-chunk resolution (exact greedy
//    on the s<t DAG), cross-chunk suppression via coalesced column loads ANDed
//    with LDS kept-masks; early exit at NPOST. Fused output gather.
__global__ __launch_bounds__(64) void k_scan(const u64* __restrict__ maskT2,
                                             const u64* __restrict__ cand,
                                             u32* __restrict__ ctrl,
                                             const float2* __restrict__ logits,
                                             const float4* __restrict__ rois,
                                             float* __restrict__ out) {
  __shared__ u64 keptm[NCHUNK];
  __shared__ u32 lkept[NPOST];
  int t = threadIdx.x;
  u32 total = min(ctrl[C_CANDCNT], (u32)KPAD);
  u32 chunks = (total + 63) >> 6;
  u32 kept = 0;
  keptm[t] = 0;
  keptm[64 + t] = 0;
  __syncthreads();
  for (u32 c = 0; c < chunks && kept < NPOST; ++c) {
    const u64* colbase = maskT2 + (u64)c * 64 + (u64)t;  // + ci*KPAD per row-chunk
    u64 diagw = colbase[(u64)c * KPAD];   // bits s<t suppressing t within chunk
    // ---- cross-chunk removed bit: OR over resolved chunks (coalesced loads) ----
    u64 a0 = 0, a1 = 0;
    u32 ci = 0;
    for (; ci + 8 <= c; ci += 8) {
      u64 w0 = colbase[(u64)(ci + 0) * KPAD];
      u64 w1 = colbase[(u64)(ci + 1) * KPAD];
      u64 w2 = colbase[(u64)(ci + 2) * KPAD];
      u64 w3 = colbase[(u64)(ci + 3) * KPAD];
      u64 w4 = colbase[(u64)(ci + 4) * KPAD];
      u64 w5 = colbase[(u64)(ci + 5) * KPAD];
      u64 w6 = colbase[(u64)(ci + 6) * KPAD];
      u64 w7 = colbase[(u64)(ci + 7) * KPAD];
      a0 |= (w0 & keptm[ci + 0]) | (w1 & keptm[ci + 1]) |
            (w2 & keptm[ci + 2]) | (w3 & keptm[ci + 3]);
      a1 |= (w4 & keptm[ci + 4]) | (w5 & keptm[ci + 5]) |
            (w6 & keptm[ci + 6]) | (w7 & keptm[ci + 7]);
    }
    for (; ci < c; ++ci) a0 |= colbase[(u64)ci * KPAD] & keptm[ci];
    bool removed = (a0 | a1) != 0ull;
    u64 w = ~__ballot(removed);
    u32 rem2 = total - c * 64;
    if (rem2 < 64) w &= ((1ull << rem2) - 1ull);
    // ---- intra-chunk greedy via ballot fixpoint (converges in <= depth iters) ----
    u64 keep = w;
    for (int it = 0; it < 64; ++it) {
      bool sup = (diagw & keep) != 0ull;
      u64 nk = w & ~__ballot(sup);
      if (nk == keep) break;     // uniform condition
      keep = nk;
    }
    // ---- parallel record via popcount prefix ----
    u32 pos = kept + (u32)__popcll(keep & ((1ull << t) - 1ull));
    if (((keep >> t) & 1ull) && pos < NPOST) lkept[pos] = c * 64 + (u32)t;
    if (t == 0) keptm[c] = keep;
    kept += (u32)__popcll(keep);
  }
  if (t == 0) ctrl[C_KEPTCNT] = min(kept, (u32)NPOST);
  __syncthreads();
  u32 kn = min(kept, (u32)NPOST);
  // ---- fused output gather (small-box filter + padding) ----
#pragma unroll 4
  for (u32 r = (u32)t; r < NPOST; r += 64) {
    float l0 = 0.f, l1 = 0.f, b0 = 0.f, b1 = 0.f, b2 = 0.f, b3 = 0.f;
    float lvf = -1.0f, vf = 0.0f;
    if (r < kn) {
      u32 pos = lkept[r];
      u64 a = cand[pos];
      u32 idx = (u32)(a & 0x3FFFFu);
      u32 lvl = (u32)((a >> 18) & 3u);
      float4 rb = rois[idx];
      float hs = __fsub_rn(rb.z, rb.x);
      float wsz = __fsub_rn(rb.w, rb.y);
      if (hs >= 1.0f && wsz >= 1.0f) {
        float2 lg = logits[idx];
        l0 = lg.x; l1 = lg.y;
        b0 = rb.x; b1 = rb.y; b2 = rb.z; b3 = rb.w;
        lvf = (float)lvl; vf = 1.0f;
      }
    }
    out[2 * r] = l0;
    out[2 * r + 1] = l1;
    out[2 * NPOST + 4 * r + 0] = b0;
    out[2 * NPOST + 4 * r + 1] = b1;
    out[2 * NPOST + 4 * r + 2] = b2;
    out[2 * NPOST + 4 * r + 3] = b3;
    out[6 * NPOST + r] = lvf;
    out[7 * NPOST + r] = vf;
  }
}

// fallback) sequential greedy NMS (only if ws too small for the mask)
__global__ __launch_bounds__(1024) void k_nms(const float4* __restrict__ shifted,
                                              u32* __restrict__ ctrl, u32* __restrict__ keptpos) {
  __shared__ float4 kbox[NPOST];
  __shared__ u32 wflag[16];
  int tid = threadIdx.x;
  u32 total = min(ctrl[C_CANDCNT], (u32)KPAD);
  int n = 0;
  for (u32 i = 0; i < total; ++i) {
    float4 cur = shifted[i];
    bool sup = false;
    if (tid < n) sup = suppress(kbox[tid], cur);
    int any = __any(sup);
    if ((tid & 63) == 0) wflag[tid >> 6] = (u32)any;
    __syncthreads();
    u32 f = 0;
#pragma unroll
    for (int w = 0; w < 16; ++w) f |= wflag[w];
    if (!f) {
      if (tid == 0) { kbox[n] = cur; keptpos[n] = i; }
      ++n;
    }
    __syncthreads();
    if (n >= NPOST) break;
  }
  if (tid == 0) ctrl[C_KEPTCNT] = (u32)n;
}

// fallback output gather
__global__ void k_out(const u64* __restrict__ cand, const u32* __restrict__ keptpos,
                      const u32* __restrict__ ctrl, const float2* __restrict__ logits,
                      const float4* __restrict__ rois, float* __restrict__ out) {
  int r = blockIdx.x * blockDim.x + threadIdx.x;
  if (r >= NPOST) return;
  u32 kn = ctrl[C_KEPTCNT];
  float l0 = 0.f, l1 = 0.f, r0 = 0.f, r1 = 0.f, r2 = 0.f, r3 = 0.f;
  float lvf = -1.0f, vf = 0.0f;
  if (r < (int)kn) {
    u32 pos = keptpos[r];
    u64 a = cand[pos];
    u32 idx = (u32)(a & 0x3FFFFu);
    u32 lvl = (u32)((a >> 18) & 3u);
    float4 rb = rois[idx];
    float hs = __fsub_rn(rb.z, rb.x);
    float wsz = __fsub_rn(rb.w, rb.y);
    if (hs >= 1.0f && wsz >= 1.0f) {
      float2 lg = logits[idx];
      l0 = lg.x; l1 = lg.y;
      r0 = rb.x; r1 = rb.y; r2 = rb.z; r3 = rb.w;
      lvf = (float)lvl; vf = 1.0f;
    }
  }
  out[2 * r] = l0;
  out[2 * r + 1] = l1;
  out[2 * NPOST + 4 * r + 0] = r0;
  out[2 * NPOST + 4 * r + 1] = r1;
  out[2 * NPOST + 4 * r + 2] = r2;
  out[2 * NPOST + 4 * r + 3] = r3;
  out[6 * NPOST + r] = lvf;
  out[7 * NPOST + r] = vf;
}

extern "C" void kernel_launch(void* const* d_in, const int* in_sizes, int n_in,
                              void* d_out, int out_size, void* d_ws, size_t ws_size,
                              hipStream_t stream) {
  const float* logits = (const float*)d_in[0];
  const float* rois = (const float*)d_in[1];
  const int* levels = (const int*)d_in[2];
  int N = in_sizes[2];

  char* ws = (char*)d_ws;
  u32* sbits = (u32*)(ws + OFF_SBITS);
  u32* ctrl = (u32*)(ws + OFF_CTRL);
  u32* rankbuf = (u32*)(ws + OFF_RANK);
  u32* hist1 = (u32*)(ws + OFF_H1);
  u32* histm = (u32*)(ws + OFF_HM);
  u32* keptpos = (u32*)(ws + OFF_KEPT);
  u64* tie = (u64*)(ws + OFF_TIE);
  u64* cand = (u64*)(ws + OFF_CAND);
  float4* shifted = (float4*)(ws + OFF_SHIFT);
  u64* cand2 = (u64*)(ws + OFF_CAND2);
  u64* maskT2 = (u64*)(ws + OFF_MASK);

  // ctrl + rankbuf + hist1 + histm contiguous: one 44KB memset
  hipMemsetAsync(ctrl, 0, MEMSET_BYTES, stream);

  int nb2 = (N + 511) / 512;
  k_score_hist<<<nb2, 512, 0, stream>>>((const float2*)logits, levels, sbits, hist1, N);
  k_scan_e<<<NLVL, 64, 0, stream>>>(hist1, ctrl);
  k_hist_m<<<nb2, 512, 0, stream>>>(sbits, levels, ctrl, histm, N);
  k_scan_m<<<NLVL, 64, 0, stream>>>(histm, ctrl);
  k_compact<<<nb2, 512, 0, stream>>>(sbits, levels, ctrl, cand, tie, N);
  k_ties<<<NLVL, 256, 0, stream>>>(ctrl, cand, tie);
  {
    dim3 g(KPAD / 256, 8);
    k_rankp<<<g, 256, 0, stream>>>(cand, ctrl, (const float4*)rois, rankbuf, ctrl);
  }
  k_scatter<<<KPAD / 256, 256, 0, stream>>>(cand, rankbuf, ctrl, (const float4*)rois,
                                            cand2, shifted);
  if (ws_size >= WS_NEED) {
    dim3 g(KPAD / 64, KPAD / 64);
    k_build<<<g, 64, 0, stream>>>((const float4*)shifted, maskT2);
    k_scan<<<1, 64, 0, stream>>>(maskT2, cand2, ctrl,
                                 (const float2*)logits, (const float4*)rois, (float*)d_out);
  } else {
    k_nms<<<1, 1024, 0, stream>>>(shifted, ctrl, keptpos);
    k_out<<<(NPOST + 255) / 256, 256, 0, stream>>>(cand2, keptpos, ctrl, (const float2*)logits,
                                                   (const float4*)rois, (float*)d_out);
  }
}

// Round 11
// 125.757 us; speedup vs baseline: 5.7506x; 1.2110x over previous
//
#include <hip/hip_runtime.h>
#include <stdint.h>

typedef uint32_t u32;
typedef uint64_t u64;

#define NLVL 4
#define NPRE 2000
#define NPOST 1000
#define KPAD 8192
#define TIE_CAP 4096
#define NCHUNK 128          // chunk count (125 used, padded to 128)

// ws layout (bytes)
#define OFF_SBITS 0u                        // 1 MB  (250K u32)
#define OFF_CTRL  (2u<<20)                  // 4 KB  [memset]
#define OFF_RANK  ((2u<<20) + (4u<<10))     // 32 KB u32[8192] [memset, contiguous]
#define OFF_H1    ((2u<<20) + (36u<<10))    // 4 KB  u32[4][256] exponent hist [memset]
#define OFF_HM    ((2u<<20) + (40u<<10))    // 4 KB  u32[4][256] mantissa hist [memset]
#define OFF_KEPT  ((2u<<20) + (48u<<10))    // 4 KB  (fallback path only)
#define OFF_TIE   ((2u<<20) + (64u<<10))    // 128 KB u64[4][4096]
#define OFF_CAND  ((2u<<20) + (192u<<10))   // 64 KB u64[8192]  (unsorted)
#define OFF_SHIFT ((2u<<20) + (256u<<10))   // 128 KB float4[8192] (sorted order)
#define OFF_CAND2 ((2u<<20) + (384u<<10))   // 64 KB u64[8192]  (sorted)
#define OFF_MASK  (3u<<20)                  // 8 MB: maskT2[128 row-chunks][8192 cols] u64
#define WS_NEED   ((size_t)(3u<<20) + (size_t)NCHUNK * KPAD * 8u)
#define MEMSET_BYTES ((44u<<10))            // ctrl + rankbuf + h1 + hm (from OFF_CTRL)

// ctrl word indices -- each hot group on its OWN 64B cacheline
#define C_CANDCNT 0    // line 0: block-aggregated adds
#define C_KEPTCNT 1
#define C_SEPMAX  16   // line 1: wave-reduced atomicMax (k_rankp h==0 only)
#define C_P       32   // line 2: threshold (b>>15 value) + RANK (written by k_compact blk0)
#define C_RANK    36
#define C_TIECNT  48   // line 3: block-aggregated tie adds

// ---- monotone float<->u32 map for atomic max over floats ----
__device__ __forceinline__ u32 fmap(float f) {
  u32 u = __float_as_uint(f);
  return (u & 0x80000000u) ? ~u : (u | 0x80000000u);
}
__device__ __forceinline__ float funmap(u32 u) {
  u = (u & 0x80000000u) ? (u & 0x7FFFFFFFu) : ~u;
  return __uint_as_float(u);
}

// ---- replicate XLA-CPU GenerateVF32Exp (Cephes/Eigen-3.3 style) ----
__device__ __forceinline__ float xla_expf(float x) {
  const float kLog2e = 1.44269504088896341f;
  const float kC1 = 0.693359375f;
  const float kC2 = -2.12194440e-4f;
  const float kP0 = 1.9875691500e-4f;
  const float kP1 = 1.3981999507e-3f;
  const float kP2 = 8.3334519073e-3f;
  const float kP3 = 4.1665795894e-2f;
  const float kP4 = 1.6666665459e-1f;
  const float kP5 = 5.0000001201e-1f;
  float xc = fminf(fmaxf(x, -88.3762626647949f), 88.3762626647950f);
  float fx = floorf(fmaf(xc, kLog2e, 0.5f));
  float tmp = __fmul_rn(kC1, fx);
  float z = __fmul_rn(kC2, fx);
  float r = __fsub_rn(xc, tmp);
  r = __fsub_rn(r, z);
  float r2 = __fmul_rn(r, r);
  float y = fmaf(r, kP0, kP1);
  y = fmaf(y, r, kP2);
  y = fmaf(y, r, kP3);
  y = fmaf(y, r, kP4);
  y = fmaf(y, r, kP5);
  y = fmaf(y, r2, r);
  y = __fadd_rn(y, 1.0f);
  int n = (int)fx;
  float two_n = __int_as_float((n + 127) << 23);
  return fmaxf(__fmul_rn(y, two_n), x);
}

// ---- IoU(a,b) > 0.7f, reference's exact f32 op sequence; exactly symmetric ----
__device__ __forceinline__ bool suppress(float4 a, float4 b) {
  float aa = __fmul_rn(__fsub_rn(a.z, a.x), __fsub_rn(a.w, a.y));
  float ab = __fmul_rn(__fsub_rn(b.z, b.x), __fsub_rn(b.w, b.y));
  float lty = fmaxf(a.x, b.x);
  float ltx = fmaxf(a.y, b.y);
  float rby = fminf(a.z, b.z);
  float rbx = fminf(a.w, b.w);
  float why = fmaxf(__fsub_rn(rby, lty), 0.0f);
  float whx = fmaxf(__fsub_rn(rbx, ltx), 0.0f);
  float inter = __fmul_rn(why, whx);
  float uni = __fsub_rn(__fadd_rn(aa, ab), inter);
  float iou = inter / fmaxf(uni, 1e-9f);
  return iou > 0.7f;
}

__device__ __forceinline__ u64 makekey(u32 sbits, u32 lvl, u32 idx) {
  // ascending key == (score desc, level asc, index asc); total order (idx unique)
  return ((u64)(0x7FFFFFFFu - sbits) << 20) | ((u64)lvl << 18) | (u64)idx;
}

// ---- wave-parallel descending rank-scan over a 256-bin histogram ----
// Finds the bin containing rank `target` (counting from the top bin down) and
// the cumulative count strictly above that bin. bin=0xFFFFFFFF if total<target.
// Must be executed by all 64 lanes of one wave.
__device__ __forceinline__ void rank_scan256(const u32* __restrict__ h, u32 target,
                                             int lane, u32* bin_out, u32* before_out) {
  u32 b0 = h[255 - 4 * lane];
  u32 b1 = h[254 - 4 * lane];
  u32 b2 = h[253 - 4 * lane];
  u32 b3 = h[252 - 4 * lane];
  u32 s = b0 + b1 + b2 + b3;
  u32 inc = s;
  for (int o = 1; o < 64; o <<= 1) {
    u32 v = (u32)__shfl_up((int)inc, o);
    if (lane >= o) inc += v;
  }
  u32 excl = inc - s;
  u32 tot = (u32)__shfl((int)inc, 63);
  if (tot < target) { *bin_out = 0xFFFFFFFFu; *before_out = 0u; return; }
  bool hit = (excl < target) && (excl + s >= target);
  u32 E = 0, before = 0;
  if (hit) {
    u32 cum = excl;
    if (cum + b0 >= target) { E = 255 - 4 * (u32)lane; before = cum; }
    else { cum += b0;
      if (cum + b1 >= target) { E = 254 - 4 * (u32)lane; before = cum; }
      else { cum += b1;
        if (cum + b2 >= target) { E = 253 - 4 * (u32)lane; before = cum; }
        else { cum += b2; E = 252 - 4 * (u32)lane; before = cum; }
      }
    }
  }
  u64 hb = __ballot(hit);
  int src = __ffsll((unsigned long long)hb) - 1;
  *bin_out = (u32)__shfl((int)E, src);
  *before_out = (u32)__shfl((int)before, src);
}

// 1) softmax score + LDS-aggregated exponent histogram (4KB global footprint)
__global__ __launch_bounds__(512) void k_score_hist(const float2* __restrict__ logits,
                                                    const int* __restrict__ levels,
                                                    u32* __restrict__ sbits,
                                                    u32* __restrict__ hist1, int n) {
  __shared__ u32 lh[NLVL * 256];
  int tid = threadIdx.x;
  for (int p = tid; p < NLVL * 256; p += 512) lh[p] = 0;
  __syncthreads();
  int i = blockIdx.x * 512 + tid;
  if (i < n) {
    float2 lg = logits[i];
    float m = fmaxf(lg.x, lg.y);
    float e0 = xla_expf(__fsub_rn(lg.x, m));
    float e1 = xla_expf(__fsub_rn(lg.y, m));
    float s = e1 / __fadd_rn(e0, e1);   // IEEE div
    u32 b = __float_as_uint(s);
    sbits[i] = b;
    int lv = levels[i];
    atomicAdd(&lh[lv * 256 + (int)((b >> 23) & 0xFFu)], 1u);
  }
  __syncthreads();
  for (int p = tid; p < NLVL * 256; p += 512) {
    u32 v = lh[p];
    if (v) atomicAdd(&hist1[p], v);
  }
}

// 2) mantissa histogram (bits 22:15) restricted to exp==E; E computed IN-BLOCK
//    from the completed exponent hist (folds the old k_scan_e launch away).
__global__ __launch_bounds__(512) void k_hist_m(const u32* __restrict__ sbits,
                                                const int* __restrict__ levels,
                                                const u32* __restrict__ hist1,
                                                u32* __restrict__ histm, int n) {
  __shared__ u32 lh[NLVL * 256];
  __shared__ u32 sE[NLVL];
  int tid = threadIdx.x;
  int lane = tid & 63, w = tid >> 6;
  for (int p = tid; p < NLVL * 256; p += 512) lh[p] = 0;
  if (w < NLVL) {
    u32 E, bef;
    rank_scan256(hist1 + w * 256, NPRE, lane, &E, &bef);
    if (lane == 0) sE[w] = E;
  }
  __syncthreads();
  int i = blockIdx.x * 512 + tid;
  if (i < n) {
    u32 b = sbits[i];
    int lv = levels[i];
    if (((b >> 23) & 0xFFu) == sE[lv])
      atomicAdd(&lh[lv * 256 + (int)((b >> 15) & 0xFFu)], 1u);
  }
  __syncthreads();
  for (int p = tid; p < NLVL * 256; p += 512) {
    u32 v = lh[p];
    if (v) atomicAdd(&histm[p], v);
  }
}

// 3) compact with BLOCK-AGGREGATED atomics; threshold P=(E<<8)|M computed
//    IN-BLOCK from both hists (folds old k_scan_m away). Block 0 publishes
//    P/RANK to ctrl for k_ties.
__global__ __launch_bounds__(512) void k_compact(const u32* __restrict__ sbits,
                                                 const int* __restrict__ levels,
                                                 const u32* __restrict__ hist1,
                                                 const u32* __restrict__ histm,
                                                 u32* __restrict__ ctrl,
                                                 u64* __restrict__ cand,
                                                 u64* __restrict__ tie, int n) {
  __shared__ u32 wcnt[8], wtieS[8][4];
  __shared__ u32 wbase, tiebase[4];
  __shared__ u32 sP[NLVL], sRANK[NLVL];
  int tid = threadIdx.x;
  int wid = tid >> 6, lane = tid & 63;
  if (wid < NLVL) {
    u32 E, bef1;
    rank_scan256(hist1 + wid * 256, NPRE, lane, &E, &bef1);
    u32 P = 0xFFFFFFFFu, RK = 0;
    if (E != 0xFFFFFFFFu) {
      u32 R1 = NPRE - bef1;          // elements needed inside exponent bin E
      u32 M, bef2;
      rank_scan256(histm + wid * 256, R1, lane, &M, &bef2);
      P = (E << 8) | M;
      RK = R1 - bef2;                // elements needed inside threshold bin
    }
    if (lane == 0) {
      sP[wid] = P; sRANK[wid] = RK;
      if (blockIdx.x == 0) { ctrl[C_P + wid] = P; ctrl[C_RANK + wid] = RK; }
    }
  }
  __syncthreads();
  int i = blockIdx.x * 512 + tid;
  bool act = i < n;
  u32 b = 0; int lv = 0; u32 P = 0xFFFFFFFEu;
  if (act) {
    b = sbits[i];
    lv = levels[i];
    P = sP[lv];
  }
  u32 K = b >> 15;
  bool iscand = act && (P == 0xFFFFFFFFu || K > P);
  bool istie  = act && !iscand && (K == P);
  u64 cb = __ballot(iscand);
  u64 t0 = __ballot(istie && lv == 0);
  u64 t1 = __ballot(istie && lv == 1);
  u64 t2 = __ballot(istie && lv == 2);
  u64 t3 = __ballot(istie && lv == 3);
  if (lane == 0) {
    wcnt[wid] = (u32)__popcll(cb);
    wtieS[wid][0] = (u32)__popcll(t0);
    wtieS[wid][1] = (u32)__popcll(t1);
    wtieS[wid][2] = (u32)__popcll(t2);
    wtieS[wid][3] = (u32)__popcll(t3);
  }
  __syncthreads();
  if (tid == 0) {
    u32 tot = 0;
#pragma unroll
    for (int w = 0; w < 8; ++w) tot += wcnt[w];
    wbase = tot ? atomicAdd(&ctrl[C_CANDCNT], tot) : 0u;
  }
  if (tid < 4) {
    u32 tt = 0;
#pragma unroll
    for (int w = 0; w < 8; ++w) tt += wtieS[w][tid];
    tiebase[tid] = tt ? atomicAdd(&ctrl[C_TIECNT + tid], tt) : 0u;
  }
  __syncthreads();
  u64 lm = (1ull << lane) - 1ull;
  if (iscand) {
    u32 pre = 0;
    for (int w = 0; w < wid; ++w) pre += wcnt[w];
    u32 pos = wbase + pre + (u32)__popcll(cb & lm);
    if (pos < (u32)KPAD) cand[pos] = makekey(b, (u32)lv, (u32)i);
  }
  if (istie) {
    u64 tb = (lv == 0) ? t0 : (lv == 1) ? t1 : (lv == 2) ? t2 : t3;
    u32 pre = 0;
    for (int w = 0; w < wid; ++w) pre += wtieS[w][lv];
    u32 pos = tiebase[lv] + pre + (u32)__popcll(tb & lm);
    if (pos < (u32)TIE_CAP) tie[lv * TIE_CAP + pos] = makekey(b, (u32)lv, (u32)i);
  }
}

// 4) bin-P resolution: sort bin members by total-order key, take first RANK
__global__ void k_ties(u32* __restrict__ ctrl, u64* __restrict__ cand,
                       const u64* __restrict__ tie) {
  int lvl = blockIdx.x;
  int tid = threadIdx.x;
  if (ctrl[C_P + lvl] == 0xFFFFFFFFu) return;   // deficient (uniform per block)
  u32 need = ctrl[C_RANK + lvl];
  if (need == 0) return;
  u32 n = min(ctrl[C_TIECNT + lvl], (u32)TIE_CAP);
  u32 m = 2; while (m < n) m <<= 1;
  __shared__ u64 buf[TIE_CAP];
  for (u32 t = tid; t < m; t += 256)
    buf[t] = (t < n) ? tie[lvl * TIE_CAP + t] : ~0ull;
  __syncthreads();
  for (u32 k = 2; k <= m; k <<= 1) {
    for (u32 j = k >> 1; j > 0; j >>= 1) {
      for (u32 p = tid; p < m; p += 256) {
        u32 q = p ^ j;
        if (q > p) {
          u64 a = buf[p], b = buf[q];
          bool desc = (p & k) != 0;
          if (desc ? (a < b) : (a > b)) { buf[p] = b; buf[q] = a; }
        }
      }
      __syncthreads();
    }
  }
  u32 cnt = min(need, n);
  __shared__ u32 basep;
  if (tid == 0) basep = atomicAdd(&ctrl[C_CANDCNT], cnt);
  __syncthreads();
  for (u32 t = tid; t < cnt; t += 256) {
    if (basep + t < (u32)KPAD) cand[basep + t] = buf[t];
  }
}

// 5a) partial enumeration rank (grid 32x8 = all CUs busy) + sepmax fold-in
__global__ __launch_bounds__(256) void k_rankp(const u64* __restrict__ cand,
                                               const u32* __restrict__ ctrl,
                                               const float4* __restrict__ rois,
                                               u32* __restrict__ rankbuf,
                                               u32* __restrict__ ctrlw) {
  __shared__ u64 tilek[256];
  int tid = threadIdx.x;
  u32 g = blockIdx.x, h = blockIdx.y;
  u32 total = min(ctrl[C_CANDCNT], (u32)KPAD);
  u32 gid = g * 256 + (u32)tid;
  u64 mykey = (gid < total) ? cand[gid] : ~0ull;
  if (h == 0) {   // sepmax over selected candidates (exact set)
    u32 mx = 0;
    if (gid < total) {
      u32 idx = (u32)(mykey & 0x3FFFFu);
      float4 r = rois[idx];
      mx = max(max(fmap(r.x), fmap(r.y)), max(fmap(r.z), fmap(r.w)));
    }
    for (int o = 32; o; o >>= 1) {
      u32 v = (u32)__shfl_xor((int)mx, o);
      mx = max(mx, v);
    }
    if ((tid & 63) == 0 && mx) atomicMax(&ctrlw[C_SEPMAX], mx);
  }
  u32 jbeg = h * 1024;
  if (jbeg >= total) return;                 // uniform per block
  u32 jend = min(jbeg + 1024, total);
  u32 cnt = 0;
  for (u32 base = jbeg; base < jend; base += 256) {
    u32 n = min(256u, jend - base);
    __syncthreads();
    if ((u32)tid < n) tilek[tid] = cand[base + (u32)tid];
    __syncthreads();
    if (n == 256u) {
#pragma unroll 8
      for (u32 j = 0; j < 256u; ++j) cnt += (tilek[j] < mykey) ? 1u : 0u;
    } else {
      for (u32 j = 0; j < n; ++j) cnt += (tilek[j] < mykey) ? 1u : 0u;
    }
  }
  if (gid < total && cnt) atomicAdd(&rankbuf[gid], cnt);
}

// 5b) scatter by rank (unique keys -> exact permutation); fused shift-write
__global__ __launch_bounds__(256) void k_scatter(const u64* __restrict__ cand,
                                                 const u32* __restrict__ rankbuf,
                                                 const u32* __restrict__ ctrl,
                                                 const float4* __restrict__ rois,
                                                 u64* __restrict__ cand2,
                                                 float4* __restrict__ shifted) {
  u32 gid = blockIdx.x * 256 + threadIdx.x;
  u32 total = min(ctrl[C_CANDCNT], (u32)KPAD);
  if (gid >= total) return;
  u64 mykey = cand[gid];
  u32 rank = rankbuf[gid];
  cand2[rank] = mykey;
  float sep = __fadd_rn(funmap(ctrl[C_SEPMAX]), 1.0f);
  u32 idx = (u32)(mykey & 0x3FFFFu);
  u32 lvl = (u32)((mykey >> 18) & 3u);
  float4 r = rois[idx];
  float sh = __fmul_rn((float)lvl, sep);
  float4 o;
  o.x = __fadd_rn(r.x, sh);
  o.y = __fadd_rn(r.y, sh);
  o.z = __fadd_rn(r.z, sh);
  o.w = __fadd_rn(r.w, sh);
  shifted[rank] = o;
}

// 6) build column-major suppression mask (fat blocks: 4 col-chunks per block):
//    maskT2[rb*KPAD + j] bit s = suppress(box[rb*64+s], box[j]) && (rb*64+s < j)
__global__ __launch_bounds__(256) void k_build(const float4* __restrict__ shifted,
                                               u64* __restrict__ maskT2) {
  u32 rb = blockIdx.y;
  u32 cb = blockIdx.x * 4 + (threadIdx.x >> 6);
  if (blockIdx.x * 4 + 3 < rb) return;       // whole block below diagonal
  int lane = threadIdx.x & 63;
  __shared__ float4 rbox[64];
  if (threadIdx.x < 64) rbox[threadIdx.x] = shifted[rb * 64 + threadIdx.x];
  __syncthreads();
  if (cb < rb) return;                       // partial skip (after the barrier)
  u32 jg = cb * 64 + (u32)lane;
  float4 myc = shifted[jg];
  u64 bits = 0;
  for (int s = 0; s < 64; ++s) {
    if ((rb * 64 + (u32)s) < jg && suppress(rbox[s], myc)) bits |= (1ull << s);
  }
  maskT2[(u64)rb * KPAD + jg] = bits;
}

// 7) pipelined 8-wave greedy scan. Wave 0 resolves chunk c (ballot-fixpoint on
//    the s<t DAG) while waves 1-7 compute chunk c+1's cross-chunk reduction
//    over ci<=c-1 (double-buffered partial ballots). The missing ci=c term is
//    patched by wave 0 from a prefetched word. One barrier per chunk.
__global__ __launch_bounds__(512) void k_scan(const u64* __restrict__ maskT2,
                                              const u64* __restrict__ cand2,
                                              u32* __restrict__ ctrl,
                                              const float2* __restrict__ logits,
                                              const float4* __restrict__ rois,
                                              float* __restrict__ out) {
  __shared__ u64 keptm[NCHUNK];
  __shared__ u64 pre[2][8];
  __shared__ u32 lkept[NPOST];
  __shared__ u32 keptS;
  int tid = threadIdx.x;
  int lane = tid & 63, w = tid >> 6;
  u32 total = min(ctrl[C_CANDCNT], (u32)KPAD);
  u32 chunks = (total + 63) >> 6;
  for (int p = tid; p < NCHUNK; p += 512) keptm[p] = 0;
  if (tid < 8)  pre[0][tid] = 0;
  if (tid >= 8 && tid < 16) pre[1][tid - 8] = 0;
  if (tid == 0) keptS = 0;
  __syncthreads();
  u32 kept = 0;
  u64 keepPrev = 0, lastWord = 0, diagCur = 0;
  if (w == 0 && chunks > 0) diagCur = maskT2[(u64)lane];   // diag word chunk 0
  for (u32 c = 0; c < chunks; ++c) {
    if (w == 0) {
      // prefetch next chunk's diag + last-term words (addresses static)
      u64 nDiag = 0, nLast = 0;
      if (c + 1 < chunks) {
        nDiag = maskT2[(u64)(c + 1) * KPAD + (u64)(c + 1) * 64 + (u64)lane];
        nLast = maskT2[(u64)c * KPAD + (u64)(c + 1) * 64 + (u64)lane];
      }
      u64 remc = pre[c & 1][1] | pre[c & 1][2] | pre[c & 1][3] | pre[c & 1][4] |
                 pre[c & 1][5] | pre[c & 1][6] | pre[c & 1][7];
      remc |= __ballot((lastWord & keepPrev) != 0ull);   // ci = c-1 patch
      u64 wv = ~remc;
      u32 rem2 = total - c * 64;
      if (rem2 < 64) wv &= ((1ull << rem2) - 1ull);
      u64 keep = wv;
      for (int it = 0; it < 64; ++it) {
        bool sup = (diagCur & keep) != 0ull;
        u64 nk = wv & ~__ballot(sup);
        if (nk == keep) break;     // uniform within wave
        keep = nk;
      }
      u32 pos = kept + (u32)__popcll(keep & ((1ull << lane) - 1ull));
      if (((keep >> lane) & 1ull) && pos < NPOST) lkept[pos] = c * 64 + (u32)lane;
      if (lane == 0) { keptm[c] = keep; keptS = kept + (u32)__popcll(keep); }
      keepPrev = keep;
      lastWord = nLast;
      diagCur = nDiag;
    } else {
      // waves 1..7: reduction for chunk c+1 over ci in {w-1, w-1+7, ...} <= c-1
      u64 a0 = 0, a1 = 0;
      if (c + 1 < chunks) {
        const u64* colbase = maskT2 + (u64)(c + 1) * 64 + (u64)lane;
        u32 ci = (u32)(w - 1);
        for (; ci + 7 < c; ci += 14) {
          u64 x0 = colbase[(u64)ci * KPAD] & keptm[ci];
          u64 x1 = colbase[(u64)(ci + 7) * KPAD] & keptm[ci + 7];
          a0 |= x0; a1 |= x1;
        }
        for (; ci < c; ci += 7) a0 |= colbase[(u64)ci * KPAD] & keptm[ci];
      }
      u64 bal = __ballot((a0 | a1) != 0ull);
      if (lane == 0) pre[(c + 1) & 1][w] = bal;
    }
    __syncthreads();
    kept = keptS;
    if (kept >= NPOST) break;
  }
  if (tid == 0) ctrl[C_KEPTCNT] = min(kept, (u32)NPOST);
  __syncthreads();
  u32 kn = min(kept, (u32)NPOST);
  // ---- fused output gather (small-box filter + padding) ----
  for (u32 r = (u32)tid; r < NPOST; r += 512) {
    float l0 = 0.f, l1 = 0.f, b0 = 0.f, b1 = 0.f, b2 = 0.f, b3 = 0.f;
    float lvf = -1.0f, vf = 0.0f;
    if (r < kn) {
      u32 pos = lkept[r];
      u64 a = cand2[pos];
      u32 idx = (u32)(a & 0x3FFFFu);
      u32 lvl = (u32)((a >> 18) & 3u);
      float4 rb = rois[idx];
      float hs = __fsub_rn(rb.z, rb.x);
      float wsz = __fsub_rn(rb.w, rb.y);
      if (hs >= 1.0f && wsz >= 1.0f) {
        float2 lg = logits[idx];
        l0 = lg.x; l1 = lg.y;
        b0 = rb.x; b1 = rb.y; b2 = rb.z; b3 = rb.w;
        lvf = (float)lvl; vf = 1.0f;
      }
    }
    out[2 * r] = l0;
    out[2 * r + 1] = l1;
    out[2 * NPOST + 4 * r + 0] = b0;
    out[2 * NPOST + 4 * r + 1] = b1;
    out[2 * NPOST + 4 * r + 2] = b2;
    out[2 * NPOST + 4 * r + 3] = b3;
    out[6 * NPOST + r] = lvf;
    out[7 * NPOST + r] = vf;
  }
}

// fallback) sequential greedy NMS (only if ws too small for the mask)
__global__ __launch_bounds__(1024) void k_nms(const float4* __restrict__ shifted,
                                              u32* __restrict__ ctrl, u32* __restrict__ keptpos) {
  __shared__ float4 kbox[NPOST];
  __shared__ u32 wflag[16];
  int tid = threadIdx.x;
  u32 total = min(ctrl[C_CANDCNT], (u32)KPAD);
  int n = 0;
  for (u32 i = 0; i < total; ++i) {
    float4 cur = shifted[i];
    bool sup = false;
    if (tid < n) sup = suppress(kbox[tid], cur);
    int any = __any(sup);
    if ((tid & 63) == 0) wflag[tid >> 6] = (u32)any;
    __syncthreads();
    u32 f = 0;
#pragma unroll
    for (int w = 0; w < 16; ++w) f |= wflag[w];
    if (!f) {
      if (tid == 0) { kbox[n] = cur; keptpos[n] = i; }
      ++n;
    }
    __syncthreads();
    if (n >= NPOST) break;
  }
  if (tid == 0) ctrl[C_KEPTCNT] = (u32)n;
}

// fallback output gather
__global__ void k_out(const u64* __restrict__ cand, const u32* __restrict__ keptpos,
                      const u32* __restrict__ ctrl, const float2* __restrict__ logits,
                      const float4* __restrict__ rois, float* __restrict__ out) {
  int r = blockIdx.x * blockDim.x + threadIdx.x;
  if (r >= NPOST) return;
  u32 kn = ctrl[C_KEPTCNT];
  float l0 = 0.f, l1 = 0.f, r0 = 0.f, r1 = 0.f, r2 = 0.f, r3 = 0.f;
  float lvf = -1.0f, vf = 0.0f;
  if (r < (int)kn) {
    u32 pos = keptpos[r];
    u64 a = cand[pos];
    u32 idx = (u32)(a & 0x3FFFFu);
    u32 lvl = (u32)((a >> 18) & 3u);
    float4 rb = rois[idx];
    float hs = __fsub_rn(rb.z, rb.x);
    float wsz = __fsub_rn(rb.w, rb.y);
    if (hs >= 1.0f && wsz >= 1.0f) {
      float2 lg = logits[idx];
      l0 = lg.x; l1 = lg.y;
      r0 = rb.x; r1 = rb.y; r2 = rb.z; r3 = rb.w;
      lvf = (float)lvl; vf = 1.0f;
    }
  }
  out[2 * r] = l0;
  out[2 * r + 1] = l1;
  out[2 * NPOST + 4 * r + 0] = r0;
  out[2 * NPOST + 4 * r + 1] = r1;
  out[2 * NPOST + 4 * r + 2] = r2;
  out[2 * NPOST + 4 * r + 3] = r3;
  out[6 * NPOST + r] = lvf;
  out[7 * NPOST + r] = vf;
}

extern "C" void kernel_launch(void* const* d_in, const int* in_sizes, int n_in,
                              void* d_out, int out_size, void* d_ws, size_t ws_size,
                              hipStream_t stream) {
  const float* logits = (const float*)d_in[0];
  const float* rois = (const float*)d_in[1];
  const int* levels = (const int*)d_in[2];
  int N = in_sizes[2];

  char* ws = (char*)d_ws;
  u32* sbits = (u32*)(ws + OFF_SBITS);
  u32* ctrl = (u32*)(ws + OFF_CTRL);
  u32* rankbuf = (u32*)(ws + OFF_RANK);
  u32* hist1 = (u32*)(ws + OFF_H1);
  u32* histm = (u32*)(ws + OFF_HM);
  u32* keptpos = (u32*)(ws + OFF_KEPT);
  u64* tie = (u64*)(ws + OFF_TIE);
  u64* cand = (u64*)(ws + OFF_CAND);
  float4* shifted = (float4*)(ws + OFF_SHIFT);
  u64* cand2 = (u64*)(ws + OFF_CAND2);
  u64* maskT2 = (u64*)(ws + OFF_MASK);

  // ctrl + rankbuf + hist1 + histm contiguous: one 44KB memset
  hipMemsetAsync(ctrl, 0, MEMSET_BYTES, stream);

  int nb2 = (N + 511) / 512;
  k_score_hist<<<nb2, 512, 0, stream>>>((const float2*)logits, levels, sbits, hist1, N);
  k_hist_m<<<nb2, 512, 0, stream>>>(sbits, levels, hist1, histm, N);
  k_compact<<<nb2, 512, 0, stream>>>(sbits, levels, hist1, histm, ctrl, cand, tie, N);
  k_ties<<<NLVL, 256, 0, stream>>>(ctrl, cand, tie);
  {
    dim3 g(KPAD / 256, 8);
    k_rankp<<<g, 256, 0, stream>>>(cand, ctrl, (const float4*)rois, rankbuf, ctrl);
  }
  k_scatter<<<KPAD / 256, 256, 0, stream>>>(cand, rankbuf, ctrl, (const float4*)rois,
                                            cand2, shifted);
  if (ws_size >= WS_NEED) {
    dim3 g(KPAD / 256, KPAD / 64);
    k_build<<<g, 256, 0, stream>>>((const float4*)shifted, maskT2);
    k_scan<<<1, 512, 0, stream>>>(maskT2, cand2, ctrl,
                                  (const float2*)logits, (const float4*)rois, (float*)d_out);
  } else {
    k_nms<<<1, 1024, 0, stream>>>(shifted, ctrl, keptpos);
    k_out<<<(NPOST + 255) / 256, 256, 0, stream>>>(cand2, keptpos, ctrl, (const float2*)logits,
                                                   (const float4*)rois, (float*)d_out);
  }
}

// Round 12
// 110.900 us; speedup vs baseline: 6.5209x; 1.1340x over previous
//
#include <hip/hip_runtime.h>
#include <stdint.h>

typedef uint32_t u32;
typedef uint64_t u64;

#define NLVL 4
#define NPRE 2000
#define NPOST 1000
#define KPAD 8192
#define TIE_CAP 4096
#define NCHUNK 128          // chunk count (125 used, padded to 128)

// ws layout (bytes)
#define OFF_SBITS 0u                        // 1 MB  (250K u32)
#define OFF_CTRL  (2u<<20)                  // 4 KB  [memset]
#define OFF_RANK  ((2u<<20) + (4u<<10))     // 32 KB u32[8192] [memset, contiguous]
#define OFF_H1    ((2u<<20) + (36u<<10))    // 4 KB  u32[4][256] exponent hist [memset]
#define OFF_HM    ((2u<<20) + (40u<<10))    // 4 KB  u32[4][256] mantissa hist [memset]
#define OFF_KEPT  ((2u<<20) + (48u<<10))    // 4 KB  (fallback path only)
#define OFF_TIE   ((2u<<20) + (64u<<10))    // 128 KB u64[4][4096]
#define OFF_CAND  ((2u<<20) + (192u<<10))   // 64 KB u64[8192]  (unsorted)
#define OFF_SHIFT ((2u<<20) + (256u<<10))   // 128 KB float4[8192] (sorted order)
#define OFF_CAND2 ((2u<<20) + (384u<<10))   // 64 KB u64[8192]  (sorted)
#define OFF_MASK  (3u<<20)                  // 8 MB: maskT2[128 row-chunks][8192 cols] u64
#define WS_NEED   ((size_t)(3u<<20) + (size_t)NCHUNK * KPAD * 8u)
#define MEMSET_BYTES ((44u<<10))            // ctrl + rankbuf + h1 + hm (from OFF_CTRL)

// ctrl word indices -- each hot group on its OWN 64B cacheline
#define C_CANDCNT 0    // line 0: block-aggregated adds
#define C_KEPTCNT 1
#define C_SEPMAX  16   // line 1: wave-reduced atomicMax (k_rankp h==0 only)
#define C_P       32   // line 2: threshold (b>>15 value) + RANK (written by k_compact blk0)
#define C_RANK    36
#define C_TIECNT  48   // line 3: block-aggregated tie adds

// exact midpoint between 0.7f (0x3F333333) and nextafterf(0.7f) (0x3F333334):
// RN32(inter/den) > 0.7f  <=>  inter/den >= MID (ties round to even = 0x3F333334 > 0.7f).
// (double)inter and (double)den are exact; MID*(double)den needs <=49 bits -> exact.
#define MID 0x1.666667p-1

// ---- monotone float<->u32 map for atomic max over floats ----
__device__ __forceinline__ u32 fmap(float f) {
  u32 u = __float_as_uint(f);
  return (u & 0x80000000u) ? ~u : (u | 0x80000000u);
}
__device__ __forceinline__ float funmap(u32 u) {
  u = (u & 0x80000000u) ? (u & 0x7FFFFFFFu) : ~u;
  return __uint_as_float(u);
}

// ---- replicate XLA-CPU GenerateVF32Exp (Cephes/Eigen-3.3 style) ----
__device__ __forceinline__ float xla_expf(float x) {
  const float kLog2e = 1.44269504088896341f;
  const float kC1 = 0.693359375f;
  const float kC2 = -2.12194440e-4f;
  const float kP0 = 1.9875691500e-4f;
  const float kP1 = 1.3981999507e-3f;
  const float kP2 = 8.3334519073e-3f;
  const float kP3 = 4.1665795894e-2f;
  const float kP4 = 1.6666665459e-1f;
  const float kP5 = 5.0000001201e-1f;
  float xc = fminf(fmaxf(x, -88.3762626647949f), 88.3762626647950f);
  float fx = floorf(fmaf(xc, kLog2e, 0.5f));
  float tmp = __fmul_rn(kC1, fx);
  float z = __fmul_rn(kC2, fx);
  float r = __fsub_rn(xc, tmp);
  r = __fsub_rn(r, z);
  float r2 = __fmul_rn(r, r);
  float y = fmaf(r, kP0, kP1);
  y = fmaf(y, r, kP2);
  y = fmaf(y, r, kP3);
  y = fmaf(y, r, kP4);
  y = fmaf(y, r, kP5);
  y = fmaf(y, r2, r);
  y = __fadd_rn(y, 1.0f);
  int n = (int)fx;
  float two_n = __int_as_float((n + 127) << 23);
  return fmaxf(__fmul_rn(y, two_n), x);
}

// ---- IoU(a,b) > 0.7f, reference's exact f32 op sequence (fallback path) ----
__device__ __forceinline__ bool suppress(float4 a, float4 b) {
  float aa = __fmul_rn(__fsub_rn(a.z, a.x), __fsub_rn(a.w, a.y));
  float ab = __fmul_rn(__fsub_rn(b.z, b.x), __fsub_rn(b.w, b.y));
  float lty = fmaxf(a.x, b.x);
  float ltx = fmaxf(a.y, b.y);
  float rby = fminf(a.z, b.z);
  float rbx = fminf(a.w, b.w);
  float why = fmaxf(__fsub_rn(rby, lty), 0.0f);
  float whx = fmaxf(__fsub_rn(rbx, ltx), 0.0f);
  float inter = __fmul_rn(why, whx);
  float uni = __fsub_rn(__fadd_rn(aa, ab), inter);
  float iou = inter / fmaxf(uni, 1e-9f);
  return iou > 0.7f;
}

// ---- div-free IoU decision: provably identical to suppress() (see MID note) ----
__device__ __forceinline__ bool sup_fast(float ra, float4 r, float ca, float4 c) {
  float lty = fmaxf(r.x, c.x);
  float ltx = fmaxf(r.y, c.y);
  float rby = fminf(r.z, c.z);
  float rbx = fminf(r.w, c.w);
  float why = fmaxf(__fsub_rn(rby, lty), 0.0f);
  float whx = fmaxf(__fsub_rn(rbx, ltx), 0.0f);
  float inter = __fmul_rn(why, whx);
  float uni = __fsub_rn(__fadd_rn(ra, ca), inter);
  float den = fmaxf(uni, 1e-9f);
  return (double)inter >= MID * (double)den;
}

__device__ __forceinline__ u64 makekey(u32 sbits, u32 lvl, u32 idx) {
  // ascending key == (score desc, level asc, index asc); total order (idx unique)
  return ((u64)(0x7FFFFFFFu - sbits) << 20) | ((u64)lvl << 18) | (u64)idx;
}

// ---- wave-parallel descending rank-scan over a 256-bin histogram ----
__device__ __forceinline__ void rank_scan256(const u32* __restrict__ h, u32 target,
                                             int lane, u32* bin_out, u32* before_out) {
  u32 b0 = h[255 - 4 * lane];
  u32 b1 = h[254 - 4 * lane];
  u32 b2 = h[253 - 4 * lane];
  u32 b3 = h[252 - 4 * lane];
  u32 s = b0 + b1 + b2 + b3;
  u32 inc = s;
  for (int o = 1; o < 64; o <<= 1) {
    u32 v = (u32)__shfl_up((int)inc, o);
    if (lane >= o) inc += v;
  }
  u32 excl = inc - s;
  u32 tot = (u32)__shfl((int)inc, 63);
  if (tot < target) { *bin_out = 0xFFFFFFFFu; *before_out = 0u; return; }
  bool hit = (excl < target) && (excl + s >= target);
  u32 E = 0, before = 0;
  if (hit) {
    u32 cum = excl;
    if (cum + b0 >= target) { E = 255 - 4 * (u32)lane; before = cum; }
    else { cum += b0;
      if (cum + b1 >= target) { E = 254 - 4 * (u32)lane; before = cum; }
      else { cum += b1;
        if (cum + b2 >= target) { E = 253 - 4 * (u32)lane; before = cum; }
        else { cum += b2; E = 252 - 4 * (u32)lane; before = cum; }
      }
    }
  }
  u64 hb = __ballot(hit);
  int src = __ffsll((unsigned long long)hb) - 1;
  *bin_out = (u32)__shfl((int)E, src);
  *before_out = (u32)__shfl((int)before, src);
}

// 1) softmax score + LDS-aggregated exponent histogram (4KB global footprint)
__global__ __launch_bounds__(512) void k_score_hist(const float2* __restrict__ logits,
                                                    const int* __restrict__ levels,
                                                    u32* __restrict__ sbits,
                                                    u32* __restrict__ hist1, int n) {
  __shared__ u32 lh[NLVL * 256];
  int tid = threadIdx.x;
  for (int p = tid; p < NLVL * 256; p += 512) lh[p] = 0;
  __syncthreads();
  int i = blockIdx.x * 512 + tid;
  if (i < n) {
    float2 lg = logits[i];
    float m = fmaxf(lg.x, lg.y);
    float e0 = xla_expf(__fsub_rn(lg.x, m));
    float e1 = xla_expf(__fsub_rn(lg.y, m));
    float s = e1 / __fadd_rn(e0, e1);   // IEEE div
    u32 b = __float_as_uint(s);
    sbits[i] = b;
    int lv = levels[i];
    atomicAdd(&lh[lv * 256 + (int)((b >> 23) & 0xFFu)], 1u);
  }
  __syncthreads();
  for (int p = tid; p < NLVL * 256; p += 512) {
    u32 v = lh[p];
    if (v) atomicAdd(&hist1[p], v);
  }
}

// 2) mantissa histogram (bits 22:15) restricted to exp==E; E computed IN-BLOCK
__global__ __launch_bounds__(512) void k_hist_m(const u32* __restrict__ sbits,
                                                const int* __restrict__ levels,
                                                const u32* __restrict__ hist1,
                                                u32* __restrict__ histm, int n) {
  __shared__ u32 lh[NLVL * 256];
  __shared__ u32 sE[NLVL];
  int tid = threadIdx.x;
  int lane = tid & 63, w = tid >> 6;
  for (int p = tid; p < NLVL * 256; p += 512) lh[p] = 0;
  if (w < NLVL) {
    u32 E, bef;
    rank_scan256(hist1 + w * 256, NPRE, lane, &E, &bef);
    if (lane == 0) sE[w] = E;
  }
  __syncthreads();
  int i = blockIdx.x * 512 + tid;
  if (i < n) {
    u32 b = sbits[i];
    int lv = levels[i];
    if (((b >> 23) & 0xFFu) == sE[lv])
      atomicAdd(&lh[lv * 256 + (int)((b >> 15) & 0xFFu)], 1u);
  }
  __syncthreads();
  for (int p = tid; p < NLVL * 256; p += 512) {
    u32 v = lh[p];
    if (v) atomicAdd(&histm[p], v);
  }
}

// 3) compact with BLOCK-AGGREGATED atomics; threshold computed IN-BLOCK.
__global__ __launch_bounds__(512) void k_compact(const u32* __restrict__ sbits,
                                                 const int* __restrict__ levels,
                                                 const u32* __restrict__ hist1,
                                                 const u32* __restrict__ histm,
                                                 u32* __restrict__ ctrl,
                                                 u64* __restrict__ cand,
                                                 u64* __restrict__ tie, int n) {
  __shared__ u32 wcnt[8], wtieS[8][4];
  __shared__ u32 wbase, tiebase[4];
  __shared__ u32 sP[NLVL], sRANK[NLVL];
  int tid = threadIdx.x;
  int wid = tid >> 6, lane = tid & 63;
  if (wid < NLVL) {
    u32 E, bef1;
    rank_scan256(hist1 + wid * 256, NPRE, lane, &E, &bef1);
    u32 P = 0xFFFFFFFFu, RK = 0;
    if (E != 0xFFFFFFFFu) {
      u32 R1 = NPRE - bef1;          // elements needed inside exponent bin E
      u32 M, bef2;
      rank_scan256(histm + wid * 256, R1, lane, &M, &bef2);
      P = (E << 8) | M;
      RK = R1 - bef2;                // elements needed inside threshold bin
    }
    if (lane == 0) {
      sP[wid] = P; sRANK[wid] = RK;
      if (blockIdx.x == 0) { ctrl[C_P + wid] = P; ctrl[C_RANK + wid] = RK; }
    }
  }
  __syncthreads();
  int i = blockIdx.x * 512 + tid;
  bool act = i < n;
  u32 b = 0; int lv = 0; u32 P = 0xFFFFFFFEu;
  if (act) {
    b = sbits[i];
    lv = levels[i];
    P = sP[lv];
  }
  u32 K = b >> 15;
  bool iscand = act && (P == 0xFFFFFFFFu || K > P);
  bool istie  = act && !iscand && (K == P);
  u64 cb = __ballot(iscand);
  u64 t0 = __ballot(istie && lv == 0);
  u64 t1 = __ballot(istie && lv == 1);
  u64 t2 = __ballot(istie && lv == 2);
  u64 t3 = __ballot(istie && lv == 3);
  if (lane == 0) {
    wcnt[wid] = (u32)__popcll(cb);
    wtieS[wid][0] = (u32)__popcll(t0);
    wtieS[wid][1] = (u32)__popcll(t1);
    wtieS[wid][2] = (u32)__popcll(t2);
    wtieS[wid][3] = (u32)__popcll(t3);
  }
  __syncthreads();
  if (tid == 0) {
    u32 tot = 0;
#pragma unroll
    for (int w = 0; w < 8; ++w) tot += wcnt[w];
    wbase = tot ? atomicAdd(&ctrl[C_CANDCNT], tot) : 0u;
  }
  if (tid < 4) {
    u32 tt = 0;
#pragma unroll
    for (int w = 0; w < 8; ++w) tt += wtieS[w][tid];
    tiebase[tid] = tt ? atomicAdd(&ctrl[C_TIECNT + tid], tt) : 0u;
  }
  __syncthreads();
  u64 lm = (1ull << lane) - 1ull;
  if (iscand) {
    u32 pre = 0;
    for (int w = 0; w < wid; ++w) pre += wcnt[w];
    u32 pos = wbase + pre + (u32)__popcll(cb & lm);
    if (pos < (u32)KPAD) cand[pos] = makekey(b, (u32)lv, (u32)i);
  }
  if (istie) {
    u64 tb = (lv == 0) ? t0 : (lv == 1) ? t1 : (lv == 2) ? t2 : t3;
    u32 pre = 0;
    for (int w = 0; w < wid; ++w) pre += wtieS[w][lv];
    u32 pos = tiebase[lv] + pre + (u32)__popcll(tb & lm);
    if (pos < (u32)TIE_CAP) tie[lv * TIE_CAP + pos] = makekey(b, (u32)lv, (u32)i);
  }
}

// 4) bin-P resolution: sort bin members by total-order key, take first RANK
__global__ void k_ties(u32* __restrict__ ctrl, u64* __restrict__ cand,
                       const u64* __restrict__ tie) {
  int lvl = blockIdx.x;
  int tid = threadIdx.x;
  if (ctrl[C_P + lvl] == 0xFFFFFFFFu) return;   // deficient (uniform per block)
  u32 need = ctrl[C_RANK + lvl];
  if (need == 0) return;
  u32 n = min(ctrl[C_TIECNT + lvl], (u32)TIE_CAP);
  u32 m = 2; while (m < n) m <<= 1;
  __shared__ u64 buf[TIE_CAP];
  for (u32 t = tid; t < m; t += 256)
    buf[t] = (t < n) ? tie[lvl * TIE_CAP + t] : ~0ull;
  __syncthreads();
  for (u32 k = 2; k <= m; k <<= 1) {
    for (u32 j = k >> 1; j > 0; j >>= 1) {
      for (u32 p = tid; p < m; p += 256) {
        u32 q = p ^ j;
        if (q > p) {
          u64 a = buf[p], b = buf[q];
          bool desc = (p & k) != 0;
          if (desc ? (a < b) : (a > b)) { buf[p] = b; buf[q] = a; }
        }
      }
      __syncthreads();
    }
  }
  u32 cnt = min(need, n);
  __shared__ u32 basep;
  if (tid == 0) basep = atomicAdd(&ctrl[C_CANDCNT], cnt);
  __syncthreads();
  for (u32 t = tid; t < cnt; t += 256) {
    if (basep + t < (u32)KPAD) cand[basep + t] = buf[t];
  }
}

// 5a) partial enumeration rank (grid 32x8 = all CUs busy) + sepmax fold-in
__global__ __launch_bounds__(256) void k_rankp(const u64* __restrict__ cand,
                                               const u32* __restrict__ ctrl,
                                               const float4* __restrict__ rois,
                                               u32* __restrict__ rankbuf,
                                               u32* __restrict__ ctrlw) {
  __shared__ u64 tilek[256];
  int tid = threadIdx.x;
  u32 g = blockIdx.x, h = blockIdx.y;
  u32 total = min(ctrl[C_CANDCNT], (u32)KPAD);
  u32 gid = g * 256 + (u32)tid;
  u64 mykey = (gid < total) ? cand[gid] : ~0ull;
  if (h == 0) {   // sepmax over selected candidates (exact set)
    u32 mx = 0;
    if (gid < total) {
      u32 idx = (u32)(mykey & 0x3FFFFu);
      float4 r = rois[idx];
      mx = max(max(fmap(r.x), fmap(r.y)), max(fmap(r.z), fmap(r.w)));
    }
    for (int o = 32; o; o >>= 1) {
      u32 v = (u32)__shfl_xor((int)mx, o);
      mx = max(mx, v);
    }
    if ((tid & 63) == 0 && mx) atomicMax(&ctrlw[C_SEPMAX], mx);
  }
  u32 jbeg = h * 1024;
  if (jbeg >= total) return;                 // uniform per block
  u32 jend = min(jbeg + 1024, total);
  u32 cnt = 0;
  for (u32 base = jbeg; base < jend; base += 256) {
    u32 n = min(256u, jend - base);
    __syncthreads();
    if ((u32)tid < n) tilek[tid] = cand[base + (u32)tid];
    __syncthreads();
    if (n == 256u) {
#pragma unroll 8
      for (u32 j = 0; j < 256u; ++j) cnt += (tilek[j] < mykey) ? 1u : 0u;
    } else {
      for (u32 j = 0; j < n; ++j) cnt += (tilek[j] < mykey) ? 1u : 0u;
    }
  }
  if (gid < total && cnt) atomicAdd(&rankbuf[gid], cnt);
}

// 5b) scatter by rank (unique keys -> exact permutation); fused shift-write
__global__ __launch_bounds__(256) void k_scatter(const u64* __restrict__ cand,
                                                 const u32* __restrict__ rankbuf,
                                                 const u32* __restrict__ ctrl,
                                                 const float4* __restrict__ rois,
                                                 u64* __restrict__ cand2,
                                                 float4* __restrict__ shifted) {
  u32 gid = blockIdx.x * 256 + threadIdx.x;
  u32 total = min(ctrl[C_CANDCNT], (u32)KPAD);
  if (gid >= total) return;
  u64 mykey = cand[gid];
  u32 rank = rankbuf[gid];
  cand2[rank] = mykey;
  float sep = __fadd_rn(funmap(ctrl[C_SEPMAX]), 1.0f);
  u32 idx = (u32)(mykey & 0x3FFFFu);
  u32 lvl = (u32)((mykey >> 18) & 3u);
  float4 r = rois[idx];
  float sh = __fmul_rn((float)lvl, sep);
  float4 o;
  o.x = __fadd_rn(r.x, sh);
  o.y = __fadd_rn(r.y, sh);
  o.z = __fadd_rn(r.z, sh);
  o.w = __fadd_rn(r.w, sh);
  shifted[rank] = o;
}

// 6) build column-major suppression mask. Block = 64 lanes, each lane owns 4
//    columns (cq*256 + lane + {0,64,128,192}); row boxes + areas staged in LDS
//    once and reused 4x. Branch-free inner loop (div-free sup_fast); diagonal
//    masking applied once per word. maskT2[rb*KPAD+j] bit s = sup && rb*64+s<j.
__global__ __launch_bounds__(64) void k_build(const float4* __restrict__ shifted,
                                              u64* __restrict__ maskT2) {
  u32 rb = blockIdx.y;
  u32 cq = blockIdx.x;                 // col chunks cq*4 .. cq*4+3
  if (cq * 4 + 3 < rb) return;         // entirely below diagonal
  int lane = threadIdx.x;
  __shared__ float4 rbox[64];
  __shared__ float rarea[64];
  float4 rv = shifted[rb * 64 + (u32)lane];
  rbox[lane] = rv;
  rarea[lane] = __fmul_rn(__fsub_rn(rv.z, rv.x), __fsub_rn(rv.w, rv.y));
  __syncthreads();
  u32 j0 = cq * 256 + (u32)lane;
  float4 c0 = shifted[j0];
  float4 c1 = shifted[j0 + 64];
  float4 c2 = shifted[j0 + 128];
  float4 c3 = shifted[j0 + 192];
  float a0 = __fmul_rn(__fsub_rn(c0.z, c0.x), __fsub_rn(c0.w, c0.y));
  float a1 = __fmul_rn(__fsub_rn(c1.z, c1.x), __fsub_rn(c1.w, c1.y));
  float a2 = __fmul_rn(__fsub_rn(c2.z, c2.x), __fsub_rn(c2.w, c2.y));
  float a3 = __fmul_rn(__fsub_rn(c3.z, c3.x), __fsub_rn(c3.w, c3.y));
  u64 b0 = 0, b1 = 0, b2 = 0, b3 = 0;
#pragma unroll 8
  for (int s = 0; s < 64; ++s) {
    float4 r = rbox[s];
    float ra = rarea[s];
    b0 |= (u64)sup_fast(ra, r, a0, c0) << s;
    b1 |= (u64)sup_fast(ra, r, a1, c1) << s;
    b2 |= (u64)sup_fast(ra, r, a2, c2) << s;
    b3 |= (u64)sup_fast(ra, r, a3, c3) << s;
  }
  u64 diagm = (1ull << lane) - 1ull;   // keep rows s with rb*64+s < j (s < lane)
  u32 cb = cq * 4;
  u64* dst = maskT2 + (u64)rb * KPAD + (u64)cb * 64 + (u64)lane;
  if (cb >= rb)     dst[0]   = (cb == rb)     ? (b0 & diagm) : b0;
  if (cb + 1 >= rb) dst[64]  = (cb + 1 == rb) ? (b1 & diagm) : b1;
  if (cb + 2 >= rb) dst[128] = (cb + 2 == rb) ? (b2 & diagm) : b2;
  if (cb + 3 >= rb) dst[192] = (cb + 3 == rb) ? (b3 & diagm) : b3;
}

// 7) pipelined 8-wave greedy scan (unchanged from R11)
__global__ __launch_bounds__(512) void k_scan(const u64* __restrict__ maskT2,
                                              const u64* __restrict__ cand2,
                                              u32* __restrict__ ctrl,
                                              const float2* __restrict__ logits,
                                              const float4* __restrict__ rois,
                                              float* __restrict__ out) {
  __shared__ u64 keptm[NCHUNK];
  __shared__ u64 pre[2][8];
  __shared__ u32 lkept[NPOST];
  __shared__ u32 keptS;
  int tid = threadIdx.x;
  int lane = tid & 63, w = tid >> 6;
  u32 total = min(ctrl[C_CANDCNT], (u32)KPAD);
  u32 chunks = (total + 63) >> 6;
  for (int p = tid; p < NCHUNK; p += 512) keptm[p] = 0;
  if (tid < 8)  pre[0][tid] = 0;
  if (tid >= 8 && tid < 16) pre[1][tid - 8] = 0;
  if (tid == 0) keptS = 0;
  __syncthreads();
  u32 kept = 0;
  u64 keepPrev = 0, lastWord = 0, diagCur = 0;
  if (w == 0 && chunks > 0) diagCur = maskT2[(u64)lane];   // diag word chunk 0
  for (u32 c = 0; c < chunks; ++c) {
    if (w == 0) {
      u64 nDiag = 0, nLast = 0;
      if (c + 1 < chunks) {
        nDiag = maskT2[(u64)(c + 1) * KPAD + (u64)(c + 1) * 64 + (u64)lane];
        nLast = maskT2[(u64)c * KPAD + (u64)(c + 1) * 64 + (u64)lane];
      }
      u64 remc = pre[c & 1][1] | pre[c & 1][2] | pre[c & 1][3] | pre[c & 1][4] |
                 pre[c & 1][5] | pre[c & 1][6] | pre[c & 1][7];
      remc |= __ballot((lastWord & keepPrev) != 0ull);   // ci = c-1 patch
      u64 wv = ~remc;
      u32 rem2 = total - c * 64;
      if (rem2 < 64) wv &= ((1ull << rem2) - 1ull);
      u64 keep = wv;
      for (int it = 0; it < 64; ++it) {
        bool sup = (diagCur & keep) != 0ull;
        u64 nk = wv & ~__ballot(sup);
        if (nk == keep) break;     // uniform within wave
        keep = nk;
      }
      u32 pos = kept + (u32)__popcll(keep & ((1ull << lane) - 1ull));
      if (((keep >> lane) & 1ull) && pos < NPOST) lkept[pos] = c * 64 + (u32)lane;
      if (lane == 0) { keptm[c] = keep; keptS = kept + (u32)__popcll(keep); }
      keepPrev = keep;
      lastWord = nLast;
      diagCur = nDiag;
    } else {
      u64 a0 = 0, a1 = 0;
      if (c + 1 < chunks) {
        const u64* colbase = maskT2 + (u64)(c + 1) * 64 + (u64)lane;
        u32 ci = (u32)(w - 1);
        for (; ci + 7 < c; ci += 14) {
          u64 x0 = colbase[(u64)ci * KPAD] & keptm[ci];
          u64 x1 = colbase[(u64)(ci + 7) * KPAD] & keptm[ci + 7];
          a0 |= x0; a1 |= x1;
        }
        for (; ci < c; ci += 7) a0 |= colbase[(u64)ci * KPAD] & keptm[ci];
      }
      u64 bal = __ballot((a0 | a1) != 0ull);
      if (lane == 0) pre[(c + 1) & 1][w] = bal;
    }
    __syncthreads();
    kept = keptS;
    if (kept >= NPOST) break;
  }
  if (tid == 0) ctrl[C_KEPTCNT] = min(kept, (u32)NPOST);
  __syncthreads();
  u32 kn = min(kept, (u32)NPOST);
  for (u32 r = (u32)tid; r < NPOST; r += 512) {
    float l0 = 0.f, l1 = 0.f, b0 = 0.f, b1 = 0.f, b2 = 0.f, b3 = 0.f;
    float lvf = -1.0f, vf = 0.0f;
    if (r < kn) {
      u32 pos = lkept[r];
      u64 a = cand2[pos];
      u32 idx = (u32)(a & 0x3FFFFu);
      u32 lvl = (u32)((a >> 18) & 3u);
      float4 rb = rois[idx];
      float hs = __fsub_rn(rb.z, rb.x);
      float wsz = __fsub_rn(rb.w, rb.y);
      if (hs >= 1.0f && wsz >= 1.0f) {
        float2 lg = logits[idx];
        l0 = lg.x; l1 = lg.y;
        b0 = rb.x; b1 = rb.y; b2 = rb.z; b3 = rb.w;
        lvf = (float)lvl; vf = 1.0f;
      }
    }
    out[2 * r] = l0;
    out[2 * r + 1] = l1;
    out[2 * NPOST + 4 * r + 0] = b0;
    out[2 * NPOST + 4 * r + 1] = b1;
    out[2 * NPOST + 4 * r + 2] = b2;
    out[2 * NPOST + 4 * r + 3] = b3;
    out[6 * NPOST + r] = lvf;
    out[7 * NPOST + r] = vf;
  }
}

// fallback) sequential greedy NMS (only if ws too small for the mask)
__global__ __launch_bounds__(1024) void k_nms(const float4* __restrict__ shifted,
                                              u32* __restrict__ ctrl, u32* __restrict__ keptpos) {
  __shared__ float4 kbox[NPOST];
  __shared__ u32 wflag[16];
  int tid = threadIdx.x;
  u32 total = min(ctrl[C_CANDCNT], (u32)KPAD);
  int n = 0;
  for (u32 i = 0; i < total; ++i) {
    float4 cur = shifted[i];
    bool sup = false;
    if (tid < n) sup = suppress(kbox[tid], cur);
    int any = __any(sup);
    if ((tid & 63) == 0) wflag[tid >> 6] = (u32)any;
    __syncthreads();
    u32 f = 0;
#pragma unroll
    for (int w = 0; w < 16; ++w) f |= wflag[w];
    if (!f) {
      if (tid == 0) { kbox[n] = cur; keptpos[n] = i; }
      ++n;
    }
    __syncthreads();
    if (n >= NPOST) break;
  }
  if (tid == 0) ctrl[C_KEPTCNT] = (u32)n;
}

// fallback output gather
__global__ void k_out(const u64* __restrict__ cand, const u32* __restrict__ keptpos,
                      const u32* __restrict__ ctrl, const float2* __restrict__ logits,
                      const float4* __restrict__ rois, float* __restrict__ out) {
  int r = blockIdx.x * blockDim.x + threadIdx.x;
  if (r >= NPOST) return;
  u32 kn = ctrl[C_KEPTCNT];
  float l0 = 0.f, l1 = 0.f, r0 = 0.f, r1 = 0.f, r2 = 0.f, r3 = 0.f;
  float lvf = -1.0f, vf = 0.0f;
  if (r < (int)kn) {
    u32 pos = keptpos[r];
    u64 a = cand[pos];
    u32 idx = (u32)(a & 0x3FFFFu);
    u32 lvl = (u32)((a >> 18) & 3u);
    float4 rb = rois[idx];
    float hs = __fsub_rn(rb.z, rb.x);
    float wsz = __fsub_rn(rb.w, rb.y);
    if (hs >= 1.0f && wsz >= 1.0f) {
      float2 lg = logits[idx];
      l0 = lg.x; l1 = lg.y;
      r0 = rb.x; r1 = rb.y; r2 = rb.z; r3 = rb.w;
      lvf = (float)lvl; vf = 1.0f;
    }
  }
  out[2 * r] = l0;
  out[2 * r + 1] = l1;
  out[2 * NPOST + 4 * r + 0] = r0;
  out[2 * NPOST + 4 * r + 1] = r1;
  out[2 * NPOST + 4 * r + 2] = r2;
  out[2 * NPOST + 4 * r + 3] = r3;
  out[6 * NPOST + r] = lvf;
  out[7 * NPOST + r] = vf;
}

extern "C" void kernel_launch(void* const* d_in, const int* in_sizes, int n_in,
                              void* d_out, int out_size, void* d_ws, size_t ws_size,
                              hipStream_t stream) {
  const float* logits = (const float*)d_in[0];
  const float* rois = (const float*)d_in[1];
  const int* levels = (const int*)d_in[2];
  int N = in_sizes[2];

  char* ws = (char*)d_ws;
  u32* sbits = (u32*)(ws + OFF_SBITS);
  u32* ctrl = (u32*)(ws + OFF_CTRL);
  u32* rankbuf = (u32*)(ws + OFF_RANK);
  u32* hist1 = (u32*)(ws + OFF_H1);
  u32* histm = (u32*)(ws + OFF_HM);
  u32* keptpos = (u32*)(ws + OFF_KEPT);
  u64* tie = (u64*)(ws + OFF_TIE);
  u64* cand = (u64*)(ws + OFF_CAND);
  float4* shifted = (float4*)(ws + OFF_SHIFT);
  u64* cand2 = (u64*)(ws + OFF_CAND2);
  u64* maskT2 = (u64*)(ws + OFF_MASK);

  // ctrl + rankbuf + hist1 + histm contiguous: one 44KB memset
  hipMemsetAsync(ctrl, 0, MEMSET_BYTES, stream);

  int nb2 = (N + 511) / 512;
  k_score_hist<<<nb2, 512, 0, stream>>>((const float2*)logits, levels, sbits, hist1, N);
  k_hist_m<<<nb2, 512, 0, stream>>>(sbits, levels, hist1, histm, N);
  k_compact<<<nb2, 512, 0, stream>>>(sbits, levels, hist1, histm, ctrl, cand, tie, N);
  k_ties<<<NLVL, 256, 0, stream>>>(ctrl, cand, tie);
  {
    dim3 g(KPAD / 256, 8);
    k_rankp<<<g, 256, 0, stream>>>(cand, ctrl, (const float4*)rois, rankbuf, ctrl);
  }
  k_scatter<<<KPAD / 256, 256, 0, stream>>>(cand, rankbuf, ctrl, (const float4*)rois,
                                            cand2, shifted);
  if (ws_size >= WS_NEED) {
    dim3 g(KPAD / 256, KPAD / 64);
    k_build<<<g, 64, 0, stream>>>((const float4*)shifted, maskT2);
    k_scan<<<1, 512, 0, stream>>>(maskT2, cand2, ctrl,
                                  (const float2*)logits, (const float4*)rois, (float*)d_out);
  } else {
    k_nms<<<1, 1024, 0, stream>>>(shifted, ctrl, keptpos);
    k_out<<<(NPOST + 255) / 256, 256, 0, stream>>>(cand2, keptpos, ctrl, (const float2*)logits,
                                                   (const float4*)rois, (float*)d_out);
  }
}